// Round 10
// baseline (588.208 us; speedup 1.0000x reference)
//
#include <hip/hip_runtime.h>

typedef unsigned short u16;
typedef __attribute__((ext_vector_type(4))) unsigned short u16x4;
typedef __attribute__((ext_vector_type(8))) unsigned short u16x8;
typedef __attribute__((ext_vector_type(4))) short s16x4;
typedef __attribute__((ext_vector_type(4))) float f32x4;
typedef __attribute__((ext_vector_type(8))) __bf16 bf16x8;

__device__ __forceinline__ u16 f2bf(float f) {
  union { float f; unsigned int u; } v; v.f = f;
  unsigned int u = v.u;
  unsigned int r = (u + 0x7fffu + ((u >> 16) & 1u)) >> 16;
  return (u16)r;
}
__device__ __forceinline__ u16 f2bf_hw(float f) {  // RNE via HW convert
  return __builtin_bit_cast(u16, (__bf16)f);
}
__device__ __forceinline__ float bf2f(u16 h) {
  union { unsigned int u; float f; } v; v.u = ((unsigned int)h) << 16;
  return v.f;
}
__device__ __forceinline__ f32x4 mfma16(u16x8 a, u16x8 b, f32x4 c) {
  return __builtin_amdgcn_mfma_f32_16x16x32_bf16(
      __builtin_bit_cast(bf16x8, a), __builtin_bit_cast(bf16x8, b), c, 0, 0, 0);
}
// K=16 variant: A/B are 4 bf16 (2 VGPRs)
__device__ __forceinline__ f32x4 mfma16k16(u16x4 a, u16x4 b, f32x4 c) {
  return __builtin_amdgcn_mfma_f32_16x16x16bf16_1k(
      __builtin_bit_cast(s16x4, a), __builtin_bit_cast(s16x4, b), c, 0, 0, 0);
}
// async global->LDS, 16B per lane; LDS dest = wave-uniform base + lane*16
__device__ __forceinline__ void glds16(const void* g, void* l) {
  __builtin_amdgcn_global_load_lds((const __attribute__((address_space(1))) void*)g,
                                   (__attribute__((address_space(3))) void*)l, 16, 0, 0);
}
// bijective XCD-chunked remap: XCD x (= bid&7 empirically) owns a contiguous
// logical-tile range -> blocks sharing operand panels are L2-co-resident.
__device__ __forceinline__ int xcd_chunk(int bid, int nwg) {
  int xcd = bid & 7, idx = bid >> 3;
  int q = nwg >> 3, r = nwg & 7;
  int base = xcd < r ? xcd * (q + 1) : r * (q + 1) + (xcd - r) * q;
  return base + idx;
}

// ---------------- fused fp32 -> bf16 conversion (all 6 tensors, 1 launch) ----------
__global__ __launch_bounds__(256) void cvt_all(
    const float* __restrict__ hs, const float* __restrict__ his,
    const float* __restrict__ Wq, const float* __restrict__ Wk,
    const float* __restrict__ Wv, const float* __restrict__ Wo,
    u16* __restrict__ hsb, u16* __restrict__ hib,
    u16* __restrict__ wqb, u16* __restrict__ wkb,
    u16* __restrict__ wvb, u16* __restrict__ wob) {
  // f4-chunk boundaries (all /256 -> block-uniform branch)
  const int N0 = 1198080, N1 = 5990400, N2 = 6580224, N3 = 7170048, N4 = 7759872;
  int i = blockIdx.x * 256 + threadIdx.x;
  const float* s; u16* o; int base;
  if (i < N0)      { s = hs;  o = hsb; base = 0;  }
  else if (i < N1) { s = his; o = hib; base = N0; }
  else if (i < N2) { s = Wq;  o = wqb; base = N1; }
  else if (i < N3) { s = Wk;  o = wkb; base = N2; }
  else if (i < N4) { s = Wv;  o = wvb; base = N3; }
  else             { s = Wo;  o = wob; base = N4; }
  int j = i - base;
  float4 v = ((const float4*)s)[j];
  u16x4 r;
  r.x = f2bf(v.x); r.y = f2bf(v.y); r.z = f2bf(v.z); r.w = f2bf(v.w);
  ((u16x4*)o)[j] = r;
}

// ---------------- GEMM: C[M,1536] = A[M,1536] @ W[1536,1536]^T + bias ----------------
// 1D grid + XCD-chunked swizzle (same-row-panel blocks co-resident per XCD).
template <int OUT, int NBX>  // OUT: 0 = bf16, 1 = f32
__global__ __launch_bounds__(256, 2) void gemm_v2(
    const u16* __restrict__ A, const u16* __restrict__ W,
    const float* __restrict__ bias, void* __restrict__ Cp, int M) {
  const int K = 1536, N = 1536;
  __shared__ __align__(16) u16 gsm[17408];
  u16* As = gsm;
  u16* Bs = gsm + 8192;
  const int tid = threadIdx.x;
  const int lane = tid & 63, wid = tid >> 6;
  const int quad = lane >> 4, l15 = lane & 15;
  const int lg = xcd_chunk(blockIdx.x, gridDim.x);
  const int m0 = (lg / NBX) * 128, n0 = (lg % NBX) * 128;
  const int wm = (wid >> 1) * 64, wn = (wid & 1) * 64;
  f32x4 acc[4][4];
#pragma unroll
  for (int i = 0; i < 4; ++i)
#pragma unroll
    for (int j = 0; j < 4; ++j)
#pragma unroll
      for (int r = 0; r < 4; ++r) acc[i][j][r] = 0.f;

  const int r8 = lane >> 3, c8 = lane & 7;
  const int gch = c8 ^ r8;

  for (int k0 = 0; k0 < K; k0 += 64) {
#pragma unroll
    for (int inst = 0; inst < 4; ++inst) {
      int row = wid * 32 + inst * 8 + r8;
      glds16(A + ((size_t)(m0 + row) * K + k0 + gch * 8), As + (wid * 32 + inst * 8) * 64);
      glds16(W + ((size_t)(n0 + row) * K + k0 + gch * 8), Bs + (wid * 32 + inst * 8) * 64);
    }
    asm volatile("s_waitcnt vmcnt(0)" ::: "memory");
    __syncthreads();
#pragma unroll
    for (int ks = 0; ks < 2; ++ks) {
      u16x8 af[4], bfr[4];
#pragma unroll
      for (int i = 0; i < 4; ++i) {
        int row = wm + i * 16 + l15;
        af[i] = *(const u16x8*)&As[row * 64 + (((ks * 4 + quad) ^ (l15 & 7)) * 8)];
      }
#pragma unroll
      for (int j = 0; j < 4; ++j) {
        int row = wn + j * 16 + l15;
        bfr[j] = *(const u16x8*)&Bs[row * 64 + (((ks * 4 + quad) ^ (l15 & 7)) * 8)];
      }
#pragma unroll
      for (int i = 0; i < 4; ++i)
#pragma unroll
        for (int j = 0; j < 4; ++j) acc[i][j] = mfma16(af[i], bfr[j], acc[i][j]);
    }
    __syncthreads();
  }

#pragma unroll
  for (int i = 0; i < 4; ++i) {
    int row = m0 + wm + i * 16 + quad * 4;
#pragma unroll
    for (int j = 0; j < 4; ++j) {
      int col = n0 + wn + j * 16 + l15;
      float bc = bias[col];
#pragma unroll
      for (int r = 0; r < 4; ++r) {
        if (row + r < M) {
          float v = acc[i][j][r] + bc;
          if (OUT == 1)
            ((float*)Cp)[(size_t)(row + r) * N + col] = v;
          else
            ((u16*)Cp)[(size_t)(row + r) * N + col] = f2bf(v);
        }
      }
    }
  }
}

// ---------------- fused K+V projection GEMM, 256^2 8-phase (T2+T3+T4+T5) ------------
// C[12480 x 3072] = A @ Wkv^T. 512 thr = 8 waves (2M x 4N), BK=64, per-wave C 128x64.
// LDS 128 KB dynamic: A/B double-buffered [buf][ks-half][256 rows][32 cols], staged as
// k-half tiles (2 glds16/wave/phase), order B0,A0,B1,A1. Counted vmcnt(4) EVERY phase
// (never 0 in the loop): phase p's wait certifies the half-tile staged at phase p-2
// (B0: staged t.ph0 -> certified t.ph2 -> read t+1.ph0; A0: t.ph1 -> t.ph3 -> t+1.ph0;
// B1: t.ph2 -> t+1.ph0 -> t+1.ph2; A1: t.ph3 -> t+1.ph1 -> t+1.ph2) -- every certify
// precedes its read. Raw s_barrier, lgkmcnt(0)+sched_barrier before MFMA (rule 18),
// setprio around the MFMA cluster. NTK = 1536/64 = 24 (R9 bug: was 12 -> half of K).
__global__ __launch_bounds__(512, 2) void gemm_kv8(
    const u16* __restrict__ A, const u16* __restrict__ Wkv,
    const float* __restrict__ bk, const float* __restrict__ bv,
    u16* __restrict__ Ck, u16* __restrict__ Vt, int M, int ldt) {
  const int K = 1536, NTK = 24;
  extern __shared__ u16 smem[];  // u16 units: A0@0, A1@16384, B0@32768, B1@49152
  const int tid = threadIdx.x;
  const int lane = tid & 63, wid = tid >> 6;
  const int quad = lane >> 4, l15 = lane & 15;
  const int lg = xcd_chunk(blockIdx.x, gridDim.x);
  const int qtr = lg / 147, rem = lg % 147;   // 147 = 49 m x 3 n per quarter
  const int m0 = (rem / 3) * 256;
  const int nt = qtr * 3 + rem % 3;
  const int n0 = nt * 256;                    // 0..2816
  const int wm = (wid >> 2) * 128, wn = (wid & 3) * 64;

  f32x4 acc[8][4];
#pragma unroll
  for (int i = 0; i < 8; ++i)
#pragma unroll
    for (int j = 0; j < 4; ++j)
#pragma unroll
      for (int r = 0; r < 4; ++r) acc[i][j][r] = 0.f;

  // stage one k-half (256 rows x 32 cols) of A or B: 2 glds16/wave, 16 rows each.
  // LDS slot s of row r holds source col-group s ^ (r&3)  (matches read swizzle).
  auto stageA = [&](int t, int ks, int buf) {
    u16* dst = smem + buf * 16384 + ks * 8192;
    const int k0 = t * 64 + ks * 32;
#pragma unroll
    for (int n = 0; n < 2; ++n) {
      int rl = n * 128 + wid * 16 + (lane >> 2);
      int grp = (lane & 3) ^ ((lane >> 2) & 3);
      glds16(A + (size_t)(m0 + rl) * K + k0 + grp * 8, dst + (n * 128 + wid * 16) * 32);
    }
  };
  auto stageB = [&](int t, int ks, int buf) {
    u16* dst = smem + 32768 + buf * 16384 + ks * 8192;
    const int k0 = t * 64 + ks * 32;
#pragma unroll
    for (int n = 0; n < 2; ++n) {
      int rl = n * 128 + wid * 16 + (lane >> 2);
      int grp = (lane & 3) ^ ((lane >> 2) & 3);
      glds16(Wkv + (size_t)(n0 + rl) * K + k0 + grp * 8, dst + (n * 128 + wid * 16) * 32);
    }
  };

  // prologue: tile 0 fully into buf 0
  stageB(0, 0, 0); stageA(0, 0, 0); stageB(0, 1, 0); stageA(0, 1, 0);
  asm volatile("s_waitcnt vmcnt(0)" ::: "memory");
  __builtin_amdgcn_s_barrier();

  for (int t = 0; t < NTK; ++t) {
    const int buf = t & 1, nb = buf ^ 1;
    const bool more = (t + 1) < NTK;
    u16* Ab = smem + buf * 16384;
    u16* Bb = smem + 32768 + buf * 16384;
    u16x8 afr[4], bfr[4];
#pragma unroll
    for (int ph = 0; ph < 4; ++ph) {
      const int ks = ph >> 1, ih = ph & 1;
      if (ih == 0) {
#pragma unroll
        for (int j = 0; j < 4; ++j) {
          int row = wn + j * 16 + l15;
          bfr[j] = *(const u16x8*)&Bb[ks * 8192 + row * 32 + ((quad ^ (row & 3)) * 8)];
        }
      }
#pragma unroll
      for (int ii = 0; ii < 4; ++ii) {
        int row = wm + ih * 64 + ii * 16 + l15;
        afr[ii] = *(const u16x8*)&Ab[ks * 8192 + row * 32 + ((quad ^ (row & 3)) * 8)];
      }
      if (more) {
        if (ph == 0) stageB(t + 1, 0, nb);
        else if (ph == 1) stageA(t + 1, 0, nb);
        else if (ph == 2) stageB(t + 1, 1, nb);
        else stageA(t + 1, 1, nb);
      }
      asm volatile("s_waitcnt vmcnt(4)" ::: "memory");
      __builtin_amdgcn_s_barrier();
      asm volatile("s_waitcnt lgkmcnt(0)" ::: "memory");
      __builtin_amdgcn_sched_barrier(0);
      __builtin_amdgcn_s_setprio(1);
#pragma unroll
      for (int ii = 0; ii < 4; ++ii)
#pragma unroll
        for (int j = 0; j < 4; ++j)
          acc[ih * 4 + ii][j] = mfma16(afr[ii], bfr[j], acc[ih * 4 + ii][j]);
      __builtin_amdgcn_s_setprio(0);
      __builtin_amdgcn_s_barrier();
      __builtin_amdgcn_sched_barrier(0);
    }
  }

  if (n0 < 1536) {  // K-projection: direct bf16 stores
#pragma unroll
    for (int i = 0; i < 8; ++i) {
      int row = m0 + wm + i * 16 + quad * 4;
#pragma unroll
      for (int j = 0; j < 4; ++j) {
        int col = n0 + wn + j * 16 + l15;
        float bc = bk[col];
#pragma unroll
        for (int r = 0; r < 4; ++r) {
          if (row + r < M)
            Ck[(size_t)(row + r) * 1536 + col] = f2bf(acc[i][j][r] + bc);
        }
      }
    }
  } else {  // V-projection: transposed store via LDS, two 128-col passes
    const int n0v = n0 - 1536;
    u16* Ct = smem;  // [128 n][264] (+8 pad)
    __syncthreads();
#pragma unroll
    for (int hn = 0; hn < 2; ++hn) {
      if (((wid & 3) >> 1) == hn) {
        int nbase = wn - hn * 128;  // 0 or 64
#pragma unroll
        for (int j = 0; j < 4; ++j) {
          int nloc = nbase + j * 16 + l15;
          float bc = bv[n0v + hn * 128 + nloc];
#pragma unroll
          for (int i = 0; i < 8; ++i) {
            int mloc = wm + i * 16 + quad * 4;
            u16x4 w4;
#pragma unroll
            for (int r = 0; r < 4; ++r) w4[r] = f2bf(acc[i][j][r] + bc);
            *(u16x4*)&Ct[nloc * 264 + mloc] = w4;
          }
        }
      }
      __syncthreads();
#pragma unroll
      for (int e = 0; e < 8; ++e) {
        int idx = e * 512 + tid;  // 128 n x 32 m-chunks
        int n = idx >> 5, mc = idx & 31;
        int mg = m0 + mc * 8;
        if (mg < M) {
          u16x8 v = *(const u16x8*)&Ct[n * 264 + mc * 8];
          *(u16x8*)(Vt + (size_t)(n0v + hn * 128 + n) * ldt + mg) = v;
        }
      }
      __syncthreads();
    }
  }
}

// ---------------- fused RMSNorm + interleaved RoPE, in-place bf16 ----------------
__global__ __launch_bounds__(192) void norm_rope2(u16* __restrict__ X,
                                                  const float* __restrict__ g,
                                                  const float* __restrict__ fc,
                                                  const float* __restrict__ fs,
                                                  float oscale) {
  const int DIMc = 1536;
  int row = blockIdx.x;
  int tid = threadIdx.x;
  u16* xr = X + (size_t)row * DIMc + tid * 8;
  u16x8 v = *(const u16x8*)xr;
  float x[8];
  float ss = 0.f;
#pragma unroll
  for (int e = 0; e < 8; ++e) { x[e] = bf2f(v[e]); ss += x[e] * x[e]; }
#pragma unroll
  for (int m = 1; m < 64; m <<= 1) ss += __shfl_xor(ss, m);
  __shared__ float w3[3];
  if ((tid & 63) == 0) w3[tid >> 6] = ss;
  __syncthreads();
  float rs = rsqrtf((w3[0] + w3[1] + w3[2]) * (1.f / 1536.f) + 1e-5f);
  int dhb = (tid * 8) & 127;
  const float* fcr = fc + (size_t)row * 128 + dhb;
  const float* fsr = fs + (size_t)row * 128 + dhb;
  float4 c0 = *(const float4*)fcr, c1 = *(const float4*)(fcr + 4);
  float4 s0 = *(const float4*)fsr, s1 = *(const float4*)(fsr + 4);
  const float* gp = g + tid * 8;
  float4 g0 = *(const float4*)gp, g1 = *(const float4*)(gp + 4);
  float cosv[4] = {c0.x, c0.z, c1.x, c1.z};
  float sinv[4] = {s0.y, s0.w, s1.y, s1.w};
  float gv[8] = {g0.x, g0.y, g0.z, g0.w, g1.x, g1.y, g1.z, g1.w};
  u16x8 o;
#pragma unroll
  for (int p = 0; p < 4; ++p) {
    float a = x[2 * p] * rs * gv[2 * p];
    float b = x[2 * p + 1] * rs * gv[2 * p + 1];
    o[2 * p] = f2bf((a * cosv[p] - b * sinv[p]) * oscale);
    o[2 * p + 1] = f2bf((a * sinv[p] + b * cosv[p]) * oscale);
  }
  *(u16x8*)xr = o;
}

// ---------------- block-sparse attention v11: t-balanced XCD map ----------------
__global__ __launch_bounds__(256, 3) void attn11(
    const u16* __restrict__ Q, const u16* __restrict__ Kb,
    const u16* __restrict__ VT, const int* __restrict__ sel,
    float* __restrict__ Oacc, float* __restrict__ Lp) {
  const int HWc = 1560, DIMc = 1536, KTt = 12480, NT = 600;
  __shared__ __align__(16) u16 smem[16384];  // Ks0|Ks1|Vt0|Vt1 (8 KB each)
  const int tid = threadIdx.x;
  const int lane = tid & 63, wid = tid >> 6;
  const int quad = lane >> 4, l15 = lane & 15;

  int bid = blockIdx.x;
  int xcd = bid & 7, idx = bid >> 3;
  int il = idx / 13, mt = idx % 13;
  int u = xcd + 8 * (il >> 1);
  const int t = il & 1;
  const int seg = u / 12;
  const int h = u % 12;
  const int m0 = mt * 128;
  const int g = h * 2 + t;

  int s0v = sel[2 * t];
  const int b0 = s0v > 0 ? s0v : 0;
  const int b1 = sel[2 * t + 1];
  const int nk = (b1 >= 0) ? 2 * HWc : HWc;
  const int nch = (nk + 31) >> 5;
  const int cpseg = (nch + 3) >> 2;
  const int c0 = seg * cpseg;
  const int c1 = (c0 + cpseg < nch) ? c0 + cpseg : nch;

  // Q B-frags: this wave's 32 q rows (2 sub-tiles of 16)
  u16x8 qf[2][4];
#pragma unroll
  for (int qt = 0; qt < 2; ++qt) {
    int qrow = m0 + wid * 32 + qt * 16 + l15;
    if (qrow > HWc - 1) qrow = HWc - 1;
    const u16* qp = Q + (size_t)(t * HWc + qrow) * DIMc + h * 128;
#pragma unroll
    for (int ks = 0; ks < 4; ++ks) qf[qt][ks] = *(const u16x8*)(qp + ks * 32 + quad * 8);
  }

  f32x4 oacc[2][8];  // partial O^T: [q-subtile][d-tile]
#pragma unroll
  for (int qt = 0; qt < 2; ++qt)
#pragma unroll
    for (int m = 0; m < 8; ++m)
#pragma unroll
      for (int r = 0; r < 4; ++r) oacc[qt][m][r] = 0.f;
  float lp[2] = {0.f, 0.f};

  auto stage = [&](int kc, int buf) {
    u16* Ks = smem + buf * 4096;
    u16* Vt = smem + 8192 + buf * 4096;
#pragma unroll
    for (int n = 0; n < 2; ++n) {
      int kl = wid * 8 + n * 4 + (lane >> 4);
      int gc = (lane & 15) ^ (kl & 15);
      int kg = kc + kl;
      if (kg >= nk) kg = 0;
      int big = kg >= HWc;
      int tok = (big ? b1 : b0) * HWc + kg - (big ? HWc : 0);
      glds16(Kb + ((size_t)tok * DIMc + h * 128 + gc * 8), Ks + (wid * 8 + n * 4) * 128);
    }
#pragma unroll
    for (int n = 0; n < 2; ++n) {
      int dl = wid * 32 + n * 16 + (lane >> 2);
      int gc = (lane & 3) ^ (dl & 3) ^ ((dl >> 2) & 3);
      int tg = kc + gc * 8;
      if (tg >= nk) tg = 0;
      int big = tg >= HWc;
      int tok = (big ? b1 : b0) * HWc + tg - (big ? HWc : 0);
      glds16(VT + ((size_t)(h * 128 + dl) * KTt + tok), Vt + (wid * 32 + n * 16) * 32);
    }
  };

  if (c0 < c1) stage(c0 * 32, 0);

  for (int c = c0; c < c1; ++c) {
    const int buf = (c - c0) & 1;
    u16* Ks = smem + buf * 4096;
    u16* Vt = smem + 8192 + buf * 4096;
    asm volatile("s_waitcnt vmcnt(0)\n\ts_barrier" ::: "memory");
    if (c + 1 < c1) stage((c + 1) * 32, buf ^ 1);

    f32x4 s[2][2];  // [gg][qt]
#pragma unroll
    for (int gg = 0; gg < 2; ++gg)
#pragma unroll
      for (int qt = 0; qt < 2; ++qt)
#pragma unroll
        for (int r = 0; r < 4; ++r) s[gg][qt][r] = 0.f;
#pragma unroll
    for (int ks = 0; ks < 4; ++ks)
#pragma unroll
      for (int gg = 0; gg < 2; ++gg) {
        u16x8 ka = *(const u16x8*)&Ks[(gg * 16 + l15) * 128 + (((ks * 4 + quad) ^ l15) * 8)];
#pragma unroll
        for (int qt = 0; qt < 2; ++qt) s[gg][qt] = mfma16(ka, qf[qt][ks], s[gg][qt]);
      }

    float p[2][2][4];
#pragma unroll
    for (int gg = 0; gg < 2; ++gg)
#pragma unroll
      for (int qt = 0; qt < 2; ++qt)
#pragma unroll
        for (int r = 0; r < 4; ++r) p[gg][qt][r] = exp2f(s[gg][qt][r]);
    if ((c + 1) * 32 > nk) {  // wave-uniform
#pragma unroll
      for (int gg = 0; gg < 2; ++gg)
#pragma unroll
        for (int r = 0; r < 4; ++r) {
          bool bad = c * 32 + gg * 16 + quad * 4 + r >= nk;
          if (bad) {
#pragma unroll
            for (int qt = 0; qt < 2; ++qt) p[gg][qt][r] = 0.f;
          }
        }
    }
    u16x4 pb[2][2];
#pragma unroll
    for (int gg = 0; gg < 2; ++gg)
#pragma unroll
      for (int qt = 0; qt < 2; ++qt)
#pragma unroll
        for (int r = 0; r < 4; ++r) {
          lp[qt] += p[gg][qt][r];
          pb[gg][qt][r] = f2bf_hw(p[gg][qt][r]);
        }

#pragma unroll
    for (int m = 0; m < 8; ++m) {
      int d = m * 16 + l15;
#pragma unroll
      for (int gg = 0; gg < 2; ++gg) {
        int sl = (gg * 2 + (quad >> 1)) ^ (d & 3) ^ ((d >> 2) & 3);
        u16x4 va = *(const u16x4*)&Vt[d * 32 + sl * 8 + (quad & 1) * 4];
#pragma unroll
        for (int qt = 0; qt < 2; ++qt) oacc[qt][m] = mfma16k16(va, pb[gg][qt], oacc[qt][m]);
      }
    }
  }

#pragma unroll
  for (int qt = 0; qt < 2; ++qt) {
    lp[qt] += __shfl_xor(lp[qt], 16);
    lp[qt] += __shfl_xor(lp[qt], 32);
  }
#pragma unroll
  for (int qt = 0; qt < 2; ++qt) {
    int qrow0 = m0 + wid * 32 + qt * 16;  // wave-uniform
    if (qrow0 < HWc) {
      size_t sb = ((size_t)seg * NT + g * 25 + (qrow0 >> 6)) * 64 + (qrow0 & 63);
      if (lane < 16 && qrow0 + lane < HWc) Lp[sb + lane] = lp[qt];
      if (qrow0 + l15 < HWc) {
#pragma unroll
        for (int m = 0; m < 8; ++m)
          *(f32x4*)&Oacc[(sb + l15) * 128 + m * 16 + quad * 4] = oacc[qt][m];
      }
    }
  }
}

// ---------------- normalize: O = bf16(sum_seg Oacc / sum_seg Lp) ----------------
__global__ __launch_bounds__(256) void attn_norm(const float* __restrict__ Oacc,
                                                 const float* __restrict__ Lp,
                                                 u16* __restrict__ O) {
  const int HWc = 1560, DIMc = 1536, NT = 600;
  int tile = blockIdx.x;  // 600
  int g = tile / 25, mt = tile % 25;
  int h = g >> 1, t = g & 1;
  int m0 = mt * 64;
  int tid = threadIdx.x;
#pragma unroll
  for (int e = 0; e < 8; ++e) {
    int idx = e * 256 + tid;   // 0..2047 f32x4 slots (64 q x 32)
    int qloc = idx >> 5;
    int d4 = (idx & 31) * 4;
    int q = m0 + qloc;
    if (q < HWc) {
      f32x4 a = {0.f, 0.f, 0.f, 0.f};
      float l = 0.f;
#pragma unroll
      for (int s = 0; s < 4; ++s) {
        const size_t sbase = ((size_t)s * NT + tile) * 64 + qloc;
        f32x4 v = *(const f32x4*)&Oacc[sbase * 128 + d4];
#pragma unroll
        for (int r = 0; r < 4; ++r) a[r] += v[r];
        l += Lp[sbase];
      }
      float linv = 1.f / l;
      u16x4 o;
#pragma unroll
      for (int r = 0; r < 4; ++r) o[r] = f2bf(a[r] * linv);
      *(u16x4*)(O + (size_t)(t * HWc + q) * DIMc + h * 128 + d4) = o;
    }
  }
}

extern "C" void kernel_launch(void* const* d_in, const int* in_sizes, int n_in,
                              void* d_out, int out_size, void* d_ws, size_t ws_size,
                              hipStream_t stream) {
  const float* hs  = (const float*)d_in[0];
  const float* his = (const float*)d_in[1];
  const float* fc  = (const float*)d_in[2];
  const float* fs  = (const float*)d_in[3];
  const float* fch = (const float*)d_in[4];
  const float* fsh = (const float*)d_in[5];
  const int*   sel = (const int*)d_in[6];
  const float* Wq  = (const float*)d_in[7];
  const float* bq  = (const float*)d_in[8];
  const float* Wk  = (const float*)d_in[9];
  const float* bk  = (const float*)d_in[10];
  const float* Wv  = (const float*)d_in[11];
  const float* bv  = (const float*)d_in[12];
  const float* Wo  = (const float*)d_in[13];
  const float* bo  = (const float*)d_in[14];
  const float* gq  = (const float*)d_in[15];
  const float* gk  = (const float*)d_in[16];

  const int QT = 3120, KT = 12480, DIMc = 1536;
  u16* p = (u16*)d_ws;
  u16* qb  = p; p += (size_t)QT * DIMc;
  u16* kb2 = p; p += (size_t)KT * DIMc;
  u16* vt  = p; p += (size_t)DIMc * KT;   // V^T [1536][12480]
  u16* ab  = p; p += (size_t)QT * DIMc;
  u16* wob = p; p += (size_t)DIMc * DIMc;
  u16* scratch = p;
  u16* hsb = scratch;
  u16* hib = hsb + (size_t)QT * DIMc;
  u16* wqb = hib + (size_t)KT * DIMc;
  u16* wkb = wqb + (size_t)DIMc * DIMc;   // wkb and wvb adjacent -> stacked [3072][1536]
  u16* wvb = wkb + (size_t)DIMc * DIMc;
  float* oaccb = (float*)scratch;                      // f32 [4][600][64][128]
  float* lpb   = oaccb + (size_t)4 * 600 * 64 * 128;   // f32 [4][600][64]

  cvt_all<<<dim3(32616), 256, 0, stream>>>(hs, his, Wq, Wk, Wv, Wo,
                                           hsb, hib, wqb, wkb, wvb, wob);

  gemm_v2<0, 12><<<dim3(300), 256, 0, stream>>>(hsb, wqb, bq, qb, QT);
  gemm_kv8<<<dim3(588), 512, 131072, stream>>>(hib, wkb, bk, bv, kb2, vt, KT, KT);

  const float qscale = (float)(0.08838834764831845 * 1.4426950408889634);
  norm_rope2<<<dim3(QT), 192, 0, stream>>>(qb, gq, fc, fs, qscale);
  norm_rope2<<<dim3(KT), 192, 0, stream>>>(kb2, gk, fch, fsh, 1.0f);

  // attn11 clobbers hsb/hib/wq/wk/wv (all dead by now); wob stays live for the final gemm.
  attn11<<<dim3(1248), 256, 0, stream>>>(qb, kb2, vt, sel, oaccb, lpb);
  attn_norm<<<dim3(600), 256, 0, stream>>>(oaccb, lpb, ab);

  gemm_v2<1, 12><<<dim3(300), 256, 0, stream>>>(ab, wob, bo, d_out, QT);
}

// Round 11
// 578.788 us; speedup vs baseline: 1.0163x; 1.0163x over previous
//
#include <hip/hip_runtime.h>

typedef unsigned short u16;
typedef __attribute__((ext_vector_type(4))) unsigned short u16x4;
typedef __attribute__((ext_vector_type(8))) unsigned short u16x8;
typedef __attribute__((ext_vector_type(4))) short s16x4;
typedef __attribute__((ext_vector_type(4))) float f32x4;
typedef __attribute__((ext_vector_type(8))) __bf16 bf16x8;

__device__ __forceinline__ u16 f2bf(float f) {
  union { float f; unsigned int u; } v; v.f = f;
  unsigned int u = v.u;
  unsigned int r = (u + 0x7fffu + ((u >> 16) & 1u)) >> 16;
  return (u16)r;
}
__device__ __forceinline__ u16 f2bf_hw(float f) {  // RNE via HW convert
  return __builtin_bit_cast(u16, (__bf16)f);
}
__device__ __forceinline__ float bf2f(u16 h) {
  union { unsigned int u; float f; } v; v.u = ((unsigned int)h) << 16;
  return v.f;
}
__device__ __forceinline__ f32x4 mfma16(u16x8 a, u16x8 b, f32x4 c) {
  return __builtin_amdgcn_mfma_f32_16x16x32_bf16(
      __builtin_bit_cast(bf16x8, a), __builtin_bit_cast(bf16x8, b), c, 0, 0, 0);
}
// K=16 variant: A/B are 4 bf16 (2 VGPRs)
__device__ __forceinline__ f32x4 mfma16k16(u16x4 a, u16x4 b, f32x4 c) {
  return __builtin_amdgcn_mfma_f32_16x16x16bf16_1k(
      __builtin_bit_cast(s16x4, a), __builtin_bit_cast(s16x4, b), c, 0, 0, 0);
}
// async global->LDS, 16B per lane; LDS dest = wave-uniform base + lane*16
__device__ __forceinline__ void glds16(const void* g, void* l) {
  __builtin_amdgcn_global_load_lds((const __attribute__((address_space(1))) void*)g,
                                   (__attribute__((address_space(3))) void*)l, 16, 0, 0);
}
// bijective XCD-chunked remap: XCD x (= bid&7 empirically) owns a contiguous
// logical-tile range -> blocks sharing operand panels are L2-co-resident.
__device__ __forceinline__ int xcd_chunk(int bid, int nwg) {
  int xcd = bid & 7, idx = bid >> 3;
  int q = nwg >> 3, r = nwg & 7;
  int base = xcd < r ? xcd * (q + 1) : r * (q + 1) + (xcd - r) * q;
  return base + idx;
}

// ---------------- fused fp32 -> bf16 conversion (all 6 tensors, 1 launch) ----------
__global__ __launch_bounds__(256) void cvt_all(
    const float* __restrict__ hs, const float* __restrict__ his,
    const float* __restrict__ Wq, const float* __restrict__ Wk,
    const float* __restrict__ Wv, const float* __restrict__ Wo,
    u16* __restrict__ hsb, u16* __restrict__ hib,
    u16* __restrict__ wqb, u16* __restrict__ wkb,
    u16* __restrict__ wvb, u16* __restrict__ wob) {
  // f4-chunk boundaries (all /256 -> block-uniform branch)
  const int N0 = 1198080, N1 = 5990400, N2 = 6580224, N3 = 7170048, N4 = 7759872;
  int i = blockIdx.x * 256 + threadIdx.x;
  const float* s; u16* o; int base;
  if (i < N0)      { s = hs;  o = hsb; base = 0;  }
  else if (i < N1) { s = his; o = hib; base = N0; }
  else if (i < N2) { s = Wq;  o = wqb; base = N1; }
  else if (i < N3) { s = Wk;  o = wkb; base = N2; }
  else if (i < N4) { s = Wv;  o = wvb; base = N3; }
  else             { s = Wo;  o = wob; base = N4; }
  int j = i - base;
  float4 v = ((const float4*)s)[j];
  u16x4 r;
  r.x = f2bf(v.x); r.y = f2bf(v.y); r.z = f2bf(v.z); r.w = f2bf(v.w);
  ((u16x4*)o)[j] = r;
}

// ---------------- GEMM: C[M,1536] = A[M,1536] @ W[1536,1536]^T + bias ----------------
// 1D grid + XCD-chunked swizzle (same-row-panel blocks co-resident per XCD).
template <int OUT, int NBX>  // OUT: 0 = bf16, 1 = f32
__global__ __launch_bounds__(256, 2) void gemm_v2(
    const u16* __restrict__ A, const u16* __restrict__ W,
    const float* __restrict__ bias, void* __restrict__ Cp, int M) {
  const int K = 1536, N = 1536;
  __shared__ __align__(16) u16 gsm[17408];
  u16* As = gsm;
  u16* Bs = gsm + 8192;
  const int tid = threadIdx.x;
  const int lane = tid & 63, wid = tid >> 6;
  const int quad = lane >> 4, l15 = lane & 15;
  const int lg = xcd_chunk(blockIdx.x, gridDim.x);
  const int m0 = (lg / NBX) * 128, n0 = (lg % NBX) * 128;
  const int wm = (wid >> 1) * 64, wn = (wid & 1) * 64;
  f32x4 acc[4][4];
#pragma unroll
  for (int i = 0; i < 4; ++i)
#pragma unroll
    for (int j = 0; j < 4; ++j)
#pragma unroll
      for (int r = 0; r < 4; ++r) acc[i][j][r] = 0.f;

  const int r8 = lane >> 3, c8 = lane & 7;
  const int gch = c8 ^ r8;

  for (int k0 = 0; k0 < K; k0 += 64) {
#pragma unroll
    for (int inst = 0; inst < 4; ++inst) {
      int row = wid * 32 + inst * 8 + r8;
      glds16(A + ((size_t)(m0 + row) * K + k0 + gch * 8), As + (wid * 32 + inst * 8) * 64);
      glds16(W + ((size_t)(n0 + row) * K + k0 + gch * 8), Bs + (wid * 32 + inst * 8) * 64);
    }
    asm volatile("s_waitcnt vmcnt(0)" ::: "memory");
    __syncthreads();
#pragma unroll
    for (int ks = 0; ks < 2; ++ks) {
      u16x8 af[4], bfr[4];
#pragma unroll
      for (int i = 0; i < 4; ++i) {
        int row = wm + i * 16 + l15;
        af[i] = *(const u16x8*)&As[row * 64 + (((ks * 4 + quad) ^ (l15 & 7)) * 8)];
      }
#pragma unroll
      for (int j = 0; j < 4; ++j) {
        int row = wn + j * 16 + l15;
        bfr[j] = *(const u16x8*)&Bs[row * 64 + (((ks * 4 + quad) ^ (l15 & 7)) * 8)];
      }
#pragma unroll
      for (int i = 0; i < 4; ++i)
#pragma unroll
        for (int j = 0; j < 4; ++j) acc[i][j] = mfma16(af[i], bfr[j], acc[i][j]);
    }
    __syncthreads();
  }

#pragma unroll
  for (int i = 0; i < 4; ++i) {
    int row = m0 + wm + i * 16 + quad * 4;
#pragma unroll
    for (int j = 0; j < 4; ++j) {
      int col = n0 + wn + j * 16 + l15;
      float bc = bias[col];
#pragma unroll
      for (int r = 0; r < 4; ++r) {
        if (row + r < M) {
          float v = acc[i][j][r] + bc;
          if (OUT == 1)
            ((float*)Cp)[(size_t)(row + r) * N + col] = v;
          else
            ((u16*)Cp)[(size_t)(row + r) * N + col] = f2bf(v);
        }
      }
    }
  }
}

// ---------------- fused K+V projection GEMM, 256^2 8-phase (T2+T3+T4+T5) ------------
// R10 post-mortem fixes:
//  (1) LDS swizzle was slot = quad ^ (row&3): row&1 (bank half) is implied by row&3,
//      so per-quad reads hit only half the bank groups -> 4-way conflict (11.1M cyc).
//      Now slot = quad ^ ((row>>1)&3): (parity,slot) covers all 8 groups x 2 lanes =
//      2-way = free (m136). Applied on stage-source AND read.
//  (2) vmcnt(4) every phase gave a uniform 2-phase certify lag (~400cy) -- too short
//      for the HBM-streamed A operand (~900cy). Now stage order A0,B0,A1,B1 with
//      vmcnt(4) at ph1/ph3 only: A-halves get 3-phase lag, L2-resident B gets 2.
//      Ledger (loads/wave): ph1 wait certifies {A1(t),B1(t)} (leaves A0,B0 of t+1);
//      ph3 wait certifies {A0(t+1),B0(t+1)} (leaves A1,B1 of t+1). Every certify
//      precedes its read phase by >=1 phase + barrier. Last tile: vmcnt(0) at ph1.
__global__ __launch_bounds__(512, 2) void gemm_kv8(
    const u16* __restrict__ A, const u16* __restrict__ Wkv,
    const float* __restrict__ bk, const float* __restrict__ bv,
    u16* __restrict__ Ck, u16* __restrict__ Vt, int M, int ldt) {
  const int K = 1536, NTK = 24;
  extern __shared__ u16 smem[];  // u16 units: A0@0, A1@16384, B0@32768, B1@49152
  const int tid = threadIdx.x;
  const int lane = tid & 63, wid = tid >> 6;
  const int quad = lane >> 4, l15 = lane & 15;
  const int lg = xcd_chunk(blockIdx.x, gridDim.x);
  const int qtr = lg / 147, rem = lg % 147;   // 147 = 49 m x 3 n per quarter
  const int m0 = (rem / 3) * 256;
  const int nt = qtr * 3 + rem % 3;
  const int n0 = nt * 256;                    // 0..2816
  const int wm = (wid >> 2) * 128, wn = (wid & 3) * 64;

  f32x4 acc[8][4];
#pragma unroll
  for (int i = 0; i < 8; ++i)
#pragma unroll
    for (int j = 0; j < 4; ++j)
#pragma unroll
      for (int r = 0; r < 4; ++r) acc[i][j][r] = 0.f;

  // stage one k-half (256 rows x 32 cols) of A or B: 2 glds16/wave, 32 rows each.
  // LDS slot s of row r holds source col-group s ^ ((r>>1)&3) (matches read swizzle).
  auto stageA = [&](int t, int ks, int buf) {
    u16* dst = smem + buf * 16384 + ks * 8192;
    const int k0 = t * 64 + ks * 32;
#pragma unroll
    for (int n = 0; n < 2; ++n) {
      int rl = n * 128 + wid * 16 + (lane >> 2);
      int grp = (lane & 3) ^ ((rl >> 1) & 3);
      glds16(A + (size_t)(m0 + rl) * K + k0 + grp * 8, dst + (n * 128 + wid * 16) * 32);
    }
  };
  auto stageB = [&](int t, int ks, int buf) {
    u16* dst = smem + 32768 + buf * 16384 + ks * 8192;
    const int k0 = t * 64 + ks * 32;
#pragma unroll
    for (int n = 0; n < 2; ++n) {
      int rl = n * 128 + wid * 16 + (lane >> 2);
      int grp = (lane & 3) ^ ((rl >> 1) & 3);
      glds16(Wkv + (size_t)(n0 + rl) * K + k0 + grp * 8, dst + (n * 128 + wid * 16) * 32);
    }
  };

  // prologue: tile 0 fully into buf 0
  stageA(0, 0, 0); stageB(0, 0, 0); stageA(0, 1, 0); stageB(0, 1, 0);
  asm volatile("s_waitcnt vmcnt(0)" ::: "memory");
  __builtin_amdgcn_s_barrier();

  for (int t = 0; t < NTK; ++t) {
    const int buf = t & 1, nb = buf ^ 1;
    const bool more = (t + 1) < NTK;
    u16* Ab = smem + buf * 16384;
    u16* Bb = smem + 32768 + buf * 16384;
    u16x8 afr[4], bfr[4];
#pragma unroll
    for (int ph = 0; ph < 4; ++ph) {
      const int ks = ph >> 1, ih = ph & 1;
      if (ih == 0) {
#pragma unroll
        for (int j = 0; j < 4; ++j) {
          int row = wn + j * 16 + l15;
          bfr[j] = *(const u16x8*)&Bb[ks * 8192 + row * 32 + ((quad ^ ((row >> 1) & 3)) * 8)];
        }
      }
#pragma unroll
      for (int ii = 0; ii < 4; ++ii) {
        int row = wm + ih * 64 + ii * 16 + l15;
        afr[ii] = *(const u16x8*)&Ab[ks * 8192 + row * 32 + ((quad ^ ((row >> 1) & 3)) * 8)];
      }
      if (more) {
        if (ph == 0) stageA(t + 1, 0, nb);
        else if (ph == 1) stageB(t + 1, 0, nb);
        else if (ph == 2) stageA(t + 1, 1, nb);
        else stageB(t + 1, 1, nb);
      }
      if (ph & 1) {
        if (more) asm volatile("s_waitcnt vmcnt(4)" ::: "memory");
        else      asm volatile("s_waitcnt vmcnt(0)" ::: "memory");
      }
      __builtin_amdgcn_s_barrier();
      asm volatile("s_waitcnt lgkmcnt(0)" ::: "memory");
      __builtin_amdgcn_sched_barrier(0);
      __builtin_amdgcn_s_setprio(1);
#pragma unroll
      for (int ii = 0; ii < 4; ++ii)
#pragma unroll
        for (int j = 0; j < 4; ++j)
          acc[ih * 4 + ii][j] = mfma16(afr[ii], bfr[j], acc[ih * 4 + ii][j]);
      __builtin_amdgcn_s_setprio(0);
      __builtin_amdgcn_s_barrier();
      __builtin_amdgcn_sched_barrier(0);
    }
  }

  if (n0 < 1536) {  // K-projection: direct bf16 stores
#pragma unroll
    for (int i = 0; i < 8; ++i) {
      int row = m0 + wm + i * 16 + quad * 4;
#pragma unroll
      for (int j = 0; j < 4; ++j) {
        int col = n0 + wn + j * 16 + l15;
        float bc = bk[col];
#pragma unroll
        for (int r = 0; r < 4; ++r) {
          if (row + r < M)
            Ck[(size_t)(row + r) * 1536 + col] = f2bf(acc[i][j][r] + bc);
        }
      }
    }
  } else {  // V-projection: transposed store via LDS, two 128-col passes
    const int n0v = n0 - 1536;
    u16* Ct = smem;  // [128 n][264] (+8 pad)
    __syncthreads();
#pragma unroll
    for (int hn = 0; hn < 2; ++hn) {
      if (((wid & 3) >> 1) == hn) {
        int nbase = wn - hn * 128;  // 0 or 64
#pragma unroll
        for (int j = 0; j < 4; ++j) {
          int nloc = nbase + j * 16 + l15;
          float bc = bv[n0v + hn * 128 + nloc];
#pragma unroll
          for (int i = 0; i < 8; ++i) {
            int mloc = wm + i * 16 + quad * 4;
            u16x4 w4;
#pragma unroll
            for (int r = 0; r < 4; ++r) w4[r] = f2bf(acc[i][j][r] + bc);
            *(u16x4*)&Ct[nloc * 264 + mloc] = w4;
          }
        }
      }
      __syncthreads();
#pragma unroll
      for (int e = 0; e < 8; ++e) {
        int idx = e * 512 + tid;  // 128 n x 32 m-chunks
        int n = idx >> 5, mc = idx & 31;
        int mg = m0 + mc * 8;
        if (mg < M) {
          u16x8 v = *(const u16x8*)&Ct[n * 264 + mc * 8];
          *(u16x8*)(Vt + (size_t)(n0v + hn * 128 + n) * ldt + mg) = v;
        }
      }
      __syncthreads();
    }
  }
}

// ---------------- fused RMSNorm + interleaved RoPE, in-place bf16 ----------------
__global__ __launch_bounds__(192) void norm_rope2(u16* __restrict__ X,
                                                  const float* __restrict__ g,
                                                  const float* __restrict__ fc,
                                                  const float* __restrict__ fs,
                                                  float oscale) {
  const int DIMc = 1536;
  int row = blockIdx.x;
  int tid = threadIdx.x;
  u16* xr = X + (size_t)row * DIMc + tid * 8;
  u16x8 v = *(const u16x8*)xr;
  float x[8];
  float ss = 0.f;
#pragma unroll
  for (int e = 0; e < 8; ++e) { x[e] = bf2f(v[e]); ss += x[e] * x[e]; }
#pragma unroll
  for (int m = 1; m < 64; m <<= 1) ss += __shfl_xor(ss, m);
  __shared__ float w3[3];
  if ((tid & 63) == 0) w3[tid >> 6] = ss;
  __syncthreads();
  float rs = rsqrtf((w3[0] + w3[1] + w3[2]) * (1.f / 1536.f) + 1e-5f);
  int dhb = (tid * 8) & 127;
  const float* fcr = fc + (size_t)row * 128 + dhb;
  const float* fsr = fs + (size_t)row * 128 + dhb;
  float4 c0 = *(const float4*)fcr, c1 = *(const float4*)(fcr + 4);
  float4 s0 = *(const float4*)fsr, s1 = *(const float4*)(fsr + 4);
  const float* gp = g + tid * 8;
  float4 g0 = *(const float4*)gp, g1 = *(const float4*)(gp + 4);
  float cosv[4] = {c0.x, c0.z, c1.x, c1.z};
  float sinv[4] = {s0.y, s0.w, s1.y, s1.w};
  float gv[8] = {g0.x, g0.y, g0.z, g0.w, g1.x, g1.y, g1.z, g1.w};
  u16x8 o;
#pragma unroll
  for (int p = 0; p < 4; ++p) {
    float a = x[2 * p] * rs * gv[2 * p];
    float b = x[2 * p + 1] * rs * gv[2 * p + 1];
    o[2 * p] = f2bf((a * cosv[p] - b * sinv[p]) * oscale);
    o[2 * p + 1] = f2bf((a * sinv[p] + b * cosv[p]) * oscale);
  }
  *(u16x8*)xr = o;
}

// ---------------- block-sparse attention v11: t-balanced XCD map ----------------
__global__ __launch_bounds__(256, 3) void attn11(
    const u16* __restrict__ Q, const u16* __restrict__ Kb,
    const u16* __restrict__ VT, const int* __restrict__ sel,
    float* __restrict__ Oacc, float* __restrict__ Lp) {
  const int HWc = 1560, DIMc = 1536, KTt = 12480, NT = 600;
  __shared__ __align__(16) u16 smem[16384];  // Ks0|Ks1|Vt0|Vt1 (8 KB each)
  const int tid = threadIdx.x;
  const int lane = tid & 63, wid = tid >> 6;
  const int quad = lane >> 4, l15 = lane & 15;

  int bid = blockIdx.x;
  int xcd = bid & 7, idx = bid >> 3;
  int il = idx / 13, mt = idx % 13;
  int u = xcd + 8 * (il >> 1);
  const int t = il & 1;
  const int seg = u / 12;
  const int h = u % 12;
  const int m0 = mt * 128;
  const int g = h * 2 + t;

  int s0v = sel[2 * t];
  const int b0 = s0v > 0 ? s0v : 0;
  const int b1 = sel[2 * t + 1];
  const int nk = (b1 >= 0) ? 2 * HWc : HWc;
  const int nch = (nk + 31) >> 5;
  const int cpseg = (nch + 3) >> 2;
  const int c0 = seg * cpseg;
  const int c1 = (c0 + cpseg < nch) ? c0 + cpseg : nch;

  // Q B-frags: this wave's 32 q rows (2 sub-tiles of 16)
  u16x8 qf[2][4];
#pragma unroll
  for (int qt = 0; qt < 2; ++qt) {
    int qrow = m0 + wid * 32 + qt * 16 + l15;
    if (qrow > HWc - 1) qrow = HWc - 1;
    const u16* qp = Q + (size_t)(t * HWc + qrow) * DIMc + h * 128;
#pragma unroll
    for (int ks = 0; ks < 4; ++ks) qf[qt][ks] = *(const u16x8*)(qp + ks * 32 + quad * 8);
  }

  f32x4 oacc[2][8];  // partial O^T: [q-subtile][d-tile]
#pragma unroll
  for (int qt = 0; qt < 2; ++qt)
#pragma unroll
    for (int m = 0; m < 8; ++m)
#pragma unroll
      for (int r = 0; r < 4; ++r) oacc[qt][m][r] = 0.f;
  float lp[2] = {0.f, 0.f};

  auto stage = [&](int kc, int buf) {
    u16* Ks = smem + buf * 4096;
    u16* Vt = smem + 8192 + buf * 4096;
#pragma unroll
    for (int n = 0; n < 2; ++n) {
      int kl = wid * 8 + n * 4 + (lane >> 4);
      int gc = (lane & 15) ^ (kl & 15);
      int kg = kc + kl;
      if (kg >= nk) kg = 0;
      int big = kg >= HWc;
      int tok = (big ? b1 : b0) * HWc + kg - (big ? HWc : 0);
      glds16(Kb + ((size_t)tok * DIMc + h * 128 + gc * 8), Ks + (wid * 8 + n * 4) * 128);
    }
#pragma unroll
    for (int n = 0; n < 2; ++n) {
      int dl = wid * 32 + n * 16 + (lane >> 2);
      int gc = (lane & 3) ^ (dl & 3) ^ ((dl >> 2) & 3);
      int tg = kc + gc * 8;
      if (tg >= nk) tg = 0;
      int big = tg >= HWc;
      int tok = (big ? b1 : b0) * HWc + tg - (big ? HWc : 0);
      glds16(VT + ((size_t)(h * 128 + dl) * KTt + tok), Vt + (wid * 32 + n * 16) * 32);
    }
  };

  if (c0 < c1) stage(c0 * 32, 0);

  for (int c = c0; c < c1; ++c) {
    const int buf = (c - c0) & 1;
    u16* Ks = smem + buf * 4096;
    u16* Vt = smem + 8192 + buf * 4096;
    asm volatile("s_waitcnt vmcnt(0)\n\ts_barrier" ::: "memory");
    if (c + 1 < c1) stage((c + 1) * 32, buf ^ 1);

    f32x4 s[2][2];  // [gg][qt]
#pragma unroll
    for (int gg = 0; gg < 2; ++gg)
#pragma unroll
      for (int qt = 0; qt < 2; ++qt)
#pragma unroll
        for (int r = 0; r < 4; ++r) s[gg][qt][r] = 0.f;
#pragma unroll
    for (int ks = 0; ks < 4; ++ks)
#pragma unroll
      for (int gg = 0; gg < 2; ++gg) {
        u16x8 ka = *(const u16x8*)&Ks[(gg * 16 + l15) * 128 + (((ks * 4 + quad) ^ l15) * 8)];
#pragma unroll
        for (int qt = 0; qt < 2; ++qt) s[gg][qt] = mfma16(ka, qf[qt][ks], s[gg][qt]);
      }

    float p[2][2][4];
#pragma unroll
    for (int gg = 0; gg < 2; ++gg)
#pragma unroll
      for (int qt = 0; qt < 2; ++qt)
#pragma unroll
        for (int r = 0; r < 4; ++r) p[gg][qt][r] = exp2f(s[gg][qt][r]);
    if ((c + 1) * 32 > nk) {  // wave-uniform
#pragma unroll
      for (int gg = 0; gg < 2; ++gg)
#pragma unroll
        for (int r = 0; r < 4; ++r) {
          bool bad = c * 32 + gg * 16 + quad * 4 + r >= nk;
          if (bad) {
#pragma unroll
            for (int qt = 0; qt < 2; ++qt) p[gg][qt][r] = 0.f;
          }
        }
    }
    u16x4 pb[2][2];
#pragma unroll
    for (int gg = 0; gg < 2; ++gg)
#pragma unroll
      for (int qt = 0; qt < 2; ++qt)
#pragma unroll
        for (int r = 0; r < 4; ++r) {
          lp[qt] += p[gg][qt][r];
          pb[gg][qt][r] = f2bf_hw(p[gg][qt][r]);
        }

#pragma unroll
    for (int m = 0; m < 8; ++m) {
      int d = m * 16 + l15;
#pragma unroll
      for (int gg = 0; gg < 2; ++gg) {
        int sl = (gg * 2 + (quad >> 1)) ^ (d & 3) ^ ((d >> 2) & 3);
        u16x4 va = *(const u16x4*)&Vt[d * 32 + sl * 8 + (quad & 1) * 4];
#pragma unroll
        for (int qt = 0; qt < 2; ++qt) oacc[qt][m] = mfma16k16(va, pb[gg][qt], oacc[qt][m]);
      }
    }
  }

#pragma unroll
  for (int qt = 0; qt < 2; ++qt) {
    lp[qt] += __shfl_xor(lp[qt], 16);
    lp[qt] += __shfl_xor(lp[qt], 32);
  }
#pragma unroll
  for (int qt = 0; qt < 2; ++qt) {
    int qrow0 = m0 + wid * 32 + qt * 16;  // wave-uniform
    if (qrow0 < HWc) {
      size_t sb = ((size_t)seg * NT + g * 25 + (qrow0 >> 6)) * 64 + (qrow0 & 63);
      if (lane < 16 && qrow0 + lane < HWc) Lp[sb + lane] = lp[qt];
      if (qrow0 + l15 < HWc) {
#pragma unroll
        for (int m = 0; m < 8; ++m)
          *(f32x4*)&Oacc[(sb + l15) * 128 + m * 16 + quad * 4] = oacc[qt][m];
      }
    }
  }
}

// ---------------- normalize: O = bf16(sum_seg Oacc / sum_seg Lp) ----------------
__global__ __launch_bounds__(256) void attn_norm(const float* __restrict__ Oacc,
                                                 const float* __restrict__ Lp,
                                                 u16* __restrict__ O) {
  const int HWc = 1560, DIMc = 1536, NT = 600;
  int tile = blockIdx.x;  // 600
  int g = tile / 25, mt = tile % 25;
  int h = g >> 1, t = g & 1;
  int m0 = mt * 64;
  int tid = threadIdx.x;
#pragma unroll
  for (int e = 0; e < 8; ++e) {
    int idx = e * 256 + tid;   // 0..2047 f32x4 slots (64 q x 32)
    int qloc = idx >> 5;
    int d4 = (idx & 31) * 4;
    int q = m0 + qloc;
    if (q < HWc) {
      f32x4 a = {0.f, 0.f, 0.f, 0.f};
      float l = 0.f;
#pragma unroll
      for (int s = 0; s < 4; ++s) {
        const size_t sbase = ((size_t)s * NT + tile) * 64 + qloc;
        f32x4 v = *(const f32x4*)&Oacc[sbase * 128 + d4];
#pragma unroll
        for (int r = 0; r < 4; ++r) a[r] += v[r];
        l += Lp[sbase];
      }
      float linv = 1.f / l;
      u16x4 o;
#pragma unroll
      for (int r = 0; r < 4; ++r) o[r] = f2bf(a[r] * linv);
      *(u16x4*)(O + (size_t)(t * HWc + q) * DIMc + h * 128 + d4) = o;
    }
  }
}

extern "C" void kernel_launch(void* const* d_in, const int* in_sizes, int n_in,
                              void* d_out, int out_size, void* d_ws, size_t ws_size,
                              hipStream_t stream) {
  const float* hs  = (const float*)d_in[0];
  const float* his = (const float*)d_in[1];
  const float* fc  = (const float*)d_in[2];
  const float* fs  = (const float*)d_in[3];
  const float* fch = (const float*)d_in[4];
  const float* fsh = (const float*)d_in[5];
  const int*   sel = (const int*)d_in[6];
  const float* Wq  = (const float*)d_in[7];
  const float* bq  = (const float*)d_in[8];
  const float* Wk  = (const float*)d_in[9];
  const float* bk  = (const float*)d_in[10];
  const float* Wv  = (const float*)d_in[11];
  const float* bv  = (const float*)d_in[12];
  const float* Wo  = (const float*)d_in[13];
  const float* bo  = (const float*)d_in[14];
  const float* gq  = (const float*)d_in[15];
  const float* gk  = (const float*)d_in[16];

  const int QT = 3120, KT = 12480, DIMc = 1536;
  u16* p = (u16*)d_ws;
  u16* qb  = p; p += (size_t)QT * DIMc;
  u16* kb2 = p; p += (size_t)KT * DIMc;
  u16* vt  = p; p += (size_t)DIMc * KT;   // V^T [1536][12480]
  u16* ab  = p; p += (size_t)QT * DIMc;
  u16* wob = p; p += (size_t)DIMc * DIMc;
  u16* scratch = p;
  u16* hsb = scratch;
  u16* hib = hsb + (size_t)QT * DIMc;
  u16* wqb = hib + (size_t)KT * DIMc;
  u16* wkb = wqb + (size_t)DIMc * DIMc;   // wkb and wvb adjacent -> stacked [3072][1536]
  u16* wvb = wkb + (size_t)DIMc * DIMc;
  float* oaccb = (float*)scratch;                      // f32 [4][600][64][128]
  float* lpb   = oaccb + (size_t)4 * 600 * 64 * 128;   // f32 [4][600][64]

  cvt_all<<<dim3(32616), 256, 0, stream>>>(hs, his, Wq, Wk, Wv, Wo,
                                           hsb, hib, wqb, wkb, wvb, wob);

  gemm_v2<0, 12><<<dim3(300), 256, 0, stream>>>(hsb, wqb, bq, qb, QT);
  gemm_kv8<<<dim3(588), 512, 131072, stream>>>(hib, wkb, bk, bv, kb2, vt, KT, KT);

  const float qscale = (float)(0.08838834764831845 * 1.4426950408889634);
  norm_rope2<<<dim3(QT), 192, 0, stream>>>(qb, gq, fc, fs, qscale);
  norm_rope2<<<dim3(KT), 192, 0, stream>>>(kb2, gk, fch, fsh, 1.0f);

  // attn11 clobbers hsb/hib/wq/wk/wv (all dead by now); wob stays live for the final gemm.
  attn11<<<dim3(1248), 256, 0, stream>>>(qb, kb2, vt, sel, oaccb, lpb);
  attn_norm<<<dim3(600), 256, 0, stream>>>(oaccb, lpb, ab);

  gemm_v2<1, 12><<<dim3(300), 256, 0, stream>>>(ab, wob, bo, d_out, QT);
}

// Round 12
// 557.280 us; speedup vs baseline: 1.0555x; 1.0386x over previous
//
#include <hip/hip_runtime.h>

typedef unsigned short u16;
typedef __attribute__((ext_vector_type(4))) unsigned short u16x4;
typedef __attribute__((ext_vector_type(8))) unsigned short u16x8;
typedef __attribute__((ext_vector_type(4))) short s16x4;
typedef __attribute__((ext_vector_type(4))) float f32x4;
typedef __attribute__((ext_vector_type(8))) __bf16 bf16x8;

__device__ __forceinline__ u16 f2bf(float f) {
  union { float f; unsigned int u; } v; v.f = f;
  unsigned int u = v.u;
  unsigned int r = (u + 0x7fffu + ((u >> 16) & 1u)) >> 16;
  return (u16)r;
}
__device__ __forceinline__ u16 f2bf_hw(float f) {  // RNE via HW convert
  return __builtin_bit_cast(u16, (__bf16)f);
}
__device__ __forceinline__ float bf2f(u16 h) {
  union { unsigned int u; float f; } v; v.u = ((unsigned int)h) << 16;
  return v.f;
}
__device__ __forceinline__ f32x4 mfma16(u16x8 a, u16x8 b, f32x4 c) {
  return __builtin_amdgcn_mfma_f32_16x16x32_bf16(
      __builtin_bit_cast(bf16x8, a), __builtin_bit_cast(bf16x8, b), c, 0, 0, 0);
}
// K=16 variant: A/B are 4 bf16 (2 VGPRs)
__device__ __forceinline__ f32x4 mfma16k16(u16x4 a, u16x4 b, f32x4 c) {
  return __builtin_amdgcn_mfma_f32_16x16x16bf16_1k(
      __builtin_bit_cast(s16x4, a), __builtin_bit_cast(s16x4, b), c, 0, 0, 0);
}
// async global->LDS, 16B per lane; LDS dest = wave-uniform base + lane*16
__device__ __forceinline__ void glds16(const void* g, void* l) {
  __builtin_amdgcn_global_load_lds((const __attribute__((address_space(1))) void*)g,
                                   (__attribute__((address_space(3))) void*)l, 16, 0, 0);
}
// bijective XCD-chunked remap: XCD x (= bid&7 empirically) owns a contiguous
// logical-tile range -> blocks sharing operand panels are L2-co-resident.
__device__ __forceinline__ int xcd_chunk(int bid, int nwg) {
  int xcd = bid & 7, idx = bid >> 3;
  int q = nwg >> 3, r = nwg & 7;
  int base = xcd < r ? xcd * (q + 1) : r * (q + 1) + (xcd - r) * q;
  return base + idx;
}

// ---------------- fused fp32 -> bf16 conversion (all 6 tensors, 1 launch) ----------
__global__ __launch_bounds__(256) void cvt_all(
    const float* __restrict__ hs, const float* __restrict__ his,
    const float* __restrict__ Wq, const float* __restrict__ Wk,
    const float* __restrict__ Wv, const float* __restrict__ Wo,
    u16* __restrict__ hsb, u16* __restrict__ hib,
    u16* __restrict__ wqb, u16* __restrict__ wkb,
    u16* __restrict__ wvb, u16* __restrict__ wob) {
  // f4-chunk boundaries (all /256 -> block-uniform branch)
  const int N0 = 1198080, N1 = 5990400, N2 = 6580224, N3 = 7170048, N4 = 7759872;
  int i = blockIdx.x * 256 + threadIdx.x;
  const float* s; u16* o; int base;
  if (i < N0)      { s = hs;  o = hsb; base = 0;  }
  else if (i < N1) { s = his; o = hib; base = N0; }
  else if (i < N2) { s = Wq;  o = wqb; base = N1; }
  else if (i < N3) { s = Wk;  o = wkb; base = N2; }
  else if (i < N4) { s = Wv;  o = wvb; base = N3; }
  else             { s = Wo;  o = wob; base = N4; }
  int j = i - base;
  float4 v = ((const float4*)s)[j];
  u16x4 r;
  r.x = f2bf(v.x); r.y = f2bf(v.y); r.z = f2bf(v.z); r.w = f2bf(v.w);
  ((u16x4*)o)[j] = r;
}

// ---------------- GEMM: C[M,1536] = A[M,1536] @ W[1536,1536]^T + bias ----------------
// 1D grid + XCD-chunked swizzle (same-row-panel blocks co-resident per XCD).
template <int OUT, int NBX>  // OUT: 0 = bf16, 1 = f32
__global__ __launch_bounds__(256, 2) void gemm_v2(
    const u16* __restrict__ A, const u16* __restrict__ W,
    const float* __restrict__ bias, void* __restrict__ Cp, int M) {
  const int K = 1536, N = 1536;
  __shared__ __align__(16) u16 gsm[17408];
  u16* As = gsm;
  u16* Bs = gsm + 8192;
  const int tid = threadIdx.x;
  const int lane = tid & 63, wid = tid >> 6;
  const int quad = lane >> 4, l15 = lane & 15;
  const int lg = xcd_chunk(blockIdx.x, gridDim.x);
  const int m0 = (lg / NBX) * 128, n0 = (lg % NBX) * 128;
  const int wm = (wid >> 1) * 64, wn = (wid & 1) * 64;
  f32x4 acc[4][4];
#pragma unroll
  for (int i = 0; i < 4; ++i)
#pragma unroll
    for (int j = 0; j < 4; ++j)
#pragma unroll
      for (int r = 0; r < 4; ++r) acc[i][j][r] = 0.f;

  const int r8 = lane >> 3, c8 = lane & 7;
  const int gch = c8 ^ r8;

  for (int k0 = 0; k0 < K; k0 += 64) {
#pragma unroll
    for (int inst = 0; inst < 4; ++inst) {
      int row = wid * 32 + inst * 8 + r8;
      glds16(A + ((size_t)(m0 + row) * K + k0 + gch * 8), As + (wid * 32 + inst * 8) * 64);
      glds16(W + ((size_t)(n0 + row) * K + k0 + gch * 8), Bs + (wid * 32 + inst * 8) * 64);
    }
    asm volatile("s_waitcnt vmcnt(0)" ::: "memory");
    __syncthreads();
#pragma unroll
    for (int ks = 0; ks < 2; ++ks) {
      u16x8 af[4], bfr[4];
#pragma unroll
      for (int i = 0; i < 4; ++i) {
        int row = wm + i * 16 + l15;
        af[i] = *(const u16x8*)&As[row * 64 + (((ks * 4 + quad) ^ (l15 & 7)) * 8)];
      }
#pragma unroll
      for (int j = 0; j < 4; ++j) {
        int row = wn + j * 16 + l15;
        bfr[j] = *(const u16x8*)&Bs[row * 64 + (((ks * 4 + quad) ^ (l15 & 7)) * 8)];
      }
#pragma unroll
      for (int i = 0; i < 4; ++i)
#pragma unroll
        for (int j = 0; j < 4; ++j) acc[i][j] = mfma16(af[i], bfr[j], acc[i][j]);
    }
    __syncthreads();
  }

#pragma unroll
  for (int i = 0; i < 4; ++i) {
    int row = m0 + wm + i * 16 + quad * 4;
#pragma unroll
    for (int j = 0; j < 4; ++j) {
      int col = n0 + wn + j * 16 + l15;
      float bc = bias[col];
#pragma unroll
      for (int r = 0; r < 4; ++r) {
        if (row + r < M) {
          float v = acc[i][j][r] + bc;
          if (OUT == 1)
            ((float*)Cp)[(size_t)(row + r) * N + col] = v;
          else
            ((u16*)Cp)[(size_t)(row + r) * N + col] = f2bf(v);
        }
      }
    }
  }
}

// ---------------- fused K+V projection GEMM (stacked [3072][1536] weights) ----------
// PROVEN 2-phase structure (R8: 132 us, MfmaUtil 41%). 8-phase port (R10/R11)
// stayed at 178-188 us -- reverted per pre-commitment. n-quartered XCD ordering:
// lg -> (qtr = lg/588, m = (lg%588)/6, n = qtr*6 + lg%6). Each XCD owns 49 m x 6 n:
// W slice 2.36 MB stays L2-resident while A streams once per quarter.
__global__ __launch_bounds__(256, 2) void gemm_kv(
    const u16* __restrict__ A, const u16* __restrict__ Wkv,
    const float* __restrict__ bk, const float* __restrict__ bv,
    u16* __restrict__ Ck, u16* __restrict__ Vt, int M, int ldt) {
  const int K = 1536;
  __shared__ __align__(16) u16 gsm[17408];
  u16* As = gsm;
  u16* Bs = gsm + 8192;
  const int tid = threadIdx.x;
  const int lane = tid & 63, wid = tid >> 6;
  const int quad = lane >> 4, l15 = lane & 15;
  const int lg = xcd_chunk(blockIdx.x, gridDim.x);
  const int qtr = lg / 588;       // 588 = 98 m x 6 n
  const int rem = lg % 588;
  const int m0 = (rem / 6) * 128;
  const int n0 = (qtr * 6 + rem % 6) * 128;  // 0..2944
  const int wm = (wid >> 1) * 64, wn = (wid & 1) * 64;
  f32x4 acc[4][4];
#pragma unroll
  for (int i = 0; i < 4; ++i)
#pragma unroll
    for (int j = 0; j < 4; ++j)
#pragma unroll
      for (int r = 0; r < 4; ++r) acc[i][j][r] = 0.f;

  const int r8 = lane >> 3, c8 = lane & 7;
  const int gch = c8 ^ r8;

  for (int k0 = 0; k0 < K; k0 += 64) {
#pragma unroll
    for (int inst = 0; inst < 4; ++inst) {
      int row = wid * 32 + inst * 8 + r8;
      glds16(A + ((size_t)(m0 + row) * K + k0 + gch * 8), As + (wid * 32 + inst * 8) * 64);
      glds16(Wkv + ((size_t)(n0 + row) * K + k0 + gch * 8), Bs + (wid * 32 + inst * 8) * 64);
    }
    asm volatile("s_waitcnt vmcnt(0)" ::: "memory");
    __syncthreads();
#pragma unroll
    for (int ks = 0; ks < 2; ++ks) {
      u16x8 af[4], bfr[4];
#pragma unroll
      for (int i = 0; i < 4; ++i) {
        int row = wm + i * 16 + l15;
        af[i] = *(const u16x8*)&As[row * 64 + (((ks * 4 + quad) ^ (l15 & 7)) * 8)];
      }
#pragma unroll
      for (int j = 0; j < 4; ++j) {
        int row = wn + j * 16 + l15;
        bfr[j] = *(const u16x8*)&Bs[row * 64 + (((ks * 4 + quad) ^ (l15 & 7)) * 8)];
      }
#pragma unroll
      for (int i = 0; i < 4; ++i)
#pragma unroll
        for (int j = 0; j < 4; ++j) acc[i][j] = mfma16(af[i], bfr[j], acc[i][j]);
    }
    __syncthreads();
  }

  if (n0 < 1536) {  // K-projection: plain bf16 store
#pragma unroll
    for (int i = 0; i < 4; ++i) {
      int row = m0 + wm + i * 16 + quad * 4;
#pragma unroll
      for (int j = 0; j < 4; ++j) {
        int col = n0 + wn + j * 16 + l15;
        float bc = bk[col];
#pragma unroll
        for (int r = 0; r < 4; ++r) {
          if (row + r < M)
            Ck[(size_t)(row + r) * 1536 + col] = f2bf(acc[i][j][r] + bc);
        }
      }
    }
  } else {  // V-projection: transposed store via LDS
    const int n0v = n0 - 1536;
    u16* Ct = gsm;  // [128 n][136]
#pragma unroll
    for (int i = 0; i < 4; ++i)
#pragma unroll
      for (int j = 0; j < 4; ++j) {
        int nloc = wn + j * 16 + l15;
        float bc = bv[n0v + nloc];
#pragma unroll
        for (int r = 0; r < 4; ++r) {
          int mloc = wm + i * 16 + quad * 4 + r;
          Ct[nloc * 136 + mloc] = f2bf(acc[i][j][r] + bc);
        }
      }
    __syncthreads();
    int n = tid >> 1, half = tid & 1;
#pragma unroll
    for (int e = 0; e < 8; ++e) {
      int mloc = half * 64 + e * 8;
      if (m0 + mloc < M) {
        u16x8 v = *(const u16x8*)&Ct[n * 136 + mloc];
        *(u16x8*)(Vt + (size_t)(n0v + n) * ldt + m0 + mloc) = v;
      }
    }
  }
}

// ---------------- fused RMSNorm + interleaved RoPE, in-place bf16 ----------------
__global__ __launch_bounds__(192) void norm_rope2(u16* __restrict__ X,
                                                  const float* __restrict__ g,
                                                  const float* __restrict__ fc,
                                                  const float* __restrict__ fs,
                                                  float oscale) {
  const int DIMc = 1536;
  int row = blockIdx.x;
  int tid = threadIdx.x;
  u16* xr = X + (size_t)row * DIMc + tid * 8;
  u16x8 v = *(const u16x8*)xr;
  float x[8];
  float ss = 0.f;
#pragma unroll
  for (int e = 0; e < 8; ++e) { x[e] = bf2f(v[e]); ss += x[e] * x[e]; }
#pragma unroll
  for (int m = 1; m < 64; m <<= 1) ss += __shfl_xor(ss, m);
  __shared__ float w3[3];
  if ((tid & 63) == 0) w3[tid >> 6] = ss;
  __syncthreads();
  float rs = rsqrtf((w3[0] + w3[1] + w3[2]) * (1.f / 1536.f) + 1e-5f);
  int dhb = (tid * 8) & 127;
  const float* fcr = fc + (size_t)row * 128 + dhb;
  const float* fsr = fs + (size_t)row * 128 + dhb;
  float4 c0 = *(const float4*)fcr, c1 = *(const float4*)(fcr + 4);
  float4 s0 = *(const float4*)fsr, s1 = *(const float4*)(fsr + 4);
  const float* gp = g + tid * 8;
  float4 g0 = *(const float4*)gp, g1 = *(const float4*)(gp + 4);
  float cosv[4] = {c0.x, c0.z, c1.x, c1.z};
  float sinv[4] = {s0.y, s0.w, s1.y, s1.w};
  float gv[8] = {g0.x, g0.y, g0.z, g0.w, g1.x, g1.y, g1.z, g1.w};
  u16x8 o;
#pragma unroll
  for (int p = 0; p < 4; ++p) {
    float a = x[2 * p] * rs * gv[2 * p];
    float b = x[2 * p + 1] * rs * gv[2 * p + 1];
    o[2 * p] = f2bf((a * cosv[p] - b * sinv[p]) * oscale);
    o[2 * p + 1] = f2bf((a * sinv[p] + b * cosv[p]) * oscale);
  }
  *(u16x8*)xr = o;
}

// ---------------- block-sparse attention v12: unit-interleaved CU balance ----------
// Same compute core as v11. Decode change: mt = idx/12, il = idx%12 (was il=idx/13,
// mt=idx%13). Consecutive bids now cycle through all 12 (h,seg,t) units of an XCD
// before advancing mt, so each CU's ~5 resident blocks mix long (25-chunk) and short
// (13-chunk) units instead of all sharing one length -> CU drain times equalize
// (v11: whole CUs idled after 13 chunks while others ran 25; occupancy 19.8%).
// L2 locality unaffected: all 12 units still live on the same XCD's L2.
__global__ __launch_bounds__(256, 3) void attn12(
    const u16* __restrict__ Q, const u16* __restrict__ Kb,
    const u16* __restrict__ VT, const int* __restrict__ sel,
    float* __restrict__ Oacc, float* __restrict__ Lp) {
  const int HWc = 1560, DIMc = 1536, KTt = 12480, NT = 600;
  __shared__ __align__(16) u16 smem[16384];  // Ks0|Ks1|Vt0|Vt1 (8 KB each)
  const int tid = threadIdx.x;
  const int lane = tid & 63, wid = tid >> 6;
  const int quad = lane >> 4, l15 = lane & 15;

  int bid = blockIdx.x;
  int xcd = bid & 7, idx = bid >> 3;
  int mt = idx / 12, il = idx % 12;   // unit-interleaved (v11: il=idx/13, mt=idx%13)
  int u = xcd + 8 * (il >> 1);
  const int t = il & 1;
  const int seg = u / 12;
  const int h = u % 12;
  const int m0 = mt * 128;
  const int g = h * 2 + t;

  int s0v = sel[2 * t];
  const int b0 = s0v > 0 ? s0v : 0;
  const int b1 = sel[2 * t + 1];
  const int nk = (b1 >= 0) ? 2 * HWc : HWc;
  const int nch = (nk + 31) >> 5;
  const int cpseg = (nch + 3) >> 2;
  const int c0 = seg * cpseg;
  const int c1 = (c0 + cpseg < nch) ? c0 + cpseg : nch;

  // Q B-frags: this wave's 32 q rows (2 sub-tiles of 16)
  u16x8 qf[2][4];
#pragma unroll
  for (int qt = 0; qt < 2; ++qt) {
    int qrow = m0 + wid * 32 + qt * 16 + l15;
    if (qrow > HWc - 1) qrow = HWc - 1;
    const u16* qp = Q + (size_t)(t * HWc + qrow) * DIMc + h * 128;
#pragma unroll
    for (int ks = 0; ks < 4; ++ks) qf[qt][ks] = *(const u16x8*)(qp + ks * 32 + quad * 8);
  }

  f32x4 oacc[2][8];  // partial O^T: [q-subtile][d-tile]
#pragma unroll
  for (int qt = 0; qt < 2; ++qt)
#pragma unroll
    for (int m = 0; m < 8; ++m)
#pragma unroll
      for (int r = 0; r < 4; ++r) oacc[qt][m][r] = 0.f;
  float lp[2] = {0.f, 0.f};

  auto stage = [&](int kc, int buf) {
    u16* Ks = smem + buf * 4096;
    u16* Vt = smem + 8192 + buf * 4096;
#pragma unroll
    for (int n = 0; n < 2; ++n) {
      int kl = wid * 8 + n * 4 + (lane >> 4);
      int gc = (lane & 15) ^ (kl & 15);
      int kg = kc + kl;
      if (kg >= nk) kg = 0;
      int big = kg >= HWc;
      int tok = (big ? b1 : b0) * HWc + kg - (big ? HWc : 0);
      glds16(Kb + ((size_t)tok * DIMc + h * 128 + gc * 8), Ks + (wid * 8 + n * 4) * 128);
    }
#pragma unroll
    for (int n = 0; n < 2; ++n) {
      int dl = wid * 32 + n * 16 + (lane >> 2);
      int gc = (lane & 3) ^ (dl & 3) ^ ((dl >> 2) & 3);
      int tg = kc + gc * 8;
      if (tg >= nk) tg = 0;
      int big = tg >= HWc;
      int tok = (big ? b1 : b0) * HWc + tg - (big ? HWc : 0);
      glds16(VT + ((size_t)(h * 128 + dl) * KTt + tok), Vt + (wid * 32 + n * 16) * 32);
    }
  };

  if (c0 < c1) stage(c0 * 32, 0);

  for (int c = c0; c < c1; ++c) {
    const int buf = (c - c0) & 1;
    u16* Ks = smem + buf * 4096;
    u16* Vt = smem + 8192 + buf * 4096;
    asm volatile("s_waitcnt vmcnt(0)\n\ts_barrier" ::: "memory");
    if (c + 1 < c1) stage((c + 1) * 32, buf ^ 1);

    f32x4 s[2][2];  // [gg][qt]
#pragma unroll
    for (int gg = 0; gg < 2; ++gg)
#pragma unroll
      for (int qt = 0; qt < 2; ++qt)
#pragma unroll
        for (int r = 0; r < 4; ++r) s[gg][qt][r] = 0.f;
#pragma unroll
    for (int ks = 0; ks < 4; ++ks)
#pragma unroll
      for (int gg = 0; gg < 2; ++gg) {
        u16x8 ka = *(const u16x8*)&Ks[(gg * 16 + l15) * 128 + (((ks * 4 + quad) ^ l15) * 8)];
#pragma unroll
        for (int qt = 0; qt < 2; ++qt) s[gg][qt] = mfma16(ka, qf[qt][ks], s[gg][qt]);
      }

    float p[2][2][4];
#pragma unroll
    for (int gg = 0; gg < 2; ++gg)
#pragma unroll
      for (int qt = 0; qt < 2; ++qt)
#pragma unroll
        for (int r = 0; r < 4; ++r) p[gg][qt][r] = exp2f(s[gg][qt][r]);
    if ((c + 1) * 32 > nk) {  // wave-uniform
#pragma unroll
      for (int gg = 0; gg < 2; ++gg)
#pragma unroll
        for (int r = 0; r < 4; ++r) {
          bool bad = c * 32 + gg * 16 + quad * 4 + r >= nk;
          if (bad) {
#pragma unroll
            for (int qt = 0; qt < 2; ++qt) p[gg][qt][r] = 0.f;
          }
        }
    }
    u16x4 pb[2][2];
#pragma unroll
    for (int gg = 0; gg < 2; ++gg)
#pragma unroll
      for (int qt = 0; qt < 2; ++qt)
#pragma unroll
        for (int r = 0; r < 4; ++r) {
          lp[qt] += p[gg][qt][r];
          pb[gg][qt][r] = f2bf_hw(p[gg][qt][r]);
        }

#pragma unroll
    for (int m = 0; m < 8; ++m) {
      int d = m * 16 + l15;
#pragma unroll
      for (int gg = 0; gg < 2; ++gg) {
        int sl = (gg * 2 + (quad >> 1)) ^ (d & 3) ^ ((d >> 2) & 3);
        u16x4 va = *(const u16x4*)&Vt[d * 32 + sl * 8 + (quad & 1) * 4];
#pragma unroll
        for (int qt = 0; qt < 2; ++qt) oacc[qt][m] = mfma16k16(va, pb[gg][qt], oacc[qt][m]);
      }
    }
  }

#pragma unroll
  for (int qt = 0; qt < 2; ++qt) {
    lp[qt] += __shfl_xor(lp[qt], 16);
    lp[qt] += __shfl_xor(lp[qt], 32);
  }
#pragma unroll
  for (int qt = 0; qt < 2; ++qt) {
    int qrow0 = m0 + wid * 32 + qt * 16;  // wave-uniform
    if (qrow0 < HWc) {
      size_t sb = ((size_t)seg * NT + g * 25 + (qrow0 >> 6)) * 64 + (qrow0 & 63);
      if (lane < 16 && qrow0 + lane < HWc) Lp[sb + lane] = lp[qt];
      if (qrow0 + l15 < HWc) {
#pragma unroll
        for (int m = 0; m < 8; ++m)
          *(f32x4*)&Oacc[(sb + l15) * 128 + m * 16 + quad * 4] = oacc[qt][m];
      }
    }
  }
}

// ---------------- normalize: O = bf16(sum_seg Oacc / sum_seg Lp) ----------------
__global__ __launch_bounds__(256) void attn_norm(const float* __restrict__ Oacc,
                                                 const float* __restrict__ Lp,
                                                 u16* __restrict__ O) {
  const int HWc = 1560, DIMc = 1536, NT = 600;
  int tile = blockIdx.x;  // 600
  int g = tile / 25, mt = tile % 25;
  int h = g >> 1, t = g & 1;
  int m0 = mt * 64;
  int tid = threadIdx.x;
#pragma unroll
  for (int e = 0; e < 8; ++e) {
    int idx = e * 256 + tid;   // 0..2047 f32x4 slots (64 q x 32)
    int qloc = idx >> 5;
    int d4 = (idx & 31) * 4;
    int q = m0 + qloc;
    if (q < HWc) {
      f32x4 a = {0.f, 0.f, 0.f, 0.f};
      float l = 0.f;
#pragma unroll
      for (int s = 0; s < 4; ++s) {
        const size_t sbase = ((size_t)s * NT + tile) * 64 + qloc;
        f32x4 v = *(const f32x4*)&Oacc[sbase * 128 + d4];
#pragma unroll
        for (int r = 0; r < 4; ++r) a[r] += v[r];
        l += Lp[sbase];
      }
      float linv = 1.f / l;
      u16x4 o;
#pragma unroll
      for (int r = 0; r < 4; ++r) o[r] = f2bf(a[r] * linv);
      *(u16x4*)(O + (size_t)(t * HWc + q) * DIMc + h * 128 + d4) = o;
    }
  }
}

extern "C" void kernel_launch(void* const* d_in, const int* in_sizes, int n_in,
                              void* d_out, int out_size, void* d_ws, size_t ws_size,
                              hipStream_t stream) {
  const float* hs  = (const float*)d_in[0];
  const float* his = (const float*)d_in[1];
  const float* fc  = (const float*)d_in[2];
  const float* fs  = (const float*)d_in[3];
  const float* fch = (const float*)d_in[4];
  const float* fsh = (const float*)d_in[5];
  const int*   sel = (const int*)d_in[6];
  const float* Wq  = (const float*)d_in[7];
  const float* bq  = (const float*)d_in[8];
  const float* Wk  = (const float*)d_in[9];
  const float* bk  = (const float*)d_in[10];
  const float* Wv  = (const float*)d_in[11];
  const float* bv  = (const float*)d_in[12];
  const float* Wo  = (const float*)d_in[13];
  const float* bo  = (const float*)d_in[14];
  const float* gq  = (const float*)d_in[15];
  const float* gk  = (const float*)d_in[16];

  const int QT = 3120, KT = 12480, DIMc = 1536;
  u16* p = (u16*)d_ws;
  u16* qb  = p; p += (size_t)QT * DIMc;
  u16* kb2 = p; p += (size_t)KT * DIMc;
  u16* vt  = p; p += (size_t)DIMc * KT;   // V^T [1536][12480]
  u16* ab  = p; p += (size_t)QT * DIMc;
  u16* wob = p; p += (size_t)DIMc * DIMc;
  u16* scratch = p;
  u16* hsb = scratch;
  u16* hib = hsb + (size_t)QT * DIMc;
  u16* wqb = hib + (size_t)KT * DIMc;
  u16* wkb = wqb + (size_t)DIMc * DIMc;   // wkb and wvb adjacent -> stacked [3072][1536]
  u16* wvb = wkb + (size_t)DIMc * DIMc;
  float* oaccb = (float*)scratch;                      // f32 [4][600][64][128]
  float* lpb   = oaccb + (size_t)4 * 600 * 64 * 128;   // f32 [4][600][64]

  cvt_all<<<dim3(32616), 256, 0, stream>>>(hs, his, Wq, Wk, Wv, Wo,
                                           hsb, hib, wqb, wkb, wvb, wob);

  gemm_v2<0, 12><<<dim3(300), 256, 0, stream>>>(hsb, wqb, bq, qb, QT);
  gemm_kv<<<dim3(2352), 256, 0, stream>>>(hib, wkb, bk, bv, kb2, vt, KT, KT);

  const float qscale = (float)(0.08838834764831845 * 1.4426950408889634);
  norm_rope2<<<dim3(QT), 192, 0, stream>>>(qb, gq, fc, fs, qscale);
  norm_rope2<<<dim3(KT), 192, 0, stream>>>(kb2, gk, fch, fsh, 1.0f);

  // attn12 clobbers hsb/hib/wq/wk/wv (all dead by now); wob stays live for the final gemm.
  attn12<<<dim3(1248), 256, 0, stream>>>(qb, kb2, vt, sel, oaccb, lpb);
  attn_norm<<<dim3(600), 256, 0, stream>>>(oaccb, lpb, ab);

  gemm_v2<1, 12><<<dim3(300), 256, 0, stream>>>(ab, wob, bo, d_out, QT);
}

// Round 13
// 471.517 us; speedup vs baseline: 1.2475x; 1.1819x over previous
//
#include <hip/hip_runtime.h>

typedef unsigned short u16;
typedef __attribute__((ext_vector_type(4))) unsigned short u16x4;
typedef __attribute__((ext_vector_type(8))) unsigned short u16x8;
typedef __attribute__((ext_vector_type(4))) short s16x4;
typedef __attribute__((ext_vector_type(4))) float f32x4;
typedef __attribute__((ext_vector_type(8))) __bf16 bf16x8;

__device__ __forceinline__ u16 f2bf(float f) {
  union { float f; unsigned int u; } v; v.f = f;
  unsigned int u = v.u;
  unsigned int r = (u + 0x7fffu + ((u >> 16) & 1u)) >> 16;
  return (u16)r;
}
__device__ __forceinline__ u16 f2bf_hw(float f) {  // RNE via HW convert
  return __builtin_bit_cast(u16, (__bf16)f);
}
__device__ __forceinline__ float bf2f(u16 h) {
  union { unsigned int u; float f; } v; v.u = ((unsigned int)h) << 16;
  return v.f;
}
__device__ __forceinline__ f32x4 mfma16(u16x8 a, u16x8 b, f32x4 c) {
  return __builtin_amdgcn_mfma_f32_16x16x32_bf16(
      __builtin_bit_cast(bf16x8, a), __builtin_bit_cast(bf16x8, b), c, 0, 0, 0);
}
// K=16 variant: A/B are 4 bf16 (2 VGPRs)
__device__ __forceinline__ f32x4 mfma16k16(u16x4 a, u16x4 b, f32x4 c) {
  return __builtin_amdgcn_mfma_f32_16x16x16bf16_1k(
      __builtin_bit_cast(s16x4, a), __builtin_bit_cast(s16x4, b), c, 0, 0, 0);
}
// async global->LDS, 16B per lane; LDS dest = wave-uniform base + lane*16
__device__ __forceinline__ void glds16(const void* g, void* l) {
  __builtin_amdgcn_global_load_lds((const __attribute__((address_space(1))) void*)g,
                                   (__attribute__((address_space(3))) void*)l, 16, 0, 0);
}
// bijective XCD-chunked remap: XCD x (= bid&7 empirically) owns a contiguous
// logical-tile range -> blocks sharing operand panels are L2-co-resident.
__device__ __forceinline__ int xcd_chunk(int bid, int nwg) {
  int xcd = bid & 7, idx = bid >> 3;
  int q = nwg >> 3, r = nwg & 7;
  int base = xcd < r ? xcd * (q + 1) : r * (q + 1) + (xcd - r) * q;
  return base + idx;
}
// selected token-block mask from sel[4]: {clip(b0), b1 if >=0} per t.
// Exactly the token-blocks the attention kernel reads.
__device__ __forceinline__ int sel_mask(const int* __restrict__ sel) {
  int m = 0;
#pragma unroll
  for (int tt = 0; tt < 2; ++tt) {
    int a = sel[2 * tt];
    if (a < 0) a = 0;
    m |= 1 << a;
    int b = sel[2 * tt + 1];
    if (b >= 0) m |= 1 << b;
  }
  return m;
}

// ---------------- fused fp32 -> bf16 conversion (all 6 tensors, 1 launch) ----------
__global__ __launch_bounds__(256) void cvt_all(
    const float* __restrict__ hs, const float* __restrict__ his,
    const float* __restrict__ Wq, const float* __restrict__ Wk,
    const float* __restrict__ Wv, const float* __restrict__ Wo,
    u16* __restrict__ hsb, u16* __restrict__ hib,
    u16* __restrict__ wqb, u16* __restrict__ wkb,
    u16* __restrict__ wvb, u16* __restrict__ wob) {
  // f4-chunk boundaries (all /256 -> block-uniform branch)
  const int N0 = 1198080, N1 = 5990400, N2 = 6580224, N3 = 7170048, N4 = 7759872;
  int i = blockIdx.x * 256 + threadIdx.x;
  const float* s; u16* o; int base;
  if (i < N0)      { s = hs;  o = hsb; base = 0;  }
  else if (i < N1) { s = his; o = hib; base = N0; }
  else if (i < N2) { s = Wq;  o = wqb; base = N1; }
  else if (i < N3) { s = Wk;  o = wkb; base = N2; }
  else if (i < N4) { s = Wv;  o = wvb; base = N3; }
  else             { s = Wo;  o = wob; base = N4; }
  int j = i - base;
  float4 v = ((const float4*)s)[j];
  u16x4 r;
  r.x = f2bf(v.x); r.y = f2bf(v.y); r.z = f2bf(v.z); r.w = f2bf(v.w);
  ((u16x4*)o)[j] = r;
}

// ---------------- GEMM: C[M,1536] = A[M,1536] @ W[1536,1536]^T + bias ----------------
// 1D grid + XCD-chunked swizzle (same-row-panel blocks co-resident per XCD).
template <int OUT, int NBX>  // OUT: 0 = bf16, 1 = f32
__global__ __launch_bounds__(256, 2) void gemm_v2(
    const u16* __restrict__ A, const u16* __restrict__ W,
    const float* __restrict__ bias, void* __restrict__ Cp, int M) {
  const int K = 1536, N = 1536;
  __shared__ __align__(16) u16 gsm[17408];
  u16* As = gsm;
  u16* Bs = gsm + 8192;
  const int tid = threadIdx.x;
  const int lane = tid & 63, wid = tid >> 6;
  const int quad = lane >> 4, l15 = lane & 15;
  const int lg = xcd_chunk(blockIdx.x, gridDim.x);
  const int m0 = (lg / NBX) * 128, n0 = (lg % NBX) * 128;
  const int wm = (wid >> 1) * 64, wn = (wid & 1) * 64;
  f32x4 acc[4][4];
#pragma unroll
  for (int i = 0; i < 4; ++i)
#pragma unroll
    for (int j = 0; j < 4; ++j)
#pragma unroll
      for (int r = 0; r < 4; ++r) acc[i][j][r] = 0.f;

  const int r8 = lane >> 3, c8 = lane & 7;
  const int gch = c8 ^ r8;

  for (int k0 = 0; k0 < K; k0 += 64) {
#pragma unroll
    for (int inst = 0; inst < 4; ++inst) {
      int row = wid * 32 + inst * 8 + r8;
      glds16(A + ((size_t)(m0 + row) * K + k0 + gch * 8), As + (wid * 32 + inst * 8) * 64);
      glds16(W + ((size_t)(n0 + row) * K + k0 + gch * 8), Bs + (wid * 32 + inst * 8) * 64);
    }
    asm volatile("s_waitcnt vmcnt(0)" ::: "memory");
    __syncthreads();
#pragma unroll
    for (int ks = 0; ks < 2; ++ks) {
      u16x8 af[4], bfr[4];
#pragma unroll
      for (int i = 0; i < 4; ++i) {
        int row = wm + i * 16 + l15;
        af[i] = *(const u16x8*)&As[row * 64 + (((ks * 4 + quad) ^ (l15 & 7)) * 8)];
      }
#pragma unroll
      for (int j = 0; j < 4; ++j) {
        int row = wn + j * 16 + l15;
        bfr[j] = *(const u16x8*)&Bs[row * 64 + (((ks * 4 + quad) ^ (l15 & 7)) * 8)];
      }
#pragma unroll
      for (int i = 0; i < 4; ++i)
#pragma unroll
        for (int j = 0; j < 4; ++j) acc[i][j] = mfma16(af[i], bfr[j], acc[i][j]);
    }
    __syncthreads();
  }

#pragma unroll
  for (int i = 0; i < 4; ++i) {
    int row = m0 + wm + i * 16 + quad * 4;
#pragma unroll
    for (int j = 0; j < 4; ++j) {
      int col = n0 + wn + j * 16 + l15;
      float bc = bias[col];
#pragma unroll
      for (int r = 0; r < 4; ++r) {
        if (row + r < M) {
          float v = acc[i][j][r] + bc;
          if (OUT == 1)
            ((float*)Cp)[(size_t)(row + r) * N + col] = v;
          else
            ((u16*)Cp)[(size_t)(row + r) * N + col] = f2bf(v);
        }
      }
    }
  }
}

// ---------------- fused K+V projection GEMM (stacked [3072][1536] weights) ----------
// 2-phase structure (R8: 132 us). NEW (R13): selection-aware early-exit -- attention
// only reads K/V rows in the <=4 selected 1560-token blocks, so m-panels outside the
// sel mask return immediately (<=half the MFMA work). m-panel index is scattered
// inside each quarter (p = mi*25 % 98, bijective) so each XCD's panels sample all 8
// token-blocks uniformly -> early-exits spread evenly, no idle XCD. A-reuse is intact
// (6 consecutive lg = same panel, same XCD); W-reuse per quarter intact (n untouched).
__global__ __launch_bounds__(256, 2) void gemm_kv(
    const u16* __restrict__ A, const u16* __restrict__ Wkv,
    const float* __restrict__ bk, const float* __restrict__ bv,
    u16* __restrict__ Ck, u16* __restrict__ Vt,
    const int* __restrict__ sel, int M, int ldt) {
  const int K = 1536;
  __shared__ __align__(16) u16 gsm[17408];
  u16* As = gsm;
  u16* Bs = gsm + 8192;
  const int tid = threadIdx.x;
  const int lane = tid & 63, wid = tid >> 6;
  const int quad = lane >> 4, l15 = lane & 15;
  const int lg = xcd_chunk(blockIdx.x, gridDim.x);
  const int qtr = lg / 588;       // 588 = 98 m x 6 n
  const int rem = lg % 588;
  const int mi = rem / 6;
  const int m0 = ((mi * 25) % 98) * 128;     // scattered m-panel (bijective, 25⊥98)
  const int n0 = (qtr * 6 + rem % 6) * 128;  // 0..2944

  // selection-aware early exit: panel [m0, m0+128) intersects no selected block?
  {
    int mask = sel_mask(sel);
    int tb0 = m0 / 1560;
    int tb1 = (m0 + 127) / 1560;
    if (!((mask >> tb0) & 1) && !((mask >> tb1) & 1)) return;
  }

  const int wm = (wid >> 1) * 64, wn = (wid & 1) * 64;
  f32x4 acc[4][4];
#pragma unroll
  for (int i = 0; i < 4; ++i)
#pragma unroll
    for (int j = 0; j < 4; ++j)
#pragma unroll
      for (int r = 0; r < 4; ++r) acc[i][j][r] = 0.f;

  const int r8 = lane >> 3, c8 = lane & 7;
  const int gch = c8 ^ r8;

  for (int k0 = 0; k0 < K; k0 += 64) {
#pragma unroll
    for (int inst = 0; inst < 4; ++inst) {
      int row = wid * 32 + inst * 8 + r8;
      glds16(A + ((size_t)(m0 + row) * K + k0 + gch * 8), As + (wid * 32 + inst * 8) * 64);
      glds16(Wkv + ((size_t)(n0 + row) * K + k0 + gch * 8), Bs + (wid * 32 + inst * 8) * 64);
    }
    asm volatile("s_waitcnt vmcnt(0)" ::: "memory");
    __syncthreads();
#pragma unroll
    for (int ks = 0; ks < 2; ++ks) {
      u16x8 af[4], bfr[4];
#pragma unroll
      for (int i = 0; i < 4; ++i) {
        int row = wm + i * 16 + l15;
        af[i] = *(const u16x8*)&As[row * 64 + (((ks * 4 + quad) ^ (l15 & 7)) * 8)];
      }
#pragma unroll
      for (int j = 0; j < 4; ++j) {
        int row = wn + j * 16 + l15;
        bfr[j] = *(const u16x8*)&Bs[row * 64 + (((ks * 4 + quad) ^ (l15 & 7)) * 8)];
      }
#pragma unroll
      for (int i = 0; i < 4; ++i)
#pragma unroll
        for (int j = 0; j < 4; ++j) acc[i][j] = mfma16(af[i], bfr[j], acc[i][j]);
    }
    __syncthreads();
  }

  if (n0 < 1536) {  // K-projection: plain bf16 store
#pragma unroll
    for (int i = 0; i < 4; ++i) {
      int row = m0 + wm + i * 16 + quad * 4;
#pragma unroll
      for (int j = 0; j < 4; ++j) {
        int col = n0 + wn + j * 16 + l15;
        float bc = bk[col];
#pragma unroll
        for (int r = 0; r < 4; ++r) {
          if (row + r < M)
            Ck[(size_t)(row + r) * 1536 + col] = f2bf(acc[i][j][r] + bc);
        }
      }
    }
  } else {  // V-projection: transposed store via LDS
    const int n0v = n0 - 1536;
    u16* Ct = gsm;  // [128 n][136]
#pragma unroll
    for (int i = 0; i < 4; ++i)
#pragma unroll
      for (int j = 0; j < 4; ++j) {
        int nloc = wn + j * 16 + l15;
        float bc = bv[n0v + nloc];
#pragma unroll
        for (int r = 0; r < 4; ++r) {
          int mloc = wm + i * 16 + quad * 4 + r;
          Ct[nloc * 136 + mloc] = f2bf(acc[i][j][r] + bc);
        }
      }
    __syncthreads();
    int n = tid >> 1, half = tid & 1;
#pragma unroll
    for (int e = 0; e < 8; ++e) {
      int mloc = half * 64 + e * 8;
      if (m0 + mloc < M) {
        u16x8 v = *(const u16x8*)&Ct[n * 136 + mloc];
        *(u16x8*)(Vt + (size_t)(n0v + n) * ldt + m0 + mloc) = v;
      }
    }
  }
}

// ---------------- fused RMSNorm + interleaved RoPE, in-place bf16 ----------------
// sel != nullptr (K pass): rows in unselected token-blocks exit early (never read).
__global__ __launch_bounds__(192) void norm_rope2(u16* __restrict__ X,
                                                  const float* __restrict__ g,
                                                  const float* __restrict__ fc,
                                                  const float* __restrict__ fs,
                                                  float oscale,
                                                  const int* __restrict__ sel) {
  const int DIMc = 1536;
  int row = blockIdx.x;
  if (sel) {
    int mask = sel_mask(sel);
    if (!((mask >> (row / 1560)) & 1)) return;
  }
  int tid = threadIdx.x;
  u16* xr = X + (size_t)row * DIMc + tid * 8;
  u16x8 v = *(const u16x8*)xr;
  float x[8];
  float ss = 0.f;
#pragma unroll
  for (int e = 0; e < 8; ++e) { x[e] = bf2f(v[e]); ss += x[e] * x[e]; }
#pragma unroll
  for (int m = 1; m < 64; m <<= 1) ss += __shfl_xor(ss, m);
  __shared__ float w3[3];
  if ((tid & 63) == 0) w3[tid >> 6] = ss;
  __syncthreads();
  float rs = rsqrtf((w3[0] + w3[1] + w3[2]) * (1.f / 1536.f) + 1e-5f);
  int dhb = (tid * 8) & 127;
  const float* fcr = fc + (size_t)row * 128 + dhb;
  const float* fsr = fs + (size_t)row * 128 + dhb;
  float4 c0 = *(const float4*)fcr, c1 = *(const float4*)(fcr + 4);
  float4 s0 = *(const float4*)fsr, s1 = *(const float4*)(fsr + 4);
  const float* gp = g + tid * 8;
  float4 g0 = *(const float4*)gp, g1 = *(const float4*)(gp + 4);
  float cosv[4] = {c0.x, c0.z, c1.x, c1.z};
  float sinv[4] = {s0.y, s0.w, s1.y, s1.w};
  float gv[8] = {g0.x, g0.y, g0.z, g0.w, g1.x, g1.y, g1.z, g1.w};
  u16x8 o;
#pragma unroll
  for (int p = 0; p < 4; ++p) {
    float a = x[2 * p] * rs * gv[2 * p];
    float b = x[2 * p + 1] * rs * gv[2 * p + 1];
    o[2 * p] = f2bf((a * cosv[p] - b * sinv[p]) * oscale);
    o[2 * p + 1] = f2bf((a * sinv[p] + b * cosv[p]) * oscale);
  }
  *(u16x8*)xr = o;
}

// ---------------- block-sparse attention v12: unit-interleaved CU balance ----------
__global__ __launch_bounds__(256, 3) void attn12(
    const u16* __restrict__ Q, const u16* __restrict__ Kb,
    const u16* __restrict__ VT, const int* __restrict__ sel,
    float* __restrict__ Oacc, float* __restrict__ Lp) {
  const int HWc = 1560, DIMc = 1536, KTt = 12480, NT = 600;
  __shared__ __align__(16) u16 smem[16384];  // Ks0|Ks1|Vt0|Vt1 (8 KB each)
  const int tid = threadIdx.x;
  const int lane = tid & 63, wid = tid >> 6;
  const int quad = lane >> 4, l15 = lane & 15;

  int bid = blockIdx.x;
  int xcd = bid & 7, idx = bid >> 3;
  int mt = idx / 12, il = idx % 12;   // unit-interleaved
  int u = xcd + 8 * (il >> 1);
  const int t = il & 1;
  const int seg = u / 12;
  const int h = u % 12;
  const int m0 = mt * 128;
  const int g = h * 2 + t;

  int s0v = sel[2 * t];
  const int b0 = s0v > 0 ? s0v : 0;
  const int b1 = sel[2 * t + 1];
  const int nk = (b1 >= 0) ? 2 * HWc : HWc;
  const int nch = (nk + 31) >> 5;
  const int cpseg = (nch + 3) >> 2;
  const int c0 = seg * cpseg;
  const int c1 = (c0 + cpseg < nch) ? c0 + cpseg : nch;

  // Q B-frags: this wave's 32 q rows (2 sub-tiles of 16)
  u16x8 qf[2][4];
#pragma unroll
  for (int qt = 0; qt < 2; ++qt) {
    int qrow = m0 + wid * 32 + qt * 16 + l15;
    if (qrow > HWc - 1) qrow = HWc - 1;
    const u16* qp = Q + (size_t)(t * HWc + qrow) * DIMc + h * 128;
#pragma unroll
    for (int ks = 0; ks < 4; ++ks) qf[qt][ks] = *(const u16x8*)(qp + ks * 32 + quad * 8);
  }

  f32x4 oacc[2][8];  // partial O^T: [q-subtile][d-tile]
#pragma unroll
  for (int qt = 0; qt < 2; ++qt)
#pragma unroll
    for (int m = 0; m < 8; ++m)
#pragma unroll
      for (int r = 0; r < 4; ++r) oacc[qt][m][r] = 0.f;
  float lp[2] = {0.f, 0.f};

  auto stage = [&](int kc, int buf) {
    u16* Ks = smem + buf * 4096;
    u16* Vt = smem + 8192 + buf * 4096;
#pragma unroll
    for (int n = 0; n < 2; ++n) {
      int kl = wid * 8 + n * 4 + (lane >> 4);
      int gc = (lane & 15) ^ (kl & 15);
      int kg = kc + kl;
      if (kg >= nk) kg = 0;
      int big = kg >= HWc;
      int tok = (big ? b1 : b0) * HWc + kg - (big ? HWc : 0);
      glds16(Kb + ((size_t)tok * DIMc + h * 128 + gc * 8), Ks + (wid * 8 + n * 4) * 128);
    }
#pragma unroll
    for (int n = 0; n < 2; ++n) {
      int dl = wid * 32 + n * 16 + (lane >> 2);
      int gc = (lane & 3) ^ (dl & 3) ^ ((dl >> 2) & 3);
      int tg = kc + gc * 8;
      if (tg >= nk) tg = 0;
      int big = tg >= HWc;
      int tok = (big ? b1 : b0) * HWc + tg - (big ? HWc : 0);
      glds16(VT + ((size_t)(h * 128 + dl) * KTt + tok), Vt + (wid * 32 + n * 16) * 32);
    }
  };

  if (c0 < c1) stage(c0 * 32, 0);

  for (int c = c0; c < c1; ++c) {
    const int buf = (c - c0) & 1;
    u16* Ks = smem + buf * 4096;
    u16* Vt = smem + 8192 + buf * 4096;
    asm volatile("s_waitcnt vmcnt(0)\n\ts_barrier" ::: "memory");
    if (c + 1 < c1) stage((c + 1) * 32, buf ^ 1);

    f32x4 s[2][2];  // [gg][qt]
#pragma unroll
    for (int gg = 0; gg < 2; ++gg)
#pragma unroll
      for (int qt = 0; qt < 2; ++qt)
#pragma unroll
        for (int r = 0; r < 4; ++r) s[gg][qt][r] = 0.f;
#pragma unroll
    for (int ks = 0; ks < 4; ++ks)
#pragma unroll
      for (int gg = 0; gg < 2; ++gg) {
        u16x8 ka = *(const u16x8*)&Ks[(gg * 16 + l15) * 128 + (((ks * 4 + quad) ^ l15) * 8)];
#pragma unroll
        for (int qt = 0; qt < 2; ++qt) s[gg][qt] = mfma16(ka, qf[qt][ks], s[gg][qt]);
      }

    float p[2][2][4];
#pragma unroll
    for (int gg = 0; gg < 2; ++gg)
#pragma unroll
      for (int qt = 0; qt < 2; ++qt)
#pragma unroll
        for (int r = 0; r < 4; ++r) p[gg][qt][r] = exp2f(s[gg][qt][r]);
    if ((c + 1) * 32 > nk) {  // wave-uniform
#pragma unroll
      for (int gg = 0; gg < 2; ++gg)
#pragma unroll
        for (int r = 0; r < 4; ++r) {
          bool bad = c * 32 + gg * 16 + quad * 4 + r >= nk;
          if (bad) {
#pragma unroll
            for (int qt = 0; qt < 2; ++qt) p[gg][qt][r] = 0.f;
          }
        }
    }
    u16x4 pb[2][2];
#pragma unroll
    for (int gg = 0; gg < 2; ++gg)
#pragma unroll
      for (int qt = 0; qt < 2; ++qt)
#pragma unroll
        for (int r = 0; r < 4; ++r) {
          lp[qt] += p[gg][qt][r];
          pb[gg][qt][r] = f2bf_hw(p[gg][qt][r]);
        }

#pragma unroll
    for (int m = 0; m < 8; ++m) {
      int d = m * 16 + l15;
#pragma unroll
      for (int gg = 0; gg < 2; ++gg) {
        int sl = (gg * 2 + (quad >> 1)) ^ (d & 3) ^ ((d >> 2) & 3);
        u16x4 va = *(const u16x4*)&Vt[d * 32 + sl * 8 + (quad & 1) * 4];
#pragma unroll
        for (int qt = 0; qt < 2; ++qt) oacc[qt][m] = mfma16k16(va, pb[gg][qt], oacc[qt][m]);
      }
    }
  }

#pragma unroll
  for (int qt = 0; qt < 2; ++qt) {
    lp[qt] += __shfl_xor(lp[qt], 16);
    lp[qt] += __shfl_xor(lp[qt], 32);
  }
#pragma unroll
  for (int qt = 0; qt < 2; ++qt) {
    int qrow0 = m0 + wid * 32 + qt * 16;  // wave-uniform
    if (qrow0 < HWc) {
      size_t sb = ((size_t)seg * NT + g * 25 + (qrow0 >> 6)) * 64 + (qrow0 & 63);
      if (lane < 16 && qrow0 + lane < HWc) Lp[sb + lane] = lp[qt];
      if (qrow0 + l15 < HWc) {
#pragma unroll
        for (int m = 0; m < 8; ++m)
          *(f32x4*)&Oacc[(sb + l15) * 128 + m * 16 + quad * 4] = oacc[qt][m];
      }
    }
  }
}

// ---------------- normalize: O = bf16(sum_seg Oacc / sum_seg Lp) ----------------
__global__ __launch_bounds__(256) void attn_norm(const float* __restrict__ Oacc,
                                                 const float* __restrict__ Lp,
                                                 u16* __restrict__ O) {
  const int HWc = 1560, DIMc = 1536, NT = 600;
  int tile = blockIdx.x;  // 600
  int g = tile / 25, mt = tile % 25;
  int h = g >> 1, t = g & 1;
  int m0 = mt * 64;
  int tid = threadIdx.x;
#pragma unroll
  for (int e = 0; e < 8; ++e) {
    int idx = e * 256 + tid;   // 0..2047 f32x4 slots (64 q x 32)
    int qloc = idx >> 5;
    int d4 = (idx & 31) * 4;
    int q = m0 + qloc;
    if (q < HWc) {
      f32x4 a = {0.f, 0.f, 0.f, 0.f};
      float l = 0.f;
#pragma unroll
      for (int s = 0; s < 4; ++s) {
        const size_t sbase = ((size_t)s * NT + tile) * 64 + qloc;
        f32x4 v = *(const f32x4*)&Oacc[sbase * 128 + d4];
#pragma unroll
        for (int r = 0; r < 4; ++r) a[r] += v[r];
        l += Lp[sbase];
      }
      float linv = 1.f / l;
      u16x4 o;
#pragma unroll
      for (int r = 0; r < 4; ++r) o[r] = f2bf(a[r] * linv);
      *(u16x4*)(O + (size_t)(t * HWc + q) * DIMc + h * 128 + d4) = o;
    }
  }
}

extern "C" void kernel_launch(void* const* d_in, const int* in_sizes, int n_in,
                              void* d_out, int out_size, void* d_ws, size_t ws_size,
                              hipStream_t stream) {
  const float* hs  = (const float*)d_in[0];
  const float* his = (const float*)d_in[1];
  const float* fc  = (const float*)d_in[2];
  const float* fs  = (const float*)d_in[3];
  const float* fch = (const float*)d_in[4];
  const float* fsh = (const float*)d_in[5];
  const int*   sel = (const int*)d_in[6];
  const float* Wq  = (const float*)d_in[7];
  const float* bq  = (const float*)d_in[8];
  const float* Wk  = (const float*)d_in[9];
  const float* bk  = (const float*)d_in[10];
  const float* Wv  = (const float*)d_in[11];
  const float* bv  = (const float*)d_in[12];
  const float* Wo  = (const float*)d_in[13];
  const float* bo  = (const float*)d_in[14];
  const float* gq  = (const float*)d_in[15];
  const float* gk  = (const float*)d_in[16];

  const int QT = 3120, KT = 12480, DIMc = 1536;
  u16* p = (u16*)d_ws;
  u16* qb  = p; p += (size_t)QT * DIMc;
  u16* kb2 = p; p += (size_t)KT * DIMc;
  u16* vt  = p; p += (size_t)DIMc * KT;   // V^T [1536][12480]
  u16* ab  = p; p += (size_t)QT * DIMc;
  u16* wob = p; p += (size_t)DIMc * DIMc;
  u16* scratch = p;
  u16* hsb = scratch;
  u16* hib = hsb + (size_t)QT * DIMc;
  u16* wqb = hib + (size_t)KT * DIMc;
  u16* wkb = wqb + (size_t)DIMc * DIMc;   // wkb and wvb adjacent -> stacked [3072][1536]
  u16* wvb = wkb + (size_t)DIMc * DIMc;
  float* oaccb = (float*)scratch;                      // f32 [4][600][64][128]
  float* lpb   = oaccb + (size_t)4 * 600 * 64 * 128;   // f32 [4][600][64]

  cvt_all<<<dim3(32616), 256, 0, stream>>>(hs, his, Wq, Wk, Wv, Wo,
                                           hsb, hib, wqb, wkb, wvb, wob);

  gemm_v2<0, 12><<<dim3(300), 256, 0, stream>>>(hsb, wqb, bq, qb, QT);
  gemm_kv<<<dim3(2352), 256, 0, stream>>>(hib, wkb, bk, bv, kb2, vt, sel, KT, KT);

  const float qscale = (float)(0.08838834764831845 * 1.4426950408889634);
  norm_rope2<<<dim3(QT), 192, 0, stream>>>(qb, gq, fc, fs, qscale, nullptr);
  norm_rope2<<<dim3(KT), 192, 0, stream>>>(kb2, gk, fch, fsh, 1.0f, sel);

  // attn12 clobbers hsb/hib/wq/wk/wv (all dead by now); wob stays live for the final gemm.
  attn12<<<dim3(1248), 256, 0, stream>>>(qb, kb2, vt, sel, oaccb, lpb);
  attn_norm<<<dim3(600), 256, 0, stream>>>(oaccb, lpb, ab);

  gemm_v2<1, 12><<<dim3(300), 256, 0, stream>>>(ab, wob, bo, d_out, QT);
}

// Round 14
// 460.184 us; speedup vs baseline: 1.2782x; 1.0246x over previous
//
#include <hip/hip_runtime.h>

typedef unsigned short u16;
typedef __attribute__((ext_vector_type(4))) unsigned short u16x4;
typedef __attribute__((ext_vector_type(8))) unsigned short u16x8;
typedef __attribute__((ext_vector_type(4))) short s16x4;
typedef __attribute__((ext_vector_type(4))) float f32x4;
typedef __attribute__((ext_vector_type(8))) __bf16 bf16x8;

__device__ __forceinline__ u16 f2bf(float f) {
  union { float f; unsigned int u; } v; v.f = f;
  unsigned int u = v.u;
  unsigned int r = (u + 0x7fffu + ((u >> 16) & 1u)) >> 16;
  return (u16)r;
}
__device__ __forceinline__ u16 f2bf_hw(float f) {  // RNE via HW convert
  return __builtin_bit_cast(u16, (__bf16)f);
}
__device__ __forceinline__ float bf2f(u16 h) {
  union { unsigned int u; float f; } v; v.u = ((unsigned int)h) << 16;
  return v.f;
}
__device__ __forceinline__ f32x4 mfma16(u16x8 a, u16x8 b, f32x4 c) {
  return __builtin_amdgcn_mfma_f32_16x16x32_bf16(
      __builtin_bit_cast(bf16x8, a), __builtin_bit_cast(bf16x8, b), c, 0, 0, 0);
}
// K=16 variant: A/B are 4 bf16 (2 VGPRs)
__device__ __forceinline__ f32x4 mfma16k16(u16x4 a, u16x4 b, f32x4 c) {
  return __builtin_amdgcn_mfma_f32_16x16x16bf16_1k(
      __builtin_bit_cast(s16x4, a), __builtin_bit_cast(s16x4, b), c, 0, 0, 0);
}
// async global->LDS, 16B per lane; LDS dest = wave-uniform base + lane*16
__device__ __forceinline__ void glds16(const void* g, void* l) {
  __builtin_amdgcn_global_load_lds((const __attribute__((address_space(1))) void*)g,
                                   (__attribute__((address_space(3))) void*)l, 16, 0, 0);
}
// bijective XCD-chunked remap: XCD x (= bid&7 empirically) owns a contiguous
// logical-tile range -> blocks sharing operand panels are L2-co-resident.
__device__ __forceinline__ int xcd_chunk(int bid, int nwg) {
  int xcd = bid & 7, idx = bid >> 3;
  int q = nwg >> 3, r = nwg & 7;
  int base = xcd < r ? xcd * (q + 1) : r * (q + 1) + (xcd - r) * q;
  return base + idx;
}
// selected token-block mask from sel[4]: {clip(b0), b1 if >=0} per t.
// Exactly the token-blocks the attention kernel reads.
__device__ __forceinline__ int sel_mask(const int* __restrict__ sel) {
  int m = 0;
#pragma unroll
  for (int tt = 0; tt < 2; ++tt) {
    int a = sel[2 * tt];
    if (a < 0) a = 0;
    m |= 1 << a;
    int b = sel[2 * tt + 1];
    if (b >= 0) m |= 1 << b;
  }
  return m;
}

// ---------------- fused fp32 -> bf16 conversion (all 6 tensors, 1 launch) ----------
__global__ __launch_bounds__(256) void cvt_all(
    const float* __restrict__ hs, const float* __restrict__ his,
    const float* __restrict__ Wq, const float* __restrict__ Wk,
    const float* __restrict__ Wv, const float* __restrict__ Wo,
    u16* __restrict__ hsb, u16* __restrict__ hib,
    u16* __restrict__ wqb, u16* __restrict__ wkb,
    u16* __restrict__ wvb, u16* __restrict__ wob) {
  // f4-chunk boundaries (all /256 -> block-uniform branch)
  const int N0 = 1198080, N1 = 5990400, N2 = 6580224, N3 = 7170048, N4 = 7759872;
  int i = blockIdx.x * 256 + threadIdx.x;
  const float* s; u16* o; int base;
  if (i < N0)      { s = hs;  o = hsb; base = 0;  }
  else if (i < N1) { s = his; o = hib; base = N0; }
  else if (i < N2) { s = Wq;  o = wqb; base = N1; }
  else if (i < N3) { s = Wk;  o = wkb; base = N2; }
  else if (i < N4) { s = Wv;  o = wvb; base = N3; }
  else             { s = Wo;  o = wob; base = N4; }
  int j = i - base;
  float4 v = ((const float4*)s)[j];
  u16x4 r;
  r.x = f2bf(v.x); r.y = f2bf(v.y); r.z = f2bf(v.z); r.w = f2bf(v.w);
  ((u16x4*)o)[j] = r;
}

// ---------------- GEMM: C[M,1536] = A[M,1536] @ W[1536,1536]^T + bias ----------------
// 1D grid + XCD-chunked swizzle (same-row-panel blocks co-resident per XCD).
template <int OUT, int NBX>  // OUT: 0 = bf16, 1 = f32
__global__ __launch_bounds__(256, 2) void gemm_v2(
    const u16* __restrict__ A, const u16* __restrict__ W,
    const float* __restrict__ bias, void* __restrict__ Cp, int M) {
  const int K = 1536, N = 1536;
  __shared__ __align__(16) u16 gsm[17408];
  u16* As = gsm;
  u16* Bs = gsm + 8192;
  const int tid = threadIdx.x;
  const int lane = tid & 63, wid = tid >> 6;
  const int quad = lane >> 4, l15 = lane & 15;
  const int lg = xcd_chunk(blockIdx.x, gridDim.x);
  const int m0 = (lg / NBX) * 128, n0 = (lg % NBX) * 128;
  const int wm = (wid >> 1) * 64, wn = (wid & 1) * 64;
  f32x4 acc[4][4];
#pragma unroll
  for (int i = 0; i < 4; ++i)
#pragma unroll
    for (int j = 0; j < 4; ++j)
#pragma unroll
      for (int r = 0; r < 4; ++r) acc[i][j][r] = 0.f;

  const int r8 = lane >> 3, c8 = lane & 7;
  const int gch = c8 ^ r8;

  for (int k0 = 0; k0 < K; k0 += 64) {
#pragma unroll
    for (int inst = 0; inst < 4; ++inst) {
      int row = wid * 32 + inst * 8 + r8;
      glds16(A + ((size_t)(m0 + row) * K + k0 + gch * 8), As + (wid * 32 + inst * 8) * 64);
      glds16(W + ((size_t)(n0 + row) * K + k0 + gch * 8), Bs + (wid * 32 + inst * 8) * 64);
    }
    asm volatile("s_waitcnt vmcnt(0)" ::: "memory");
    __syncthreads();
#pragma unroll
    for (int ks = 0; ks < 2; ++ks) {
      u16x8 af[4], bfr[4];
#pragma unroll
      for (int i = 0; i < 4; ++i) {
        int row = wm + i * 16 + l15;
        af[i] = *(const u16x8*)&As[row * 64 + (((ks * 4 + quad) ^ (l15 & 7)) * 8)];
      }
#pragma unroll
      for (int j = 0; j < 4; ++j) {
        int row = wn + j * 16 + l15;
        bfr[j] = *(const u16x8*)&Bs[row * 64 + (((ks * 4 + quad) ^ (l15 & 7)) * 8)];
      }
#pragma unroll
      for (int i = 0; i < 4; ++i)
#pragma unroll
        for (int j = 0; j < 4; ++j) acc[i][j] = mfma16(af[i], bfr[j], acc[i][j]);
    }
    __syncthreads();
  }

#pragma unroll
  for (int i = 0; i < 4; ++i) {
    int row = m0 + wm + i * 16 + quad * 4;
#pragma unroll
    for (int j = 0; j < 4; ++j) {
      int col = n0 + wn + j * 16 + l15;
      float bc = bias[col];
#pragma unroll
      for (int r = 0; r < 4; ++r) {
        if (row + r < M) {
          float v = acc[i][j][r] + bc;
          if (OUT == 1)
            ((float*)Cp)[(size_t)(row + r) * N + col] = v;
          else
            ((u16*)Cp)[(size_t)(row + r) * N + col] = f2bf(v);
        }
      }
    }
  }
}

// ---------------- fused K+V projection GEMM (stacked [3072][1536] weights) ----------
// 2-phase structure (R8: 132 us) + selection-aware early-exit (R13): m-panels outside
// the sel mask return immediately. Scattered m-panel (p = mi*25 % 98, bijective).
__global__ __launch_bounds__(256, 2) void gemm_kv(
    const u16* __restrict__ A, const u16* __restrict__ Wkv,
    const float* __restrict__ bk, const float* __restrict__ bv,
    u16* __restrict__ Ck, u16* __restrict__ Vt,
    const int* __restrict__ sel, int M, int ldt) {
  const int K = 1536;
  __shared__ __align__(16) u16 gsm[17408];
  u16* As = gsm;
  u16* Bs = gsm + 8192;
  const int tid = threadIdx.x;
  const int lane = tid & 63, wid = tid >> 6;
  const int quad = lane >> 4, l15 = lane & 15;
  const int lg = xcd_chunk(blockIdx.x, gridDim.x);
  const int qtr = lg / 588;       // 588 = 98 m x 6 n
  const int rem = lg % 588;
  const int mi = rem / 6;
  const int m0 = ((mi * 25) % 98) * 128;     // scattered m-panel (bijective, 25⊥98)
  const int n0 = (qtr * 6 + rem % 6) * 128;  // 0..2944

  // selection-aware early exit: panel [m0, m0+128) intersects no selected block?
  {
    int mask = sel_mask(sel);
    int tb0 = m0 / 1560;
    int tb1 = (m0 + 127) / 1560;
    if (!((mask >> tb0) & 1) && !((mask >> tb1) & 1)) return;
  }

  const int wm = (wid >> 1) * 64, wn = (wid & 1) * 64;
  f32x4 acc[4][4];
#pragma unroll
  for (int i = 0; i < 4; ++i)
#pragma unroll
    for (int j = 0; j < 4; ++j)
#pragma unroll
      for (int r = 0; r < 4; ++r) acc[i][j][r] = 0.f;

  const int r8 = lane >> 3, c8 = lane & 7;
  const int gch = c8 ^ r8;

  for (int k0 = 0; k0 < K; k0 += 64) {
#pragma unroll
    for (int inst = 0; inst < 4; ++inst) {
      int row = wid * 32 + inst * 8 + r8;
      glds16(A + ((size_t)(m0 + row) * K + k0 + gch * 8), As + (wid * 32 + inst * 8) * 64);
      glds16(Wkv + ((size_t)(n0 + row) * K + k0 + gch * 8), Bs + (wid * 32 + inst * 8) * 64);
    }
    asm volatile("s_waitcnt vmcnt(0)" ::: "memory");
    __syncthreads();
#pragma unroll
    for (int ks = 0; ks < 2; ++ks) {
      u16x8 af[4], bfr[4];
#pragma unroll
      for (int i = 0; i < 4; ++i) {
        int row = wm + i * 16 + l15;
        af[i] = *(const u16x8*)&As[row * 64 + (((ks * 4 + quad) ^ (l15 & 7)) * 8)];
      }
#pragma unroll
      for (int j = 0; j < 4; ++j) {
        int row = wn + j * 16 + l15;
        bfr[j] = *(const u16x8*)&Bs[row * 64 + (((ks * 4 + quad) ^ (l15 & 7)) * 8)];
      }
#pragma unroll
      for (int i = 0; i < 4; ++i)
#pragma unroll
        for (int j = 0; j < 4; ++j) acc[i][j] = mfma16(af[i], bfr[j], acc[i][j]);
    }
    __syncthreads();
  }

  if (n0 < 1536) {  // K-projection: plain bf16 store
#pragma unroll
    for (int i = 0; i < 4; ++i) {
      int row = m0 + wm + i * 16 + quad * 4;
#pragma unroll
      for (int j = 0; j < 4; ++j) {
        int col = n0 + wn + j * 16 + l15;
        float bc = bk[col];
#pragma unroll
        for (int r = 0; r < 4; ++r) {
          if (row + r < M)
            Ck[(size_t)(row + r) * 1536 + col] = f2bf(acc[i][j][r] + bc);
        }
      }
    }
  } else {  // V-projection: transposed store via LDS
    const int n0v = n0 - 1536;
    u16* Ct = gsm;  // [128 n][136]
#pragma unroll
    for (int i = 0; i < 4; ++i)
#pragma unroll
      for (int j = 0; j < 4; ++j) {
        int nloc = wn + j * 16 + l15;
        float bc = bv[n0v + nloc];
#pragma unroll
        for (int r = 0; r < 4; ++r) {
          int mloc = wm + i * 16 + quad * 4 + r;
          Ct[nloc * 136 + mloc] = f2bf(acc[i][j][r] + bc);
        }
      }
    __syncthreads();
    int n = tid >> 1, half = tid & 1;
#pragma unroll
    for (int e = 0; e < 8; ++e) {
      int mloc = half * 64 + e * 8;
      if (m0 + mloc < M) {
        u16x8 v = *(const u16x8*)&Ct[n * 136 + mloc];
        *(u16x8*)(Vt + (size_t)(n0v + n) * ldt + m0 + mloc) = v;
      }
    }
  }
}

// ---------------- fused RMSNorm + interleaved RoPE, in-place bf16 ----------------
// sel != nullptr (K pass): rows in unselected token-blocks exit early (never read).
__global__ __launch_bounds__(192) void norm_rope2(u16* __restrict__ X,
                                                  const float* __restrict__ g,
                                                  const float* __restrict__ fc,
                                                  const float* __restrict__ fs,
                                                  float oscale,
                                                  const int* __restrict__ sel) {
  const int DIMc = 1536;
  int row = blockIdx.x;
  if (sel) {
    int mask = sel_mask(sel);
    if (!((mask >> (row / 1560)) & 1)) return;
  }
  int tid = threadIdx.x;
  u16* xr = X + (size_t)row * DIMc + tid * 8;
  u16x8 v = *(const u16x8*)xr;
  float x[8];
  float ss = 0.f;
#pragma unroll
  for (int e = 0; e < 8; ++e) { x[e] = bf2f(v[e]); ss += x[e] * x[e]; }
#pragma unroll
  for (int m = 1; m < 64; m <<= 1) ss += __shfl_xor(ss, m);
  __shared__ float w3[3];
  if ((tid & 63) == 0) w3[tid >> 6] = ss;
  __syncthreads();
  float rs = rsqrtf((w3[0] + w3[1] + w3[2]) * (1.f / 1536.f) + 1e-5f);
  int dhb = (tid * 8) & 127;
  const float* fcr = fc + (size_t)row * 128 + dhb;
  const float* fsr = fs + (size_t)row * 128 + dhb;
  float4 c0 = *(const float4*)fcr, c1 = *(const float4*)(fcr + 4);
  float4 s0 = *(const float4*)fsr, s1 = *(const float4*)(fsr + 4);
  const float* gp = g + tid * 8;
  float4 g0 = *(const float4*)gp, g1 = *(const float4*)(gp + 4);
  float cosv[4] = {c0.x, c0.z, c1.x, c1.z};
  float sinv[4] = {s0.y, s0.w, s1.y, s1.w};
  float gv[8] = {g0.x, g0.y, g0.z, g0.w, g1.x, g1.y, g1.z, g1.w};
  u16x8 o;
#pragma unroll
  for (int p = 0; p < 4; ++p) {
    float a = x[2 * p] * rs * gv[2 * p];
    float b = x[2 * p + 1] * rs * gv[2 * p + 1];
    o[2 * p] = f2bf((a * cosv[p] - b * sinv[p]) * oscale);
    o[2 * p + 1] = f2bf((a * sinv[p] + b * cosv[p]) * oscale);
  }
  *(u16x8*)xr = o;
}

// ---------------- block-sparse attention v13: equal-length adaptive segmentation ----
// v12 tail diagnosis: grid == resident capacity, so short-t (13-chunk) blocks drained
// with no backfill -> time-avg occupancy 19% and 40% of the kernel ran near-empty.
// v13: each h gets 6 slots split between t0/t1 proportional to chunk count:
// ns0 = 6*nch0/(nch0+nch1), EXACTLY integer for all sel cases ((98,98)->3+3@33ch,
// (98,49)->4+2@25ch, (49,49)->3+3@16ch) -> every block does ~equal chunks, no length
// mixing, minimal tail. Max 4 segs per t -> existing [4][600] Oacc layout unchanged
// (attn_norm recomputes nseg from sel and sums only live slots). Grid 936 = 12h x
// 6slot x 13mt; 13 mt-blocks of one (h,slot) unit are consecutive bids on one XCD
// (restores R6's K/V L2 sharing; FETCH 48.7 -> ~25 MB expected).
__global__ __launch_bounds__(256, 3) void attn13(
    const u16* __restrict__ Q, const u16* __restrict__ Kb,
    const u16* __restrict__ VT, const int* __restrict__ sel,
    float* __restrict__ Oacc, float* __restrict__ Lp) {
  const int HWc = 1560, DIMc = 1536, KTt = 12480, NT = 600;
  __shared__ __align__(16) u16 smem[16384];  // Ks0|Ks1|Vt0|Vt1 (8 KB each)
  const int tid = threadIdx.x;
  const int lane = tid & 63, wid = tid >> 6;
  const int quad = lane >> 4, l15 = lane & 15;

  int bid = blockIdx.x;
  int xcd = bid & 7, idx = bid >> 3;   // idx 0..116
  int ug = idx / 13, mt = idx % 13;    // ug 0..8
  int u = xcd + 8 * ug;                // 0..71
  const int h = u / 6;
  const int slot = u % 6;

  // adaptive slot -> (t, seg)
  const int nch0 = (sel[1] >= 0) ? 98 : 49;
  const int nch1 = (sel[3] >= 0) ? 98 : 49;
  const int ns0 = 6 * nch0 / (nch0 + nch1);  // exact integer for all cases
  const int t = (slot < ns0) ? 0 : 1;
  const int si = (slot < ns0) ? slot : slot - ns0;
  const int nseg = (slot < ns0) ? ns0 : 6 - ns0;
  const int m0 = mt * 128;
  const int g = h * 2 + t;

  int s0v = sel[2 * t];
  const int b0 = s0v > 0 ? s0v : 0;
  const int b1 = sel[2 * t + 1];
  const int nk = (b1 >= 0) ? 2 * HWc : HWc;
  const int nch = (b1 >= 0) ? 98 : 49;
  const int cpseg = (nch + nseg - 1) / nseg;
  const int c0 = si * cpseg;
  const int c1 = (c0 + cpseg < nch) ? c0 + cpseg : nch;

  // Q B-frags: this wave's 32 q rows (2 sub-tiles of 16)
  u16x8 qf[2][4];
#pragma unroll
  for (int qt = 0; qt < 2; ++qt) {
    int qrow = m0 + wid * 32 + qt * 16 + l15;
    if (qrow > HWc - 1) qrow = HWc - 1;
    const u16* qp = Q + (size_t)(t * HWc + qrow) * DIMc + h * 128;
#pragma unroll
    for (int ks = 0; ks < 4; ++ks) qf[qt][ks] = *(const u16x8*)(qp + ks * 32 + quad * 8);
  }

  f32x4 oacc[2][8];  // partial O^T: [q-subtile][d-tile]
#pragma unroll
  for (int qt = 0; qt < 2; ++qt)
#pragma unroll
    for (int m = 0; m < 8; ++m)
#pragma unroll
      for (int r = 0; r < 4; ++r) oacc[qt][m][r] = 0.f;
  float lp[2] = {0.f, 0.f};

  auto stage = [&](int kc, int buf) {
    u16* Ks = smem + buf * 4096;
    u16* Vt = smem + 8192 + buf * 4096;
#pragma unroll
    for (int n = 0; n < 2; ++n) {
      int kl = wid * 8 + n * 4 + (lane >> 4);
      int gc = (lane & 15) ^ (kl & 15);
      int kg = kc + kl;
      if (kg >= nk) kg = 0;
      int big = kg >= HWc;
      int tok = (big ? b1 : b0) * HWc + kg - (big ? HWc : 0);
      glds16(Kb + ((size_t)tok * DIMc + h * 128 + gc * 8), Ks + (wid * 8 + n * 4) * 128);
    }
#pragma unroll
    for (int n = 0; n < 2; ++n) {
      int dl = wid * 32 + n * 16 + (lane >> 2);
      int gc = (lane & 3) ^ (dl & 3) ^ ((dl >> 2) & 3);
      int tg = kc + gc * 8;
      if (tg >= nk) tg = 0;
      int big = tg >= HWc;
      int tok = (big ? b1 : b0) * HWc + tg - (big ? HWc : 0);
      glds16(VT + ((size_t)(h * 128 + dl) * KTt + tok), Vt + (wid * 32 + n * 16) * 32);
    }
  };

  if (c0 < c1) stage(c0 * 32, 0);

  for (int c = c0; c < c1; ++c) {
    const int buf = (c - c0) & 1;
    u16* Ks = smem + buf * 4096;
    u16* Vt = smem + 8192 + buf * 4096;
    asm volatile("s_waitcnt vmcnt(0)\n\ts_barrier" ::: "memory");
    if (c + 1 < c1) stage((c + 1) * 32, buf ^ 1);

    f32x4 s[2][2];  // [gg][qt]
#pragma unroll
    for (int gg = 0; gg < 2; ++gg)
#pragma unroll
      for (int qt = 0; qt < 2; ++qt)
#pragma unroll
        for (int r = 0; r < 4; ++r) s[gg][qt][r] = 0.f;
#pragma unroll
    for (int ks = 0; ks < 4; ++ks)
#pragma unroll
      for (int gg = 0; gg < 2; ++gg) {
        u16x8 ka = *(const u16x8*)&Ks[(gg * 16 + l15) * 128 + (((ks * 4 + quad) ^ l15) * 8)];
#pragma unroll
        for (int qt = 0; qt < 2; ++qt) s[gg][qt] = mfma16(ka, qf[qt][ks], s[gg][qt]);
      }

    float p[2][2][4];
#pragma unroll
    for (int gg = 0; gg < 2; ++gg)
#pragma unroll
      for (int qt = 0; qt < 2; ++qt)
#pragma unroll
        for (int r = 0; r < 4; ++r) p[gg][qt][r] = exp2f(s[gg][qt][r]);
    if ((c + 1) * 32 > nk) {  // wave-uniform
#pragma unroll
      for (int gg = 0; gg < 2; ++gg)
#pragma unroll
        for (int r = 0; r < 4; ++r) {
          bool bad = c * 32 + gg * 16 + quad * 4 + r >= nk;
          if (bad) {
#pragma unroll
            for (int qt = 0; qt < 2; ++qt) p[gg][qt][r] = 0.f;
          }
        }
    }
    u16x4 pb[2][2];
#pragma unroll
    for (int gg = 0; gg < 2; ++gg)
#pragma unroll
      for (int qt = 0; qt < 2; ++qt)
#pragma unroll
        for (int r = 0; r < 4; ++r) {
          lp[qt] += p[gg][qt][r];
          pb[gg][qt][r] = f2bf_hw(p[gg][qt][r]);
        }

#pragma unroll
    for (int m = 0; m < 8; ++m) {
      int d = m * 16 + l15;
#pragma unroll
      for (int gg = 0; gg < 2; ++gg) {
        int sl = (gg * 2 + (quad >> 1)) ^ (d & 3) ^ ((d >> 2) & 3);
        u16x4 va = *(const u16x4*)&Vt[d * 32 + sl * 8 + (quad & 1) * 4];
#pragma unroll
        for (int qt = 0; qt < 2; ++qt) oacc[qt][m] = mfma16k16(va, pb[gg][qt], oacc[qt][m]);
      }
    }
  }

#pragma unroll
  for (int qt = 0; qt < 2; ++qt) {
    lp[qt] += __shfl_xor(lp[qt], 16);
    lp[qt] += __shfl_xor(lp[qt], 32);
  }
#pragma unroll
  for (int qt = 0; qt < 2; ++qt) {
    int qrow0 = m0 + wid * 32 + qt * 16;  // wave-uniform
    if (qrow0 < HWc) {
      size_t sb = ((size_t)si * NT + g * 25 + (qrow0 >> 6)) * 64 + (qrow0 & 63);
      if (lane < 16 && qrow0 + lane < HWc) Lp[sb + lane] = lp[qt];
      if (qrow0 + l15 < HWc) {
#pragma unroll
        for (int m = 0; m < 8; ++m)
          *(f32x4*)&Oacc[(sb + l15) * 128 + m * 16 + quad * 4] = oacc[qt][m];
      }
    }
  }
}

// ---------------- normalize: O = bf16(sum_seg Oacc / sum_seg Lp) ----------------
// Sums only the live segment slots (nseg from sel, matching attn13's split).
__global__ __launch_bounds__(256) void attn_norm(const float* __restrict__ Oacc,
                                                 const float* __restrict__ Lp,
                                                 const int* __restrict__ sel,
                                                 u16* __restrict__ O) {
  const int HWc = 1560, DIMc = 1536, NT = 600;
  int tile = blockIdx.x;  // 600
  int g = tile / 25, mt = tile % 25;
  int h = g >> 1, t = g & 1;
  int m0 = mt * 64;
  int tid = threadIdx.x;
  const int nch0 = (sel[1] >= 0) ? 98 : 49;
  const int nch1 = (sel[3] >= 0) ? 98 : 49;
  const int ns0 = 6 * nch0 / (nch0 + nch1);
  const int nseg = (t == 0) ? ns0 : 6 - ns0;
#pragma unroll
  for (int e = 0; e < 8; ++e) {
    int idx = e * 256 + tid;   // 0..2047 f32x4 slots (64 q x 32)
    int qloc = idx >> 5;
    int d4 = (idx & 31) * 4;
    int q = m0 + qloc;
    if (q < HWc) {
      f32x4 a = {0.f, 0.f, 0.f, 0.f};
      float l = 0.f;
      for (int s = 0; s < nseg; ++s) {
        const size_t sbase = ((size_t)s * NT + tile) * 64 + qloc;
        f32x4 v = *(const f32x4*)&Oacc[sbase * 128 + d4];
#pragma unroll
        for (int r = 0; r < 4; ++r) a[r] += v[r];
        l += Lp[sbase];
      }
      float linv = 1.f / l;
      u16x4 o;
#pragma unroll
      for (int r = 0; r < 4; ++r) o[r] = f2bf(a[r] * linv);
      *(u16x4*)(O + (size_t)(t * HWc + q) * DIMc + h * 128 + d4) = o;
    }
  }
}

extern "C" void kernel_launch(void* const* d_in, const int* in_sizes, int n_in,
                              void* d_out, int out_size, void* d_ws, size_t ws_size,
                              hipStream_t stream) {
  const float* hs  = (const float*)d_in[0];
  const float* his = (const float*)d_in[1];
  const float* fc  = (const float*)d_in[2];
  const float* fs  = (const float*)d_in[3];
  const float* fch = (const float*)d_in[4];
  const float* fsh = (const float*)d_in[5];
  const int*   sel = (const int*)d_in[6];
  const float* Wq  = (const float*)d_in[7];
  const float* bq  = (const float*)d_in[8];
  const float* Wk  = (const float*)d_in[9];
  const float* bk  = (const float*)d_in[10];
  const float* Wv  = (const float*)d_in[11];
  const float* bv  = (const float*)d_in[12];
  const float* Wo  = (const float*)d_in[13];
  const float* bo  = (const float*)d_in[14];
  const float* gq  = (const float*)d_in[15];
  const float* gk  = (const float*)d_in[16];

  const int QT = 3120, KT = 12480, DIMc = 1536;
  u16* p = (u16*)d_ws;
  u16* qb  = p; p += (size_t)QT * DIMc;
  u16* kb2 = p; p += (size_t)KT * DIMc;
  u16* vt  = p; p += (size_t)DIMc * KT;   // V^T [1536][12480]
  u16* ab  = p; p += (size_t)QT * DIMc;
  u16* wob = p; p += (size_t)DIMc * DIMc;
  u16* scratch = p;
  u16* hsb = scratch;
  u16* hib = hsb + (size_t)QT * DIMc;
  u16* wqb = hib + (size_t)KT * DIMc;
  u16* wkb = wqb + (size_t)DIMc * DIMc;   // wkb and wvb adjacent -> stacked [3072][1536]
  u16* wvb = wkb + (size_t)DIMc * DIMc;
  float* oaccb = (float*)scratch;                      // f32 [4][600][64][128]
  float* lpb   = oaccb + (size_t)4 * 600 * 64 * 128;   // f32 [4][600][64]

  cvt_all<<<dim3(32616), 256, 0, stream>>>(hs, his, Wq, Wk, Wv, Wo,
                                           hsb, hib, wqb, wkb, wvb, wob);

  gemm_v2<0, 12><<<dim3(300), 256, 0, stream>>>(hsb, wqb, bq, qb, QT);
  gemm_kv<<<dim3(2352), 256, 0, stream>>>(hib, wkb, bk, bv, kb2, vt, sel, KT, KT);

  const float qscale = (float)(0.08838834764831845 * 1.4426950408889634);
  norm_rope2<<<dim3(QT), 192, 0, stream>>>(qb, gq, fc, fs, qscale, nullptr);
  norm_rope2<<<dim3(KT), 192, 0, stream>>>(kb2, gk, fch, fsh, 1.0f, sel);

  // attn13 clobbers hsb/hib/wq/wk/wv (all dead by now); wob stays live for the final gemm.
  attn13<<<dim3(936), 256, 0, stream>>>(qb, kb2, vt, sel, oaccb, lpb);
  attn_norm<<<dim3(600), 256, 0, stream>>>(oaccb, lpb, sel, ab);

  gemm_v2<1, 12><<<dim3(300), 256, 0, stream>>>(ab, wob, bo, d_out, QT);
}

// Round 15
// 453.154 us; speedup vs baseline: 1.2980x; 1.0155x over previous
//
#include <hip/hip_runtime.h>

typedef unsigned short u16;
typedef __attribute__((ext_vector_type(4))) unsigned short u16x4;
typedef __attribute__((ext_vector_type(8))) unsigned short u16x8;
typedef __attribute__((ext_vector_type(4))) short s16x4;
typedef __attribute__((ext_vector_type(4))) float f32x4;
typedef __attribute__((ext_vector_type(8))) __bf16 bf16x8;

__device__ __forceinline__ u16 f2bf(float f) {
  union { float f; unsigned int u; } v; v.f = f;
  unsigned int u = v.u;
  unsigned int r = (u + 0x7fffu + ((u >> 16) & 1u)) >> 16;
  return (u16)r;
}
__device__ __forceinline__ u16 f2bf_hw(float f) {  // RNE via HW convert
  return __builtin_bit_cast(u16, (__bf16)f);
}
__device__ __forceinline__ float bf2f(u16 h) {
  union { unsigned int u; float f; } v; v.u = ((unsigned int)h) << 16;
  return v.f;
}
__device__ __forceinline__ f32x4 mfma16(u16x8 a, u16x8 b, f32x4 c) {
  return __builtin_amdgcn_mfma_f32_16x16x32_bf16(
      __builtin_bit_cast(bf16x8, a), __builtin_bit_cast(bf16x8, b), c, 0, 0, 0);
}
// K=16 variant: A/B are 4 bf16 (2 VGPRs)
__device__ __forceinline__ f32x4 mfma16k16(u16x4 a, u16x4 b, f32x4 c) {
  return __builtin_amdgcn_mfma_f32_16x16x16bf16_1k(
      __builtin_bit_cast(s16x4, a), __builtin_bit_cast(s16x4, b), c, 0, 0, 0);
}
// async global->LDS, 16B per lane; LDS dest = wave-uniform base + lane*16
__device__ __forceinline__ void glds16(const void* g, void* l) {
  __builtin_amdgcn_global_load_lds((const __attribute__((address_space(1))) void*)g,
                                   (__attribute__((address_space(3))) void*)l, 16, 0, 0);
}
// bijective XCD-chunked remap: XCD x (= bid&7 empirically) owns a contiguous
// logical-tile range -> blocks sharing operand panels are L2-co-resident.
__device__ __forceinline__ int xcd_chunk(int bid, int nwg) {
  int xcd = bid & 7, idx = bid >> 3;
  int q = nwg >> 3, r = nwg & 7;
  int base = xcd < r ? xcd * (q + 1) : r * (q + 1) + (xcd - r) * q;
  return base + idx;
}
// selected token-block mask from sel[4]: {clip(b0), b1 if >=0} per t.
__device__ __forceinline__ int sel_mask(const int* __restrict__ sel) {
  int m = 0;
#pragma unroll
  for (int tt = 0; tt < 2; ++tt) {
    int a = sel[2 * tt];
    if (a < 0) a = 0;
    m |= 1 << a;
    int b = sel[2 * tt + 1];
    if (b >= 0) m |= 1 << b;
  }
  return m;
}

// ---------------- fused fp32 -> bf16 conversion; his rows sel-predicated ----------
__global__ __launch_bounds__(256) void cvt_all(
    const float* __restrict__ hs, const float* __restrict__ his,
    const float* __restrict__ Wq, const float* __restrict__ Wk,
    const float* __restrict__ Wv, const float* __restrict__ Wo,
    u16* __restrict__ hsb, u16* __restrict__ hib,
    u16* __restrict__ wqb, u16* __restrict__ wkb,
    u16* __restrict__ wvb, u16* __restrict__ wob,
    const int* __restrict__ sel) {
  // f4-chunk boundaries (all /256 -> block-uniform branch)
  const int N0 = 1198080, N1 = 5990400, N2 = 6580224, N3 = 7170048, N4 = 7759872;
  int i = blockIdx.x * 256 + threadIdx.x;
  const float* s; u16* o; int base;
  if (i < N0)      { s = hs;  o = hsb; base = 0;  }
  else if (i < N1) { s = his; o = hib; base = N0; }
  else if (i < N2) { s = Wq;  o = wqb; base = N1; }
  else if (i < N3) { s = Wk;  o = wkb; base = N2; }
  else if (i < N4) { s = Wv;  o = wvb; base = N3; }
  else             { s = Wo;  o = wob; base = N4; }
  int j = i - base;
  if (base == N0) {  // his region: skip rows in unselected token-blocks (never read:
    // gemm_qkv early-exits those m-panels; garbage A rows only affect their own
    // never-read C rows)
    int row = j / 384;                 // 384 f4 per 1536-col row
    if (!((sel_mask(sel) >> (row / 1560)) & 1)) return;
  }
  float4 v = ((const float4*)s)[j];
  u16x4 r;
  r.x = f2bf(v.x); r.y = f2bf(v.y); r.z = f2bf(v.z); r.w = f2bf(v.w);
  ((u16x4*)o)[j] = r;
}

// ---------------- GEMM: C[M,1536] = A[M,1536] @ W[1536,1536]^T + bias ----------------
// (used for the output projection only now)
template <int OUT, int NBX>  // OUT: 0 = bf16, 1 = f32
__global__ __launch_bounds__(256, 2) void gemm_v2(
    const u16* __restrict__ A, const u16* __restrict__ W,
    const float* __restrict__ bias, void* __restrict__ Cp, int M) {
  const int K = 1536, N = 1536;
  __shared__ __align__(16) u16 gsm[17408];
  u16* As = gsm;
  u16* Bs = gsm + 8192;
  const int tid = threadIdx.x;
  const int lane = tid & 63, wid = tid >> 6;
  const int quad = lane >> 4, l15 = lane & 15;
  const int lg = xcd_chunk(blockIdx.x, gridDim.x);
  const int m0 = (lg / NBX) * 128, n0 = (lg % NBX) * 128;
  const int wm = (wid >> 1) * 64, wn = (wid & 1) * 64;
  f32x4 acc[4][4];
#pragma unroll
  for (int i = 0; i < 4; ++i)
#pragma unroll
    for (int j = 0; j < 4; ++j)
#pragma unroll
      for (int r = 0; r < 4; ++r) acc[i][j][r] = 0.f;

  const int r8 = lane >> 3, c8 = lane & 7;
  const int gch = c8 ^ r8;

  for (int k0 = 0; k0 < K; k0 += 64) {
#pragma unroll
    for (int inst = 0; inst < 4; ++inst) {
      int row = wid * 32 + inst * 8 + r8;
      glds16(A + ((size_t)(m0 + row) * K + k0 + gch * 8), As + (wid * 32 + inst * 8) * 64);
      glds16(W + ((size_t)(n0 + row) * K + k0 + gch * 8), Bs + (wid * 32 + inst * 8) * 64);
    }
    asm volatile("s_waitcnt vmcnt(0)" ::: "memory");
    __syncthreads();
#pragma unroll
    for (int ks = 0; ks < 2; ++ks) {
      u16x8 af[4], bfr[4];
#pragma unroll
      for (int i = 0; i < 4; ++i) {
        int row = wm + i * 16 + l15;
        af[i] = *(const u16x8*)&As[row * 64 + (((ks * 4 + quad) ^ (l15 & 7)) * 8)];
      }
#pragma unroll
      for (int j = 0; j < 4; ++j) {
        int row = wn + j * 16 + l15;
        bfr[j] = *(const u16x8*)&Bs[row * 64 + (((ks * 4 + quad) ^ (l15 & 7)) * 8)];
      }
#pragma unroll
      for (int i = 0; i < 4; ++i)
#pragma unroll
        for (int j = 0; j < 4; ++j) acc[i][j] = mfma16(af[i], bfr[j], acc[i][j]);
    }
    __syncthreads();
  }

#pragma unroll
  for (int i = 0; i < 4; ++i) {
    int row = m0 + wm + i * 16 + quad * 4;
#pragma unroll
    for (int j = 0; j < 4; ++j) {
      int col = n0 + wn + j * 16 + l15;
      float bc = bias[col];
#pragma unroll
      for (int r = 0; r < 4; ++r) {
        if (row + r < M) {
          float v = acc[i][j][r] + bc;
          if (OUT == 1)
            ((float*)Cp)[(size_t)(row + r) * N + col] = v;
          else
            ((u16*)Cp)[(size_t)(row + r) * N + col] = f2bf(v);
        }
      }
    }
  }
}

// ---------------- merged Q + K + V projection GEMM (one launch, 2652 blocks) -------
// lg < 300: Q-projection (A=hsb, W=wqb, 25m x 12n).  lg >= 300: KV-projection
// (A=hib, W=stacked wkb|wvb, n-quartered XCD map + scattered m + sel early-exit,
// R12/R13 proven). Q's 300-block tail now co-runs with KV's ramp; one less launch.
__global__ __launch_bounds__(256, 2) void gemm_qkv(
    const u16* __restrict__ Aq, const u16* __restrict__ Akv,
    const u16* __restrict__ Wqp, const u16* __restrict__ Wkv,
    const float* __restrict__ bq, const float* __restrict__ bk,
    const float* __restrict__ bv,
    u16* __restrict__ Cq, u16* __restrict__ Ck, u16* __restrict__ Vt,
    const int* __restrict__ sel, int ldt) {
  const int K = 1536;
  __shared__ __align__(16) u16 gsm[17408];
  u16* As = gsm;
  u16* Bs = gsm + 8192;
  const int tid = threadIdx.x;
  const int lane = tid & 63, wid = tid >> 6;
  const int quad = lane >> 4, l15 = lane & 15;
  const int lg = xcd_chunk(blockIdx.x, gridDim.x);

  const u16 *A, *W;
  const float* bias;
  u16* out;
  int m0, n0, M, vmode;
  if (lg < 300) {  // Q-projection
    A = Aq; W = Wqp; bias = bq; out = Cq;
    m0 = (lg / 12) * 128; n0 = (lg % 12) * 128; M = 3120; vmode = 0;
  } else {  // KV-projection
    int L2 = lg - 300;
    int qtr = L2 / 588, rem = L2 % 588;   // 588 = 98 m x 6 n per quarter
    int mi = rem / 6;
    m0 = ((mi * 25) % 98) * 128;          // scattered m-panel (bijective, 25⊥98)
    n0 = (qtr * 6 + rem % 6) * 128;       // 0..2944
    {  // selection-aware early exit
      int mask = sel_mask(sel);
      int tb0 = m0 / 1560, tb1 = (m0 + 127) / 1560;
      if (!((mask >> tb0) & 1) && !((mask >> tb1) & 1)) return;
    }
    A = Akv; W = Wkv; M = 12480;
    if (n0 < 1536) { bias = bk; out = Ck; vmode = 0; }
    else { bias = bv; out = nullptr; vmode = 1; }
  }

  const int wm = (wid >> 1) * 64, wn = (wid & 1) * 64;
  f32x4 acc[4][4];
#pragma unroll
  for (int i = 0; i < 4; ++i)
#pragma unroll
    for (int j = 0; j < 4; ++j)
#pragma unroll
      for (int r = 0; r < 4; ++r) acc[i][j][r] = 0.f;

  const int r8 = lane >> 3, c8 = lane & 7;
  const int gch = c8 ^ r8;

  for (int k0 = 0; k0 < K; k0 += 64) {
#pragma unroll
    for (int inst = 0; inst < 4; ++inst) {
      int row = wid * 32 + inst * 8 + r8;
      glds16(A + ((size_t)(m0 + row) * K + k0 + gch * 8), As + (wid * 32 + inst * 8) * 64);
      glds16(W + ((size_t)(n0 + row) * K + k0 + gch * 8), Bs + (wid * 32 + inst * 8) * 64);
    }
    asm volatile("s_waitcnt vmcnt(0)" ::: "memory");
    __syncthreads();
#pragma unroll
    for (int ks = 0; ks < 2; ++ks) {
      u16x8 af[4], bfr[4];
#pragma unroll
      for (int i = 0; i < 4; ++i) {
        int row = wm + i * 16 + l15;
        af[i] = *(const u16x8*)&As[row * 64 + (((ks * 4 + quad) ^ (l15 & 7)) * 8)];
      }
#pragma unroll
      for (int j = 0; j < 4; ++j) {
        int row = wn + j * 16 + l15;
        bfr[j] = *(const u16x8*)&Bs[row * 64 + (((ks * 4 + quad) ^ (l15 & 7)) * 8)];
      }
#pragma unroll
      for (int i = 0; i < 4; ++i)
#pragma unroll
        for (int j = 0; j < 4; ++j) acc[i][j] = mfma16(af[i], bfr[j], acc[i][j]);
    }
    __syncthreads();
  }

  if (vmode == 0) {  // plain bf16 store (Q-proj or K-proj)
#pragma unroll
    for (int i = 0; i < 4; ++i) {
      int row = m0 + wm + i * 16 + quad * 4;
#pragma unroll
      for (int j = 0; j < 4; ++j) {
        int col = n0 + wn + j * 16 + l15;
        float bc = bias[col];
#pragma unroll
        for (int r = 0; r < 4; ++r) {
          if (row + r < M)
            out[(size_t)(row + r) * 1536 + col] = f2bf(acc[i][j][r] + bc);
        }
      }
    }
  } else {  // V-projection: transposed store via LDS
    const int n0v = n0 - 1536;
    u16* Ct = gsm;  // [128 n][136]
#pragma unroll
    for (int i = 0; i < 4; ++i)
#pragma unroll
      for (int j = 0; j < 4; ++j) {
        int nloc = wn + j * 16 + l15;
        float bc = bias[n0v + nloc];
#pragma unroll
        for (int r = 0; r < 4; ++r) {
          int mloc = wm + i * 16 + quad * 4 + r;
          Ct[nloc * 136 + mloc] = f2bf(acc[i][j][r] + bc);
        }
      }
    __syncthreads();
    int n = tid >> 1, half = tid & 1;
#pragma unroll
    for (int e = 0; e < 8; ++e) {
      int mloc = half * 64 + e * 8;
      if (m0 + mloc < M) {
        u16x8 v = *(const u16x8*)&Ct[n * 136 + mloc];
        *(u16x8*)(Vt + (size_t)(n0v + n) * ldt + m0 + mloc) = v;
      }
    }
  }
}

// ---------------- merged RMSNorm + RoPE for Q and K (one launch) -------------------
// bid < 3120: Q row. bid >= 3120: K row (sel-skipped if unselected).
__global__ __launch_bounds__(192) void norm_rope_all(
    u16* __restrict__ Xq, u16* __restrict__ Xk,
    const float* __restrict__ gq, const float* __restrict__ gk,
    const float* __restrict__ fc, const float* __restrict__ fs,
    const float* __restrict__ fch, const float* __restrict__ fsh,
    float qscale, const int* __restrict__ sel) {
  const int DIMc = 1536;
  int bidr = blockIdx.x;
  u16* X;
  const float *g, *fcp, *fsp;
  float oscale;
  int row;
  if (bidr < 3120) {
    X = Xq; g = gq; fcp = fc; fsp = fs; oscale = qscale; row = bidr;
  } else {
    row = bidr - 3120;
    if (!((sel_mask(sel) >> (row / 1560)) & 1)) return;
    X = Xk; g = gk; fcp = fch; fsp = fsh; oscale = 1.0f;
  }
  int tid = threadIdx.x;
  u16* xr = X + (size_t)row * DIMc + tid * 8;
  u16x8 v = *(const u16x8*)xr;
  float x[8];
  float ss = 0.f;
#pragma unroll
  for (int e = 0; e < 8; ++e) { x[e] = bf2f(v[e]); ss += x[e] * x[e]; }
#pragma unroll
  for (int m = 1; m < 64; m <<= 1) ss += __shfl_xor(ss, m);
  __shared__ float w3[3];
  if ((tid & 63) == 0) w3[tid >> 6] = ss;
  __syncthreads();
  float rs = rsqrtf((w3[0] + w3[1] + w3[2]) * (1.f / 1536.f) + 1e-5f);
  int dhb = (tid * 8) & 127;
  const float* fcr = fcp + (size_t)row * 128 + dhb;
  const float* fsr = fsp + (size_t)row * 128 + dhb;
  float4 c0 = *(const float4*)fcr, c1 = *(const float4*)(fcr + 4);
  float4 s0 = *(const float4*)fsr, s1 = *(const float4*)(fsr + 4);
  const float* gp = g + tid * 8;
  float4 g0 = *(const float4*)gp, g1 = *(const float4*)(gp + 4);
  float cosv[4] = {c0.x, c0.z, c1.x, c1.z};
  float sinv[4] = {s0.y, s0.w, s1.y, s1.w};
  float gv[8] = {g0.x, g0.y, g0.z, g0.w, g1.x, g1.y, g1.z, g1.w};
  u16x8 o;
#pragma unroll
  for (int p = 0; p < 4; ++p) {
    float a = x[2 * p] * rs * gv[2 * p];
    float b = x[2 * p + 1] * rs * gv[2 * p + 1];
    o[2 * p] = f2bf((a * cosv[p] - b * sinv[p]) * oscale);
    o[2 * p + 1] = f2bf((a * sinv[p] + b * cosv[p]) * oscale);
  }
  *(u16x8*)xr = o;
}

// ---------------- block-sparse attention v13: equal-length adaptive segmentation ----
__global__ __launch_bounds__(256, 3) void attn13(
    const u16* __restrict__ Q, const u16* __restrict__ Kb,
    const u16* __restrict__ VT, const int* __restrict__ sel,
    float* __restrict__ Oacc, float* __restrict__ Lp) {
  const int HWc = 1560, DIMc = 1536, KTt = 12480, NT = 600;
  __shared__ __align__(16) u16 smem[16384];  // Ks0|Ks1|Vt0|Vt1 (8 KB each)
  const int tid = threadIdx.x;
  const int lane = tid & 63, wid = tid >> 6;
  const int quad = lane >> 4, l15 = lane & 15;

  int bid = blockIdx.x;
  int xcd = bid & 7, idx = bid >> 3;   // idx 0..116
  int ug = idx / 13, mt = idx % 13;    // ug 0..8
  int u = xcd + 8 * ug;                // 0..71
  const int h = u / 6;
  const int slot = u % 6;

  // adaptive slot -> (t, seg)
  const int nch0 = (sel[1] >= 0) ? 98 : 49;
  const int nch1 = (sel[3] >= 0) ? 98 : 49;
  const int ns0 = 6 * nch0 / (nch0 + nch1);  // exact integer for all cases
  const int t = (slot < ns0) ? 0 : 1;
  const int si = (slot < ns0) ? slot : slot - ns0;
  const int nseg = (slot < ns0) ? ns0 : 6 - ns0;
  const int m0 = mt * 128;
  const int g = h * 2 + t;

  int s0v = sel[2 * t];
  const int b0 = s0v > 0 ? s0v : 0;
  const int b1 = sel[2 * t + 1];
  const int nk = (b1 >= 0) ? 2 * HWc : HWc;
  const int nch = (b1 >= 0) ? 98 : 49;
  const int cpseg = (nch + nseg - 1) / nseg;
  const int c0 = si * cpseg;
  const int c1 = (c0 + cpseg < nch) ? c0 + cpseg : nch;

  // Q B-frags: this wave's 32 q rows (2 sub-tiles of 16)
  u16x8 qf[2][4];
#pragma unroll
  for (int qt = 0; qt < 2; ++qt) {
    int qrow = m0 + wid * 32 + qt * 16 + l15;
    if (qrow > HWc - 1) qrow = HWc - 1;
    const u16* qp = Q + (size_t)(t * HWc + qrow) * DIMc + h * 128;
#pragma unroll
    for (int ks = 0; ks < 4; ++ks) qf[qt][ks] = *(const u16x8*)(qp + ks * 32 + quad * 8);
  }

  f32x4 oacc[2][8];  // partial O^T: [q-subtile][d-tile]
#pragma unroll
  for (int qt = 0; qt < 2; ++qt)
#pragma unroll
    for (int m = 0; m < 8; ++m)
#pragma unroll
      for (int r = 0; r < 4; ++r) oacc[qt][m][r] = 0.f;
  float lp[2] = {0.f, 0.f};

  auto stage = [&](int kc, int buf) {
    u16* Ks = smem + buf * 4096;
    u16* Vt = smem + 8192 + buf * 4096;
#pragma unroll
    for (int n = 0; n < 2; ++n) {
      int kl = wid * 8 + n * 4 + (lane >> 4);
      int gc = (lane & 15) ^ (kl & 15);
      int kg = kc + kl;
      if (kg >= nk) kg = 0;
      int big = kg >= HWc;
      int tok = (big ? b1 : b0) * HWc + kg - (big ? HWc : 0);
      glds16(Kb + ((size_t)tok * DIMc + h * 128 + gc * 8), Ks + (wid * 8 + n * 4) * 128);
    }
#pragma unroll
    for (int n = 0; n < 2; ++n) {
      int dl = wid * 32 + n * 16 + (lane >> 2);
      int gc = (lane & 3) ^ (dl & 3) ^ ((dl >> 2) & 3);
      int tg = kc + gc * 8;
      if (tg >= nk) tg = 0;
      int big = tg >= HWc;
      int tok = (big ? b1 : b0) * HWc + tg - (big ? HWc : 0);
      glds16(VT + ((size_t)(h * 128 + dl) * KTt + tok), Vt + (wid * 32 + n * 16) * 32);
    }
  };

  if (c0 < c1) stage(c0 * 32, 0);

  for (int c = c0; c < c1; ++c) {
    const int buf = (c - c0) & 1;
    u16* Ks = smem + buf * 4096;
    u16* Vt = smem + 8192 + buf * 4096;
    asm volatile("s_waitcnt vmcnt(0)\n\ts_barrier" ::: "memory");
    if (c + 1 < c1) stage((c + 1) * 32, buf ^ 1);

    f32x4 s[2][2];  // [gg][qt]
#pragma unroll
    for (int gg = 0; gg < 2; ++gg)
#pragma unroll
      for (int qt = 0; qt < 2; ++qt)
#pragma unroll
        for (int r = 0; r < 4; ++r) s[gg][qt][r] = 0.f;
#pragma unroll
    for (int ks = 0; ks < 4; ++ks)
#pragma unroll
      for (int gg = 0; gg < 2; ++gg) {
        u16x8 ka = *(const u16x8*)&Ks[(gg * 16 + l15) * 128 + (((ks * 4 + quad) ^ l15) * 8)];
#pragma unroll
        for (int qt = 0; qt < 2; ++qt) s[gg][qt] = mfma16(ka, qf[qt][ks], s[gg][qt]);
      }

    float p[2][2][4];
#pragma unroll
    for (int gg = 0; gg < 2; ++gg)
#pragma unroll
      for (int qt = 0; qt < 2; ++qt)
#pragma unroll
        for (int r = 0; r < 4; ++r) p[gg][qt][r] = exp2f(s[gg][qt][r]);
    if ((c + 1) * 32 > nk) {  // wave-uniform
#pragma unroll
      for (int gg = 0; gg < 2; ++gg)
#pragma unroll
        for (int r = 0; r < 4; ++r) {
          bool bad = c * 32 + gg * 16 + quad * 4 + r >= nk;
          if (bad) {
#pragma unroll
            for (int qt = 0; qt < 2; ++qt) p[gg][qt][r] = 0.f;
          }
        }
    }
    u16x4 pb[2][2];
#pragma unroll
    for (int gg = 0; gg < 2; ++gg)
#pragma unroll
      for (int qt = 0; qt < 2; ++qt)
#pragma unroll
        for (int r = 0; r < 4; ++r) {
          lp[qt] += p[gg][qt][r];
          pb[gg][qt][r] = f2bf_hw(p[gg][qt][r]);
        }

#pragma unroll
    for (int m = 0; m < 8; ++m) {
      int d = m * 16 + l15;
#pragma unroll
      for (int gg = 0; gg < 2; ++gg) {
        int sl = (gg * 2 + (quad >> 1)) ^ (d & 3) ^ ((d >> 2) & 3);
        u16x4 va = *(const u16x4*)&Vt[d * 32 + sl * 8 + (quad & 1) * 4];
#pragma unroll
        for (int qt = 0; qt < 2; ++qt) oacc[qt][m] = mfma16k16(va, pb[gg][qt], oacc[qt][m]);
      }
    }
  }

#pragma unroll
  for (int qt = 0; qt < 2; ++qt) {
    lp[qt] += __shfl_xor(lp[qt], 16);
    lp[qt] += __shfl_xor(lp[qt], 32);
  }
#pragma unroll
  for (int qt = 0; qt < 2; ++qt) {
    int qrow0 = m0 + wid * 32 + qt * 16;  // wave-uniform
    if (qrow0 < HWc) {
      size_t sb = ((size_t)si * NT + g * 25 + (qrow0 >> 6)) * 64 + (qrow0 & 63);
      if (lane < 16 && qrow0 + lane < HWc) Lp[sb + lane] = lp[qt];
      if (qrow0 + l15 < HWc) {
#pragma unroll
        for (int m = 0; m < 8; ++m)
          *(f32x4*)&Oacc[(sb + l15) * 128 + m * 16 + quad * 4] = oacc[qt][m];
      }
    }
  }
}

// ---------------- normalize: O = bf16(sum_seg Oacc / sum_seg Lp) ----------------
__global__ __launch_bounds__(256) void attn_norm(const float* __restrict__ Oacc,
                                                 const float* __restrict__ Lp,
                                                 const int* __restrict__ sel,
                                                 u16* __restrict__ O) {
  const int HWc = 1560, DIMc = 1536, NT = 600;
  int tile = blockIdx.x;  // 600
  int g = tile / 25, mt = tile % 25;
  int h = g >> 1, t = g & 1;
  int m0 = mt * 64;
  int tid = threadIdx.x;
  const int nch0 = (sel[1] >= 0) ? 98 : 49;
  const int nch1 = (sel[3] >= 0) ? 98 : 49;
  const int ns0 = 6 * nch0 / (nch0 + nch1);
  const int nseg = (t == 0) ? ns0 : 6 - ns0;
#pragma unroll
  for (int e = 0; e < 8; ++e) {
    int idx = e * 256 + tid;   // 0..2047 f32x4 slots (64 q x 32)
    int qloc = idx >> 5;
    int d4 = (idx & 31) * 4;
    int q = m0 + qloc;
    if (q < HWc) {
      f32x4 a = {0.f, 0.f, 0.f, 0.f};
      float l = 0.f;
      for (int s = 0; s < nseg; ++s) {
        const size_t sbase = ((size_t)s * NT + tile) * 64 + qloc;
        f32x4 v = *(const f32x4*)&Oacc[sbase * 128 + d4];
#pragma unroll
        for (int r = 0; r < 4; ++r) a[r] += v[r];
        l += Lp[sbase];
      }
      float linv = 1.f / l;
      u16x4 o;
#pragma unroll
      for (int r = 0; r < 4; ++r) o[r] = f2bf(a[r] * linv);
      *(u16x4*)(O + (size_t)(t * HWc + q) * DIMc + h * 128 + d4) = o;
    }
  }
}

extern "C" void kernel_launch(void* const* d_in, const int* in_sizes, int n_in,
                              void* d_out, int out_size, void* d_ws, size_t ws_size,
                              hipStream_t stream) {
  const float* hs  = (const float*)d_in[0];
  const float* his = (const float*)d_in[1];
  const float* fc  = (const float*)d_in[2];
  const float* fs  = (const float*)d_in[3];
  const float* fch = (const float*)d_in[4];
  const float* fsh = (const float*)d_in[5];
  const int*   sel = (const int*)d_in[6];
  const float* Wq  = (const float*)d_in[7];
  const float* bq  = (const float*)d_in[8];
  const float* Wk  = (const float*)d_in[9];
  const float* bk  = (const float*)d_in[10];
  const float* Wv  = (const float*)d_in[11];
  const float* bv  = (const float*)d_in[12];
  const float* Wo  = (const float*)d_in[13];
  const float* bo  = (const float*)d_in[14];
  const float* gq  = (const float*)d_in[15];
  const float* gk  = (const float*)d_in[16];

  const int QT = 3120, KT = 12480, DIMc = 1536;
  u16* p = (u16*)d_ws;
  u16* qb  = p; p += (size_t)QT * DIMc;
  u16* kb2 = p; p += (size_t)KT * DIMc;
  u16* vt  = p; p += (size_t)DIMc * KT;   // V^T [1536][12480]
  u16* ab  = p; p += (size_t)QT * DIMc;
  u16* wob = p; p += (size_t)DIMc * DIMc;
  u16* scratch = p;
  u16* hsb = scratch;
  u16* hib = hsb + (size_t)QT * DIMc;
  u16* wqb = hib + (size_t)KT * DIMc;
  u16* wkb = wqb + (size_t)DIMc * DIMc;   // wkb and wvb adjacent -> stacked [3072][1536]
  u16* wvb = wkb + (size_t)DIMc * DIMc;
  float* oaccb = (float*)scratch;                      // f32 [4][600][64][128]
  float* lpb   = oaccb + (size_t)4 * 600 * 64 * 128;   // f32 [4][600][64]

  cvt_all<<<dim3(32616), 256, 0, stream>>>(hs, his, Wq, Wk, Wv, Wo,
                                           hsb, hib, wqb, wkb, wvb, wob, sel);

  gemm_qkv<<<dim3(2652), 256, 0, stream>>>(hsb, hib, wqb, wkb, bq, bk, bv,
                                           qb, kb2, vt, sel, KT);

  const float qscale = (float)(0.08838834764831845 * 1.4426950408889634);
  norm_rope_all<<<dim3(QT + KT), 192, 0, stream>>>(qb, kb2, gq, gk, fc, fs, fch, fsh,
                                                   qscale, sel);

  // attn13 clobbers hsb/hib/wq/wk/wv (all dead by now); wob stays live for the final gemm.
  attn13<<<dim3(936), 256, 0, stream>>>(qb, kb2, vt, sel, oaccb, lpb);
  attn_norm<<<dim3(600), 256, 0, stream>>>(oaccb, lpb, sel, ab);

  gemm_v2<1, 12><<<dim3(300), 256, 0, stream>>>(ab, wob, bo, d_out, QT);
}

// Round 16
// 415.475 us; speedup vs baseline: 1.4157x; 1.0907x over previous
//
#include <hip/hip_runtime.h>

typedef unsigned short u16;
typedef __attribute__((ext_vector_type(4))) unsigned short u16x4;
typedef __attribute__((ext_vector_type(8))) unsigned short u16x8;
typedef __attribute__((ext_vector_type(4))) short s16x4;
typedef __attribute__((ext_vector_type(4))) float f32x4;
typedef __attribute__((ext_vector_type(8))) __bf16 bf16x8;

__device__ __forceinline__ u16 f2bf(float f) {
  union { float f; unsigned int u; } v; v.f = f;
  unsigned int u = v.u;
  unsigned int r = (u + 0x7fffu + ((u >> 16) & 1u)) >> 16;
  return (u16)r;
}
__device__ __forceinline__ u16 f2bf_hw(float f) {  // RNE via HW convert
  return __builtin_bit_cast(u16, (__bf16)f);
}
__device__ __forceinline__ float bf2f(u16 h) {
  union { unsigned int u; float f; } v; v.u = ((unsigned int)h) << 16;
  return v.f;
}
__device__ __forceinline__ f32x4 mfma16(u16x8 a, u16x8 b, f32x4 c) {
  return __builtin_amdgcn_mfma_f32_16x16x32_bf16(
      __builtin_bit_cast(bf16x8, a), __builtin_bit_cast(bf16x8, b), c, 0, 0, 0);
}
// K=16 variant: A/B are 4 bf16 (2 VGPRs)
__device__ __forceinline__ f32x4 mfma16k16(u16x4 a, u16x4 b, f32x4 c) {
  return __builtin_amdgcn_mfma_f32_16x16x16bf16_1k(
      __builtin_bit_cast(s16x4, a), __builtin_bit_cast(s16x4, b), c, 0, 0, 0);
}
// async global->LDS, 16B per lane; LDS dest = wave-uniform base + lane*16
__device__ __forceinline__ void glds16(const void* g, void* l) {
  __builtin_amdgcn_global_load_lds((const __attribute__((address_space(1))) void*)g,
                                   (__attribute__((address_space(3))) void*)l, 16, 0, 0);
}
// bijective XCD-chunked remap: XCD x (= bid&7 empirically) owns a contiguous
// logical-tile range -> blocks sharing operand panels are L2-co-resident.
__device__ __forceinline__ int xcd_chunk(int bid, int nwg) {
  int xcd = bid & 7, idx = bid >> 3;
  int q = nwg >> 3, r = nwg & 7;
  int base = xcd < r ? xcd * (q + 1) : r * (q + 1) + (xcd - r) * q;
  return base + idx;
}
// selected token-block mask from sel[4]: {clip(b0), b1 if >=0} per t.
__device__ __forceinline__ int sel_mask(const int* __restrict__ sel) {
  int m = 0;
#pragma unroll
  for (int tt = 0; tt < 2; ++tt) {
    int a = sel[2 * tt];
    if (a < 0) a = 0;
    m |= 1 << a;
    int b = sel[2 * tt + 1];
    if (b >= 0) m |= 1 << b;
  }
  return m;
}

// ---------------- fused fp32 -> bf16 conversion; his rows sel-predicated ----------
__global__ __launch_bounds__(256) void cvt_all(
    const float* __restrict__ hs, const float* __restrict__ his,
    const float* __restrict__ Wq, const float* __restrict__ Wk,
    const float* __restrict__ Wv, const float* __restrict__ Wo,
    u16* __restrict__ hsb, u16* __restrict__ hib,
    u16* __restrict__ wqb, u16* __restrict__ wkb,
    u16* __restrict__ wvb, u16* __restrict__ wob,
    const int* __restrict__ sel) {
  // f4-chunk boundaries (all /256 -> block-uniform branch)
  const int N0 = 1198080, N1 = 5990400, N2 = 6580224, N3 = 7170048, N4 = 7759872;
  int i = blockIdx.x * 256 + threadIdx.x;
  const float* s; u16* o; int base;
  if (i < N0)      { s = hs;  o = hsb; base = 0;  }
  else if (i < N1) { s = his; o = hib; base = N0; }
  else if (i < N2) { s = Wq;  o = wqb; base = N1; }
  else if (i < N3) { s = Wk;  o = wkb; base = N2; }
  else if (i < N4) { s = Wv;  o = wvb; base = N3; }
  else             { s = Wo;  o = wob; base = N4; }
  int j = i - base;
  if (base == N0) {  // his region: skip rows in unselected token-blocks (never read)
    int row = j / 384;                 // 384 f4 per 1536-col row
    if (!((sel_mask(sel) >> (row / 1560)) & 1)) return;
  }
  float4 v = ((const float4*)s)[j];
  u16x4 r;
  r.x = f2bf(v.x); r.y = f2bf(v.y); r.z = f2bf(v.z); r.w = f2bf(v.w);
  ((u16x4*)o)[j] = r;
}

// ---------------- GEMM: C[M,1536] = A[M,1536] @ W[1536,1536]^T + bias ----------------
// (used for the output projection only now)
template <int OUT, int NBX>  // OUT: 0 = bf16, 1 = f32
__global__ __launch_bounds__(256, 2) void gemm_v2(
    const u16* __restrict__ A, const u16* __restrict__ W,
    const float* __restrict__ bias, void* __restrict__ Cp, int M) {
  const int K = 1536, N = 1536;
  __shared__ __align__(16) u16 gsm[17408];
  u16* As = gsm;
  u16* Bs = gsm + 8192;
  const int tid = threadIdx.x;
  const int lane = tid & 63, wid = tid >> 6;
  const int quad = lane >> 4, l15 = lane & 15;
  const int lg = xcd_chunk(blockIdx.x, gridDim.x);
  const int m0 = (lg / NBX) * 128, n0 = (lg % NBX) * 128;
  const int wm = (wid >> 1) * 64, wn = (wid & 1) * 64;
  f32x4 acc[4][4];
#pragma unroll
  for (int i = 0; i < 4; ++i)
#pragma unroll
    for (int j = 0; j < 4; ++j)
#pragma unroll
      for (int r = 0; r < 4; ++r) acc[i][j][r] = 0.f;

  const int r8 = lane >> 3, c8 = lane & 7;
  const int gch = c8 ^ r8;

  for (int k0 = 0; k0 < K; k0 += 64) {
#pragma unroll
    for (int inst = 0; inst < 4; ++inst) {
      int row = wid * 32 + inst * 8 + r8;
      glds16(A + ((size_t)(m0 + row) * K + k0 + gch * 8), As + (wid * 32 + inst * 8) * 64);
      glds16(W + ((size_t)(n0 + row) * K + k0 + gch * 8), Bs + (wid * 32 + inst * 8) * 64);
    }
    asm volatile("s_waitcnt vmcnt(0)" ::: "memory");
    __syncthreads();
#pragma unroll
    for (int ks = 0; ks < 2; ++ks) {
      u16x8 af[4], bfr[4];
#pragma unroll
      for (int i = 0; i < 4; ++i) {
        int row = wm + i * 16 + l15;
        af[i] = *(const u16x8*)&As[row * 64 + (((ks * 4 + quad) ^ (l15 & 7)) * 8)];
      }
#pragma unroll
      for (int j = 0; j < 4; ++j) {
        int row = wn + j * 16 + l15;
        bfr[j] = *(const u16x8*)&Bs[row * 64 + (((ks * 4 + quad) ^ (l15 & 7)) * 8)];
      }
#pragma unroll
      for (int i = 0; i < 4; ++i)
#pragma unroll
        for (int j = 0; j < 4; ++j) acc[i][j] = mfma16(af[i], bfr[j], acc[i][j]);
    }
    __syncthreads();
  }

#pragma unroll
  for (int i = 0; i < 4; ++i) {
    int row = m0 + wm + i * 16 + quad * 4;
#pragma unroll
    for (int j = 0; j < 4; ++j) {
      int col = n0 + wn + j * 16 + l15;
      float bc = bias[col];
#pragma unroll
      for (int r = 0; r < 4; ++r) {
        if (row + r < M) {
          float v = acc[i][j][r] + bc;
          if (OUT == 1)
            ((float*)Cp)[(size_t)(row + r) * N + col] = v;
          else
            ((u16*)Cp)[(size_t)(row + r) * N + col] = f2bf(v);
        }
      }
    }
  }
}

// ---------------- merged Q + K + V projection GEMM, XCD-balanced (R16) -------------
// R15 bug: xcd_chunk put ALL 300 Q-blocks on XCD 0 (contiguous lg 0..299) -> XCD 0
// ran ~5 rounds while others ran ~2.6 and idled; MfmaUtil 19%. Now decode directly
// from (xcd = bid&7, idx = bid>>3), grid 2656 = 8 x 332: first qn[xcd] indices are
// Q-tiles (38 for xcd<4, 37 for xcd>=4 -> exactly 300, bijective), remaining 294 are
// the KV blocks with the SAME n-quartered + scattered-m + sel-early-exit mapping
// (2352 = 8*294, byte-identical lg assignment). xcd>=4 idx 331 returns immediately.
__global__ __launch_bounds__(256, 2) void gemm_qkv(
    const u16* __restrict__ Aq, const u16* __restrict__ Akv,
    const u16* __restrict__ Wqp, const u16* __restrict__ Wkv,
    const float* __restrict__ bq, const float* __restrict__ bk,
    const float* __restrict__ bv,
    u16* __restrict__ Cq, u16* __restrict__ Ck, u16* __restrict__ Vt,
    const int* __restrict__ sel, int ldt) {
  const int K = 1536;
  __shared__ __align__(16) u16 gsm[17408];
  u16* As = gsm;
  u16* Bs = gsm + 8192;
  const int tid = threadIdx.x;
  const int lane = tid & 63, wid = tid >> 6;
  const int quad = lane >> 4, l15 = lane & 15;
  const int xcd = blockIdx.x & 7, idx = blockIdx.x >> 3;
  const int qn = (xcd < 4) ? 38 : 37;

  const u16 *A, *W;
  const float* bias;
  u16* out;
  int m0, n0, M, vmode;
  if (idx < qn) {  // Q-projection tile (balanced across XCDs)
    int qid = (xcd < 4 ? xcd * 38 : 152 + (xcd - 4) * 37) + idx;  // 0..299
    A = Aq; W = Wqp; bias = bq; out = Cq;
    m0 = (qid / 12) * 128; n0 = (qid % 12) * 128; M = 3120; vmode = 0;
  } else {  // KV-projection
    int kidx = idx - qn;
    if (kidx >= 294) return;           // xcd>=4 spare slot
    int L2 = xcd * 294 + kidx;         // 0..2351, same assignment as R15
    int qtr = L2 / 588, rem = L2 % 588;   // 588 = 98 m x 6 n per quarter
    int mi = rem / 6;
    m0 = ((mi * 25) % 98) * 128;          // scattered m-panel (bijective, 25⊥98)
    n0 = (qtr * 6 + rem % 6) * 128;       // 0..2944
    {  // selection-aware early exit
      int mask = sel_mask(sel);
      int tb0 = m0 / 1560, tb1 = (m0 + 127) / 1560;
      if (!((mask >> tb0) & 1) && !((mask >> tb1) & 1)) return;
    }
    A = Akv; W = Wkv; M = 12480;
    if (n0 < 1536) { bias = bk; out = Ck; vmode = 0; }
    else { bias = bv; out = nullptr; vmode = 1; }
  }

  const int wm = (wid >> 1) * 64, wn = (wid & 1) * 64;
  f32x4 acc[4][4];
#pragma unroll
  for (int i = 0; i < 4; ++i)
#pragma unroll
    for (int j = 0; j < 4; ++j)
#pragma unroll
      for (int r = 0; r < 4; ++r) acc[i][j][r] = 0.f;

  const int r8 = lane >> 3, c8 = lane & 7;
  const int gch = c8 ^ r8;

  for (int k0 = 0; k0 < K; k0 += 64) {
#pragma unroll
    for (int inst = 0; inst < 4; ++inst) {
      int row = wid * 32 + inst * 8 + r8;
      glds16(A + ((size_t)(m0 + row) * K + k0 + gch * 8), As + (wid * 32 + inst * 8) * 64);
      glds16(W + ((size_t)(n0 + row) * K + k0 + gch * 8), Bs + (wid * 32 + inst * 8) * 64);
    }
    asm volatile("s_waitcnt vmcnt(0)" ::: "memory");
    __syncthreads();
#pragma unroll
    for (int ks = 0; ks < 2; ++ks) {
      u16x8 af[4], bfr[4];
#pragma unroll
      for (int i = 0; i < 4; ++i) {
        int row = wm + i * 16 + l15;
        af[i] = *(const u16x8*)&As[row * 64 + (((ks * 4 + quad) ^ (l15 & 7)) * 8)];
      }
#pragma unroll
      for (int j = 0; j < 4; ++j) {
        int row = wn + j * 16 + l15;
        bfr[j] = *(const u16x8*)&Bs[row * 64 + (((ks * 4 + quad) ^ (l15 & 7)) * 8)];
      }
#pragma unroll
      for (int i = 0; i < 4; ++i)
#pragma unroll
        for (int j = 0; j < 4; ++j) acc[i][j] = mfma16(af[i], bfr[j], acc[i][j]);
    }
    __syncthreads();
  }

  if (vmode == 0) {  // plain bf16 store (Q-proj or K-proj)
#pragma unroll
    for (int i = 0; i < 4; ++i) {
      int row = m0 + wm + i * 16 + quad * 4;
#pragma unroll
      for (int j = 0; j < 4; ++j) {
        int col = n0 + wn + j * 16 + l15;
        float bc = bias[col];
#pragma unroll
        for (int r = 0; r < 4; ++r) {
          if (row + r < M)
            out[(size_t)(row + r) * 1536 + col] = f2bf(acc[i][j][r] + bc);
        }
      }
    }
  } else {  // V-projection: transposed store via LDS
    const int n0v = n0 - 1536;
    u16* Ct = gsm;  // [128 n][136]
#pragma unroll
    for (int i = 0; i < 4; ++i)
#pragma unroll
      for (int j = 0; j < 4; ++j) {
        int nloc = wn + j * 16 + l15;
        float bc = bias[n0v + nloc];
#pragma unroll
        for (int r = 0; r < 4; ++r) {
          int mloc = wm + i * 16 + quad * 4 + r;
          Ct[nloc * 136 + mloc] = f2bf(acc[i][j][r] + bc);
        }
      }
    __syncthreads();
    int n = tid >> 1, half = tid & 1;
#pragma unroll
    for (int e = 0; e < 8; ++e) {
      int mloc = half * 64 + e * 8;
      if (m0 + mloc < M) {
        u16x8 v = *(const u16x8*)&Ct[n * 136 + mloc];
        *(u16x8*)(Vt + (size_t)(n0v + n) * ldt + m0 + mloc) = v;
      }
    }
  }
}

// ---------------- merged RMSNorm + RoPE for Q and K (one launch) -------------------
// bid < 3120: Q row. bid >= 3120: K row (sel-skipped if unselected).
__global__ __launch_bounds__(192) void norm_rope_all(
    u16* __restrict__ Xq, u16* __restrict__ Xk,
    const float* __restrict__ gq, const float* __restrict__ gk,
    const float* __restrict__ fc, const float* __restrict__ fs,
    const float* __restrict__ fch, const float* __restrict__ fsh,
    float qscale, const int* __restrict__ sel) {
  const int DIMc = 1536;
  int bidr = blockIdx.x;
  u16* X;
  const float *g, *fcp, *fsp;
  float oscale;
  int row;
  if (bidr < 3120) {
    X = Xq; g = gq; fcp = fc; fsp = fs; oscale = qscale; row = bidr;
  } else {
    row = bidr - 3120;
    if (!((sel_mask(sel) >> (row / 1560)) & 1)) return;
    X = Xk; g = gk; fcp = fch; fsp = fsh; oscale = 1.0f;
  }
  int tid = threadIdx.x;
  u16* xr = X + (size_t)row * DIMc + tid * 8;
  u16x8 v = *(const u16x8*)xr;
  float x[8];
  float ss = 0.f;
#pragma unroll
  for (int e = 0; e < 8; ++e) { x[e] = bf2f(v[e]); ss += x[e] * x[e]; }
#pragma unroll
  for (int m = 1; m < 64; m <<= 1) ss += __shfl_xor(ss, m);
  __shared__ float w3[3];
  if ((tid & 63) == 0) w3[tid >> 6] = ss;
  __syncthreads();
  float rs = rsqrtf((w3[0] + w3[1] + w3[2]) * (1.f / 1536.f) + 1e-5f);
  int dhb = (tid * 8) & 127;
  const float* fcr = fcp + (size_t)row * 128 + dhb;
  const float* fsr = fsp + (size_t)row * 128 + dhb;
  float4 c0 = *(const float4*)fcr, c1 = *(const float4*)(fcr + 4);
  float4 s0 = *(const float4*)fsr, s1 = *(const float4*)(fsr + 4);
  const float* gp = g + tid * 8;
  float4 g0 = *(const float4*)gp, g1 = *(const float4*)(gp + 4);
  float cosv[4] = {c0.x, c0.z, c1.x, c1.z};
  float sinv[4] = {s0.y, s0.w, s1.y, s1.w};
  float gv[8] = {g0.x, g0.y, g0.z, g0.w, g1.x, g1.y, g1.z, g1.w};
  u16x8 o;
#pragma unroll
  for (int p = 0; p < 4; ++p) {
    float a = x[2 * p] * rs * gv[2 * p];
    float b = x[2 * p + 1] * rs * gv[2 * p + 1];
    o[2 * p] = f2bf((a * cosv[p] - b * sinv[p]) * oscale);
    o[2 * p + 1] = f2bf((a * sinv[p] + b * cosv[p]) * oscale);
  }
  *(u16x8*)xr = o;
}

// ---------------- block-sparse attention v13: equal-length adaptive segmentation ----
__global__ __launch_bounds__(256, 3) void attn13(
    const u16* __restrict__ Q, const u16* __restrict__ Kb,
    const u16* __restrict__ VT, const int* __restrict__ sel,
    float* __restrict__ Oacc, float* __restrict__ Lp) {
  const int HWc = 1560, DIMc = 1536, KTt = 12480, NT = 600;
  __shared__ __align__(16) u16 smem[16384];  // Ks0|Ks1|Vt0|Vt1 (8 KB each)
  const int tid = threadIdx.x;
  const int lane = tid & 63, wid = tid >> 6;
  const int quad = lane >> 4, l15 = lane & 15;

  int bid = blockIdx.x;
  int xcd = bid & 7, idx = bid >> 3;   // idx 0..116
  int ug = idx / 13, mt = idx % 13;    // ug 0..8
  int u = xcd + 8 * ug;                // 0..71
  const int h = u / 6;
  const int slot = u % 6;

  // adaptive slot -> (t, seg)
  const int nch0 = (sel[1] >= 0) ? 98 : 49;
  const int nch1 = (sel[3] >= 0) ? 98 : 49;
  const int ns0 = 6 * nch0 / (nch0 + nch1);  // exact integer for all cases
  const int t = (slot < ns0) ? 0 : 1;
  const int si = (slot < ns0) ? slot : slot - ns0;
  const int nseg = (slot < ns0) ? ns0 : 6 - ns0;
  const int m0 = mt * 128;
  const int g = h * 2 + t;

  int s0v = sel[2 * t];
  const int b0 = s0v > 0 ? s0v : 0;
  const int b1 = sel[2 * t + 1];
  const int nk = (b1 >= 0) ? 2 * HWc : HWc;
  const int nch = (b1 >= 0) ? 98 : 49;
  const int cpseg = (nch + nseg - 1) / nseg;
  const int c0 = si * cpseg;
  const int c1 = (c0 + cpseg < nch) ? c0 + cpseg : nch;

  // Q B-frags: this wave's 32 q rows (2 sub-tiles of 16)
  u16x8 qf[2][4];
#pragma unroll
  for (int qt = 0; qt < 2; ++qt) {
    int qrow = m0 + wid * 32 + qt * 16 + l15;
    if (qrow > HWc - 1) qrow = HWc - 1;
    const u16* qp = Q + (size_t)(t * HWc + qrow) * DIMc + h * 128;
#pragma unroll
    for (int ks = 0; ks < 4; ++ks) qf[qt][ks] = *(const u16x8*)(qp + ks * 32 + quad * 8);
  }

  f32x4 oacc[2][8];  // partial O^T: [q-subtile][d-tile]
#pragma unroll
  for (int qt = 0; qt < 2; ++qt)
#pragma unroll
    for (int m = 0; m < 8; ++m)
#pragma unroll
      for (int r = 0; r < 4; ++r) oacc[qt][m][r] = 0.f;
  float lp[2] = {0.f, 0.f};

  auto stage = [&](int kc, int buf) {
    u16* Ks = smem + buf * 4096;
    u16* Vt = smem + 8192 + buf * 4096;
#pragma unroll
    for (int n = 0; n < 2; ++n) {
      int kl = wid * 8 + n * 4 + (lane >> 4);
      int gc = (lane & 15) ^ (kl & 15);
      int kg = kc + kl;
      if (kg >= nk) kg = 0;
      int big = kg >= HWc;
      int tok = (big ? b1 : b0) * HWc + kg - (big ? HWc : 0);
      glds16(Kb + ((size_t)tok * DIMc + h * 128 + gc * 8), Ks + (wid * 8 + n * 4) * 128);
    }
#pragma unroll
    for (int n = 0; n < 2; ++n) {
      int dl = wid * 32 + n * 16 + (lane >> 2);
      int gc = (lane & 3) ^ (dl & 3) ^ ((dl >> 2) & 3);
      int tg = kc + gc * 8;
      if (tg >= nk) tg = 0;
      int big = tg >= HWc;
      int tok = (big ? b1 : b0) * HWc + tg - (big ? HWc : 0);
      glds16(VT + ((size_t)(h * 128 + dl) * KTt + tok), Vt + (wid * 32 + n * 16) * 32);
    }
  };

  if (c0 < c1) stage(c0 * 32, 0);

  for (int c = c0; c < c1; ++c) {
    const int buf = (c - c0) & 1;
    u16* Ks = smem + buf * 4096;
    u16* Vt = smem + 8192 + buf * 4096;
    asm volatile("s_waitcnt vmcnt(0)\n\ts_barrier" ::: "memory");
    if (c + 1 < c1) stage((c + 1) * 32, buf ^ 1);

    f32x4 s[2][2];  // [gg][qt]
#pragma unroll
    for (int gg = 0; gg < 2; ++gg)
#pragma unroll
      for (int qt = 0; qt < 2; ++qt)
#pragma unroll
        for (int r = 0; r < 4; ++r) s[gg][qt][r] = 0.f;
#pragma unroll
    for (int ks = 0; ks < 4; ++ks)
#pragma unroll
      for (int gg = 0; gg < 2; ++gg) {
        u16x8 ka = *(const u16x8*)&Ks[(gg * 16 + l15) * 128 + (((ks * 4 + quad) ^ l15) * 8)];
#pragma unroll
        for (int qt = 0; qt < 2; ++qt) s[gg][qt] = mfma16(ka, qf[qt][ks], s[gg][qt]);
      }

    float p[2][2][4];
#pragma unroll
    for (int gg = 0; gg < 2; ++gg)
#pragma unroll
      for (int qt = 0; qt < 2; ++qt)
#pragma unroll
        for (int r = 0; r < 4; ++r) p[gg][qt][r] = exp2f(s[gg][qt][r]);
    if ((c + 1) * 32 > nk) {  // wave-uniform
#pragma unroll
      for (int gg = 0; gg < 2; ++gg)
#pragma unroll
        for (int r = 0; r < 4; ++r) {
          bool bad = c * 32 + gg * 16 + quad * 4 + r >= nk;
          if (bad) {
#pragma unroll
            for (int qt = 0; qt < 2; ++qt) p[gg][qt][r] = 0.f;
          }
        }
    }
    u16x4 pb[2][2];
#pragma unroll
    for (int gg = 0; gg < 2; ++gg)
#pragma unroll
      for (int qt = 0; qt < 2; ++qt)
#pragma unroll
        for (int r = 0; r < 4; ++r) {
          lp[qt] += p[gg][qt][r];
          pb[gg][qt][r] = f2bf_hw(p[gg][qt][r]);
        }

#pragma unroll
    for (int m = 0; m < 8; ++m) {
      int d = m * 16 + l15;
#pragma unroll
      for (int gg = 0; gg < 2; ++gg) {
        int sl = (gg * 2 + (quad >> 1)) ^ (d & 3) ^ ((d >> 2) & 3);
        u16x4 va = *(const u16x4*)&Vt[d * 32 + sl * 8 + (quad & 1) * 4];
#pragma unroll
        for (int qt = 0; qt < 2; ++qt) oacc[qt][m] = mfma16k16(va, pb[gg][qt], oacc[qt][m]);
      }
    }
  }

#pragma unroll
  for (int qt = 0; qt < 2; ++qt) {
    lp[qt] += __shfl_xor(lp[qt], 16);
    lp[qt] += __shfl_xor(lp[qt], 32);
  }
#pragma unroll
  for (int qt = 0; qt < 2; ++qt) {
    int qrow0 = m0 + wid * 32 + qt * 16;  // wave-uniform
    if (qrow0 < HWc) {
      size_t sb = ((size_t)si * NT + g * 25 + (qrow0 >> 6)) * 64 + (qrow0 & 63);
      if (lane < 16 && qrow0 + lane < HWc) Lp[sb + lane] = lp[qt];
      if (qrow0 + l15 < HWc) {
#pragma unroll
        for (int m = 0; m < 8; ++m)
          *(f32x4*)&Oacc[(sb + l15) * 128 + m * 16 + quad * 4] = oacc[qt][m];
      }
    }
  }
}

// ---------------- normalize: O = bf16(sum_seg Oacc / sum_seg Lp) ----------------
__global__ __launch_bounds__(256) void attn_norm(const float* __restrict__ Oacc,
                                                 const float* __restrict__ Lp,
                                                 const int* __restrict__ sel,
                                                 u16* __restrict__ O) {
  const int HWc = 1560, DIMc = 1536, NT = 600;
  int tile = blockIdx.x;  // 600
  int g = tile / 25, mt = tile % 25;
  int h = g >> 1, t = g & 1;
  int m0 = mt * 64;
  int tid = threadIdx.x;
  const int nch0 = (sel[1] >= 0) ? 98 : 49;
  const int nch1 = (sel[3] >= 0) ? 98 : 49;
  const int ns0 = 6 * nch0 / (nch0 + nch1);
  const int nseg = (t == 0) ? ns0 : 6 - ns0;
#pragma unroll
  for (int e = 0; e < 8; ++e) {
    int idx = e * 256 + tid;   // 0..2047 f32x4 slots (64 q x 32)
    int qloc = idx >> 5;
    int d4 = (idx & 31) * 4;
    int q = m0 + qloc;
    if (q < HWc) {
      f32x4 a = {0.f, 0.f, 0.f, 0.f};
      float l = 0.f;
      for (int s = 0; s < nseg; ++s) {
        const size_t sbase = ((size_t)s * NT + tile) * 64 + qloc;
        f32x4 v = *(const f32x4*)&Oacc[sbase * 128 + d4];
#pragma unroll
        for (int r = 0; r < 4; ++r) a[r] += v[r];
        l += Lp[sbase];
      }
      float linv = 1.f / l;
      u16x4 o;
#pragma unroll
      for (int r = 0; r < 4; ++r) o[r] = f2bf(a[r] * linv);
      *(u16x4*)(O + (size_t)(t * HWc + q) * DIMc + h * 128 + d4) = o;
    }
  }
}

extern "C" void kernel_launch(void* const* d_in, const int* in_sizes, int n_in,
                              void* d_out, int out_size, void* d_ws, size_t ws_size,
                              hipStream_t stream) {
  const float* hs  = (const float*)d_in[0];
  const float* his = (const float*)d_in[1];
  const float* fc  = (const float*)d_in[2];
  const float* fs  = (const float*)d_in[3];
  const float* fch = (const float*)d_in[4];
  const float* fsh = (const float*)d_in[5];
  const int*   sel = (const int*)d_in[6];
  const float* Wq  = (const float*)d_in[7];
  const float* bq  = (const float*)d_in[8];
  const float* Wk  = (const float*)d_in[9];
  const float* bk  = (const float*)d_in[10];
  const float* Wv  = (const float*)d_in[11];
  const float* bv  = (const float*)d_in[12];
  const float* Wo  = (const float*)d_in[13];
  const float* bo  = (const float*)d_in[14];
  const float* gq  = (const float*)d_in[15];
  const float* gk  = (const float*)d_in[16];

  const int QT = 3120, KT = 12480, DIMc = 1536;
  u16* p = (u16*)d_ws;
  u16* qb  = p; p += (size_t)QT * DIMc;
  u16* kb2 = p; p += (size_t)KT * DIMc;
  u16* vt  = p; p += (size_t)DIMc * KT;   // V^T [1536][12480]
  u16* ab  = p; p += (size_t)QT * DIMc;
  u16* wob = p; p += (size_t)DIMc * DIMc;
  u16* scratch = p;
  u16* hsb = scratch;
  u16* hib = hsb + (size_t)QT * DIMc;
  u16* wqb = hib + (size_t)KT * DIMc;
  u16* wkb = wqb + (size_t)DIMc * DIMc;   // wkb and wvb adjacent -> stacked [3072][1536]
  u16* wvb = wkb + (size_t)DIMc * DIMc;
  float* oaccb = (float*)scratch;                      // f32 [4][600][64][128]
  float* lpb   = oaccb + (size_t)4 * 600 * 64 * 128;   // f32 [4][600][64]

  cvt_all<<<dim3(32616), 256, 0, stream>>>(hs, his, Wq, Wk, Wv, Wo,
                                           hsb, hib, wqb, wkb, wvb, wob, sel);

  gemm_qkv<<<dim3(2656), 256, 0, stream>>>(hsb, hib, wqb, wkb, bq, bk, bv,
                                           qb, kb2, vt, sel, KT);

  const float qscale = (float)(0.08838834764831845 * 1.4426950408889634);
  norm_rope_all<<<dim3(QT + KT), 192, 0, stream>>>(qb, kb2, gq, gk, fc, fs, fch, fsh,
                                                   qscale, sel);

  // attn13 clobbers hsb/hib/wq/wk/wv (all dead by now); wob stays live for the final gemm.
  attn13<<<dim3(936), 256, 0, stream>>>(qb, kb2, vt, sel, oaccb, lpb);
  attn_norm<<<dim3(600), 256, 0, stream>>>(oaccb, lpb, sel, ab);

  gemm_v2<1, 12><<<dim3(300), 256, 0, stream>>>(ab, wob, bo, d_out, QT);
}

// Round 17
// 412.604 us; speedup vs baseline: 1.4256x; 1.0070x over previous
//
#include <hip/hip_runtime.h>

typedef unsigned short u16;
typedef __attribute__((ext_vector_type(4))) unsigned short u16x4;
typedef __attribute__((ext_vector_type(8))) unsigned short u16x8;
typedef __attribute__((ext_vector_type(4))) short s16x4;
typedef __attribute__((ext_vector_type(4))) float f32x4;
typedef __attribute__((ext_vector_type(8))) __bf16 bf16x8;

__device__ __forceinline__ u16 f2bf(float f) {
  union { float f; unsigned int u; } v; v.f = f;
  unsigned int u = v.u;
  unsigned int r = (u + 0x7fffu + ((u >> 16) & 1u)) >> 16;
  return (u16)r;
}
__device__ __forceinline__ u16 f2bf_hw(float f) {  // RNE via HW convert
  return __builtin_bit_cast(u16, (__bf16)f);
}
__device__ __forceinline__ float bf2f(u16 h) {
  union { unsigned int u; float f; } v; v.u = ((unsigned int)h) << 16;
  return v.f;
}
__device__ __forceinline__ f32x4 mfma16(u16x8 a, u16x8 b, f32x4 c) {
  return __builtin_amdgcn_mfma_f32_16x16x32_bf16(
      __builtin_bit_cast(bf16x8, a), __builtin_bit_cast(bf16x8, b), c, 0, 0, 0);
}
// K=16 variant: A/B are 4 bf16 (2 VGPRs)
__device__ __forceinline__ f32x4 mfma16k16(u16x4 a, u16x4 b, f32x4 c) {
  return __builtin_amdgcn_mfma_f32_16x16x16bf16_1k(
      __builtin_bit_cast(s16x4, a), __builtin_bit_cast(s16x4, b), c, 0, 0, 0);
}
// async global->LDS, 16B per lane; LDS dest = wave-uniform base + lane*16
__device__ __forceinline__ void glds16(const void* g, void* l) {
  __builtin_amdgcn_global_load_lds((const __attribute__((address_space(1))) void*)g,
                                   (__attribute__((address_space(3))) void*)l, 16, 0, 0);
}
// bijective XCD-chunked remap: XCD x (= bid&7 empirically) owns a contiguous
// logical-tile range -> blocks sharing operand panels are L2-co-resident.
__device__ __forceinline__ int xcd_chunk(int bid, int nwg) {
  int xcd = bid & 7, idx = bid >> 3;
  int q = nwg >> 3, r = nwg & 7;
  int base = xcd < r ? xcd * (q + 1) : r * (q + 1) + (xcd - r) * q;
  return base + idx;
}
// selected token-block mask from sel[4]: {clip(b0), b1 if >=0} per t.
__device__ __forceinline__ int sel_mask(const int* __restrict__ sel) {
  int m = 0;
#pragma unroll
  for (int tt = 0; tt < 2; ++tt) {
    int a = sel[2 * tt];
    if (a < 0) a = 0;
    m |= 1 << a;
    int b = sel[2 * tt + 1];
    if (b >= 0) m |= 1 << b;
  }
  return m;
}

// ---------------- fused fp32 -> bf16 conversion; his rows sel-predicated ----------
__global__ __launch_bounds__(256) void cvt_all(
    const float* __restrict__ hs, const float* __restrict__ his,
    const float* __restrict__ Wq, const float* __restrict__ Wk,
    const float* __restrict__ Wv, const float* __restrict__ Wo,
    u16* __restrict__ hsb, u16* __restrict__ hib,
    u16* __restrict__ wqb, u16* __restrict__ wkb,
    u16* __restrict__ wvb, u16* __restrict__ wob,
    const int* __restrict__ sel) {
  // f4-chunk boundaries (all /256 -> block-uniform branch)
  const int N0 = 1198080, N1 = 5990400, N2 = 6580224, N3 = 7170048, N4 = 7759872;
  int i = blockIdx.x * 256 + threadIdx.x;
  const float* s; u16* o; int base;
  if (i < N0)      { s = hs;  o = hsb; base = 0;  }
  else if (i < N1) { s = his; o = hib; base = N0; }
  else if (i < N2) { s = Wq;  o = wqb; base = N1; }
  else if (i < N3) { s = Wk;  o = wkb; base = N2; }
  else if (i < N4) { s = Wv;  o = wvb; base = N3; }
  else             { s = Wo;  o = wob; base = N4; }
  int j = i - base;
  if (base == N0) {  // his region: skip rows in unselected token-blocks (never read)
    int row = j / 384;                 // 384 f4 per 1536-col row
    if (!((sel_mask(sel) >> (row / 1560)) & 1)) return;
  }
  float4 v = ((const float4*)s)[j];
  u16x4 r;
  r.x = f2bf(v.x); r.y = f2bf(v.y); r.z = f2bf(v.z); r.w = f2bf(v.w);
  ((u16x4*)o)[j] = r;
}

// ---------------- GEMM: C[M,1536] = A[M,1536] @ W[1536,1536]^T + bias ----------------
// (used for the output projection only now)
template <int OUT, int NBX>  // OUT: 0 = bf16, 1 = f32
__global__ __launch_bounds__(256, 2) void gemm_v2(
    const u16* __restrict__ A, const u16* __restrict__ W,
    const float* __restrict__ bias, void* __restrict__ Cp, int M) {
  const int K = 1536, N = 1536;
  __shared__ __align__(16) u16 gsm[17408];
  u16* As = gsm;
  u16* Bs = gsm + 8192;
  const int tid = threadIdx.x;
  const int lane = tid & 63, wid = tid >> 6;
  const int quad = lane >> 4, l15 = lane & 15;
  const int lg = xcd_chunk(blockIdx.x, gridDim.x);
  const int m0 = (lg / NBX) * 128, n0 = (lg % NBX) * 128;
  const int wm = (wid >> 1) * 64, wn = (wid & 1) * 64;
  f32x4 acc[4][4];
#pragma unroll
  for (int i = 0; i < 4; ++i)
#pragma unroll
    for (int j = 0; j < 4; ++j)
#pragma unroll
      for (int r = 0; r < 4; ++r) acc[i][j][r] = 0.f;

  const int r8 = lane >> 3, c8 = lane & 7;
  const int gch = c8 ^ r8;

  for (int k0 = 0; k0 < K; k0 += 64) {
#pragma unroll
    for (int inst = 0; inst < 4; ++inst) {
      int row = wid * 32 + inst * 8 + r8;
      glds16(A + ((size_t)(m0 + row) * K + k0 + gch * 8), As + (wid * 32 + inst * 8) * 64);
      glds16(W + ((size_t)(n0 + row) * K + k0 + gch * 8), Bs + (wid * 32 + inst * 8) * 64);
    }
    asm volatile("s_waitcnt vmcnt(0)" ::: "memory");
    __syncthreads();
#pragma unroll
    for (int ks = 0; ks < 2; ++ks) {
      u16x8 af[4], bfr[4];
#pragma unroll
      for (int i = 0; i < 4; ++i) {
        int row = wm + i * 16 + l15;
        af[i] = *(const u16x8*)&As[row * 64 + (((ks * 4 + quad) ^ (l15 & 7)) * 8)];
      }
#pragma unroll
      for (int j = 0; j < 4; ++j) {
        int row = wn + j * 16 + l15;
        bfr[j] = *(const u16x8*)&Bs[row * 64 + (((ks * 4 + quad) ^ (l15 & 7)) * 8)];
      }
#pragma unroll
      for (int i = 0; i < 4; ++i)
#pragma unroll
        for (int j = 0; j < 4; ++j) acc[i][j] = mfma16(af[i], bfr[j], acc[i][j]);
    }
    __syncthreads();
  }

#pragma unroll
  for (int i = 0; i < 4; ++i) {
    int row = m0 + wm + i * 16 + quad * 4;
#pragma unroll
    for (int j = 0; j < 4; ++j) {
      int col = n0 + wn + j * 16 + l15;
      float bc = bias[col];
#pragma unroll
      for (int r = 0; r < 4; ++r) {
        if (row + r < M) {
          float v = acc[i][j][r] + bc;
          if (OUT == 1)
            ((float*)Cp)[(size_t)(row + r) * N + col] = v;
          else
            ((u16*)Cp)[(size_t)(row + r) * N + col] = f2bf(v);
        }
      }
    }
  }
}

// ---------------- merged Q + K + V projection GEMM, XCD-balanced -------------------
__global__ __launch_bounds__(256, 2) void gemm_qkv(
    const u16* __restrict__ Aq, const u16* __restrict__ Akv,
    const u16* __restrict__ Wqp, const u16* __restrict__ Wkv,
    const float* __restrict__ bq, const float* __restrict__ bk,
    const float* __restrict__ bv,
    u16* __restrict__ Cq, u16* __restrict__ Ck, u16* __restrict__ Vt,
    const int* __restrict__ sel, int ldt) {
  const int K = 1536;
  __shared__ __align__(16) u16 gsm[17408];
  u16* As = gsm;
  u16* Bs = gsm + 8192;
  const int tid = threadIdx.x;
  const int lane = tid & 63, wid = tid >> 6;
  const int quad = lane >> 4, l15 = lane & 15;
  const int xcd = blockIdx.x & 7, idx = blockIdx.x >> 3;
  const int qn = (xcd < 4) ? 38 : 37;

  const u16 *A, *W;
  const float* bias;
  u16* out;
  int m0, n0, M, vmode;
  if (idx < qn) {  // Q-projection tile (balanced across XCDs)
    int qid = (xcd < 4 ? xcd * 38 : 152 + (xcd - 4) * 37) + idx;  // 0..299
    A = Aq; W = Wqp; bias = bq; out = Cq;
    m0 = (qid / 12) * 128; n0 = (qid % 12) * 128; M = 3120; vmode = 0;
  } else {  // KV-projection
    int kidx = idx - qn;
    if (kidx >= 294) return;           // xcd>=4 spare slot
    int L2 = xcd * 294 + kidx;         // 0..2351
    int qtr = L2 / 588, rem = L2 % 588;   // 588 = 98 m x 6 n per quarter
    int mi = rem / 6;
    m0 = ((mi * 25) % 98) * 128;          // scattered m-panel (bijective, 25⊥98)
    n0 = (qtr * 6 + rem % 6) * 128;       // 0..2944
    {  // selection-aware early exit
      int mask = sel_mask(sel);
      int tb0 = m0 / 1560, tb1 = (m0 + 127) / 1560;
      if (!((mask >> tb0) & 1) && !((mask >> tb1) & 1)) return;
    }
    A = Akv; W = Wkv; M = 12480;
    if (n0 < 1536) { bias = bk; out = Ck; vmode = 0; }
    else { bias = bv; out = nullptr; vmode = 1; }
  }

  const int wm = (wid >> 1) * 64, wn = (wid & 1) * 64;
  f32x4 acc[4][4];
#pragma unroll
  for (int i = 0; i < 4; ++i)
#pragma unroll
    for (int j = 0; j < 4; ++j)
#pragma unroll
      for (int r = 0; r < 4; ++r) acc[i][j][r] = 0.f;

  const int r8 = lane >> 3, c8 = lane & 7;
  const int gch = c8 ^ r8;

  for (int k0 = 0; k0 < K; k0 += 64) {
#pragma unroll
    for (int inst = 0; inst < 4; ++inst) {
      int row = wid * 32 + inst * 8 + r8;
      glds16(A + ((size_t)(m0 + row) * K + k0 + gch * 8), As + (wid * 32 + inst * 8) * 64);
      glds16(W + ((size_t)(n0 + row) * K + k0 + gch * 8), Bs + (wid * 32 + inst * 8) * 64);
    }
    asm volatile("s_waitcnt vmcnt(0)" ::: "memory");
    __syncthreads();
#pragma unroll
    for (int ks = 0; ks < 2; ++ks) {
      u16x8 af[4], bfr[4];
#pragma unroll
      for (int i = 0; i < 4; ++i) {
        int row = wm + i * 16 + l15;
        af[i] = *(const u16x8*)&As[row * 64 + (((ks * 4 + quad) ^ (l15 & 7)) * 8)];
      }
#pragma unroll
      for (int j = 0; j < 4; ++j) {
        int row = wn + j * 16 + l15;
        bfr[j] = *(const u16x8*)&Bs[row * 64 + (((ks * 4 + quad) ^ (l15 & 7)) * 8)];
      }
#pragma unroll
      for (int i = 0; i < 4; ++i)
#pragma unroll
        for (int j = 0; j < 4; ++j) acc[i][j] = mfma16(af[i], bfr[j], acc[i][j]);
    }
    __syncthreads();
  }

  if (vmode == 0) {  // plain bf16 store (Q-proj or K-proj)
#pragma unroll
    for (int i = 0; i < 4; ++i) {
      int row = m0 + wm + i * 16 + quad * 4;
#pragma unroll
      for (int j = 0; j < 4; ++j) {
        int col = n0 + wn + j * 16 + l15;
        float bc = bias[col];
#pragma unroll
        for (int r = 0; r < 4; ++r) {
          if (row + r < M)
            out[(size_t)(row + r) * 1536 + col] = f2bf(acc[i][j][r] + bc);
        }
      }
    }
  } else {  // V-projection: transposed store via LDS
    const int n0v = n0 - 1536;
    u16* Ct = gsm;  // [128 n][136]
#pragma unroll
    for (int i = 0; i < 4; ++i)
#pragma unroll
      for (int j = 0; j < 4; ++j) {
        int nloc = wn + j * 16 + l15;
        float bc = bias[n0v + nloc];
#pragma unroll
        for (int r = 0; r < 4; ++r) {
          int mloc = wm + i * 16 + quad * 4 + r;
          Ct[nloc * 136 + mloc] = f2bf(acc[i][j][r] + bc);
        }
      }
    __syncthreads();
    int n = tid >> 1, half = tid & 1;
#pragma unroll
    for (int e = 0; e < 8; ++e) {
      int mloc = half * 64 + e * 8;
      if (m0 + mloc < M) {
        u16x8 v = *(const u16x8*)&Ct[n * 136 + mloc];
        *(u16x8*)(Vt + (size_t)(n0v + n) * ldt + m0 + mloc) = v;
      }
    }
  }
}

// ---------------- merged RMSNorm + RoPE for Q and K (one launch) -------------------
__global__ __launch_bounds__(192) void norm_rope_all(
    u16* __restrict__ Xq, u16* __restrict__ Xk,
    const float* __restrict__ gq, const float* __restrict__ gk,
    const float* __restrict__ fc, const float* __restrict__ fs,
    const float* __restrict__ fch, const float* __restrict__ fsh,
    float qscale, const int* __restrict__ sel) {
  const int DIMc = 1536;
  int bidr = blockIdx.x;
  u16* X;
  const float *g, *fcp, *fsp;
  float oscale;
  int row;
  if (bidr < 3120) {
    X = Xq; g = gq; fcp = fc; fsp = fs; oscale = qscale; row = bidr;
  } else {
    row = bidr - 3120;
    if (!((sel_mask(sel) >> (row / 1560)) & 1)) return;
    X = Xk; g = gk; fcp = fch; fsp = fsh; oscale = 1.0f;
  }
  int tid = threadIdx.x;
  u16* xr = X + (size_t)row * DIMc + tid * 8;
  u16x8 v = *(const u16x8*)xr;
  float x[8];
  float ss = 0.f;
#pragma unroll
  for (int e = 0; e < 8; ++e) { x[e] = bf2f(v[e]); ss += x[e] * x[e]; }
#pragma unroll
  for (int m = 1; m < 64; m <<= 1) ss += __shfl_xor(ss, m);
  __shared__ float w3[3];
  if ((tid & 63) == 0) w3[tid >> 6] = ss;
  __syncthreads();
  float rs = rsqrtf((w3[0] + w3[1] + w3[2]) * (1.f / 1536.f) + 1e-5f);
  int dhb = (tid * 8) & 127;
  const float* fcr = fcp + (size_t)row * 128 + dhb;
  const float* fsr = fsp + (size_t)row * 128 + dhb;
  float4 c0 = *(const float4*)fcr, c1 = *(const float4*)(fcr + 4);
  float4 s0 = *(const float4*)fsr, s1 = *(const float4*)(fsr + 4);
  const float* gp = g + tid * 8;
  float4 g0 = *(const float4*)gp, g1 = *(const float4*)(gp + 4);
  float cosv[4] = {c0.x, c0.z, c1.x, c1.z};
  float sinv[4] = {s0.y, s0.w, s1.y, s1.w};
  float gv[8] = {g0.x, g0.y, g0.z, g0.w, g1.x, g1.y, g1.z, g1.w};
  u16x8 o;
#pragma unroll
  for (int p = 0; p < 4; ++p) {
    float a = x[2 * p] * rs * gv[2 * p];
    float b = x[2 * p + 1] * rs * gv[2 * p + 1];
    o[2 * p] = f2bf((a * cosv[p] - b * sinv[p]) * oscale);
    o[2 * p + 1] = f2bf((a * sinv[p] + b * cosv[p]) * oscale);
  }
  *(u16x8*)xr = o;
}

// ---------------- block-sparse attention v14: VALU-trimmed (R17) -------------------
// Same structure as v13 (equal-length adaptive segmentation). Two VALU cuts:
//  (1) stateless precomputed-base staging addresses: off = kg*DIMc + (kg>=HWc?C1:C0),
//      OOB -> C0 (key 0). Replaces per-chunk token select + 2 integer muls per glds
//      group (~13 ops) with ~7. C1 garbage when b1<0 is dead (kg>=HWc => OOB => C0).
//  (2) softmax denominator via ones-MFMA: lacc[qt] += mfma16k16(ones, pb[gg][qt]) --
//      all-ones A makes every D row = sum_k p[k][q], so 4 idle-pipe MFMAs/chunk
//      replace 16 VALU adds AND the final cross-quad shuffles. Denominator now uses
//      the same bf16-rounded p as the numerator (self-consistent).
__global__ __launch_bounds__(256, 3) void attn14(
    const u16* __restrict__ Q, const u16* __restrict__ Kb,
    const u16* __restrict__ VT, const int* __restrict__ sel,
    float* __restrict__ Oacc, float* __restrict__ Lp) {
  const int HWc = 1560, DIMc = 1536, KTt = 12480, NT = 600;
  __shared__ __align__(16) u16 smem[16384];  // Ks0|Ks1|Vt0|Vt1 (8 KB each)
  const int tid = threadIdx.x;
  const int lane = tid & 63, wid = tid >> 6;
  const int quad = lane >> 4, l15 = lane & 15;

  int bid = blockIdx.x;
  int xcd = bid & 7, idx = bid >> 3;   // idx 0..116
  int ug = idx / 13, mt = idx % 13;    // ug 0..8
  int u = xcd + 8 * ug;                // 0..71
  const int h = u / 6;
  const int slot = u % 6;

  // adaptive slot -> (t, seg)
  const int nch0 = (sel[1] >= 0) ? 98 : 49;
  const int nch1 = (sel[3] >= 0) ? 98 : 49;
  const int ns0 = 6 * nch0 / (nch0 + nch1);  // exact integer for all cases
  const int t = (slot < ns0) ? 0 : 1;
  const int si = (slot < ns0) ? slot : slot - ns0;
  const int nseg = (slot < ns0) ? ns0 : 6 - ns0;
  const int m0 = mt * 128;
  const int g = h * 2 + t;

  int s0v = sel[2 * t];
  const int b0 = s0v > 0 ? s0v : 0;
  const int b1 = sel[2 * t + 1];
  const int b1c = b1 >= 0 ? b1 : 0;
  const int nk = (b1 >= 0) ? 2 * HWc : HWc;
  const int nch = (b1 >= 0) ? 98 : 49;
  const int cpseg = (nch + nseg - 1) / nseg;
  const int c0 = si * cpseg;
  const int c1 = (c0 + cpseg < nch) ? c0 + cpseg : nch;

  // Q B-frags: this wave's 32 q rows (2 sub-tiles of 16)
  u16x8 qf[2][4];
#pragma unroll
  for (int qt = 0; qt < 2; ++qt) {
    int qrow = m0 + wid * 32 + qt * 16 + l15;
    if (qrow > HWc - 1) qrow = HWc - 1;
    const u16* qp = Q + (size_t)(t * HWc + qrow) * DIMc + h * 128;
#pragma unroll
    for (int ks = 0; ks < 4; ++ks) qf[qt][ks] = *(const u16x8*)(qp + ks * 32 + quad * 8);
  }

  // precomputed per-lane staging address bases (u16-element units, signed int)
  const int hb = h * 128;
  int klK[2], C0K[2], C1K[2];
#pragma unroll
  for (int n = 0; n < 2; ++n) {
    klK[n] = wid * 8 + n * 4 + (lane >> 4);
    int gc = (lane & 15) ^ (klK[n] & 15);
    int col = hb + gc * 8;
    C0K[n] = b0 * HWc * DIMc + col;
    C1K[n] = (b1c - 1) * HWc * DIMc + col;
  }
  int tgV[2], D0V[2], D1V[2];
#pragma unroll
  for (int n = 0; n < 2; ++n) {
    int dl = wid * 32 + n * 16 + (lane >> 2);
    int gc = (lane & 3) ^ (dl & 3) ^ ((dl >> 2) & 3);
    tgV[n] = gc * 8;
    int rowbase = (hb + dl) * KTt;
    D0V[n] = rowbase + b0 * HWc;
    D1V[n] = rowbase + (b1c - 1) * HWc;
  }

  f32x4 oacc[2][8];  // partial O^T: [q-subtile][d-tile]
#pragma unroll
  for (int qt = 0; qt < 2; ++qt)
#pragma unroll
    for (int m = 0; m < 8; ++m)
#pragma unroll
      for (int r = 0; r < 4; ++r) oacc[qt][m][r] = 0.f;
  f32x4 lacc[2];  // denominator accumulators (every row = sum_k p)
#pragma unroll
  for (int qt = 0; qt < 2; ++qt)
#pragma unroll
    for (int r = 0; r < 4; ++r) lacc[qt][r] = 0.f;
  const u16x4 ones4 = {0x3F80u, 0x3F80u, 0x3F80u, 0x3F80u};  // bf16 1.0 x4

  auto stage = [&](int kc, int buf) {
    u16* Ks = smem + buf * 4096;
    u16* Vt = smem + 8192 + buf * 4096;
#pragma unroll
    for (int n = 0; n < 2; ++n) {
      int kg = kc + klK[n];
      int off = kg * DIMc + (kg >= HWc ? C1K[n] : C0K[n]);
      if (kg >= nk) off = C0K[n];
      glds16(Kb + off, Ks + (wid * 8 + n * 4) * 128);
    }
#pragma unroll
    for (int n = 0; n < 2; ++n) {
      int tg = kc + tgV[n];
      int off = tg + (tg >= HWc ? D1V[n] : D0V[n]);
      if (tg >= nk) off = D0V[n];
      glds16(VT + off, Vt + (wid * 32 + n * 16) * 32);
    }
  };

  if (c0 < c1) stage(c0 * 32, 0);

  for (int c = c0; c < c1; ++c) {
    const int buf = (c - c0) & 1;
    u16* Ks = smem + buf * 4096;
    u16* Vt = smem + 8192 + buf * 4096;
    asm volatile("s_waitcnt vmcnt(0)\n\ts_barrier" ::: "memory");
    if (c + 1 < c1) stage((c + 1) * 32, buf ^ 1);

    f32x4 s[2][2];  // [gg][qt]
#pragma unroll
    for (int gg = 0; gg < 2; ++gg)
#pragma unroll
      for (int qt = 0; qt < 2; ++qt)
#pragma unroll
        for (int r = 0; r < 4; ++r) s[gg][qt][r] = 0.f;
#pragma unroll
    for (int ks = 0; ks < 4; ++ks)
#pragma unroll
      for (int gg = 0; gg < 2; ++gg) {
        u16x8 ka = *(const u16x8*)&Ks[(gg * 16 + l15) * 128 + (((ks * 4 + quad) ^ l15) * 8)];
#pragma unroll
        for (int qt = 0; qt < 2; ++qt) s[gg][qt] = mfma16(ka, qf[qt][ks], s[gg][qt]);
      }

    float p[2][2][4];
#pragma unroll
    for (int gg = 0; gg < 2; ++gg)
#pragma unroll
      for (int qt = 0; qt < 2; ++qt)
#pragma unroll
        for (int r = 0; r < 4; ++r) p[gg][qt][r] = exp2f(s[gg][qt][r]);
    if ((c + 1) * 32 > nk) {  // wave-uniform
#pragma unroll
      for (int gg = 0; gg < 2; ++gg)
#pragma unroll
        for (int r = 0; r < 4; ++r) {
          bool bad = c * 32 + gg * 16 + quad * 4 + r >= nk;
          if (bad) {
#pragma unroll
            for (int qt = 0; qt < 2; ++qt) p[gg][qt][r] = 0.f;
          }
        }
    }
    u16x4 pb[2][2];
#pragma unroll
    for (int gg = 0; gg < 2; ++gg)
#pragma unroll
      for (int qt = 0; qt < 2; ++qt)
#pragma unroll
        for (int r = 0; r < 4; ++r) pb[gg][qt][r] = f2bf_hw(p[gg][qt][r]);

    // denominator: ones-MFMA (every output row = full key-sum for q-col l15)
#pragma unroll
    for (int gg = 0; gg < 2; ++gg)
#pragma unroll
      for (int qt = 0; qt < 2; ++qt) lacc[qt] = mfma16k16(ones4, pb[gg][qt], lacc[qt]);

#pragma unroll
    for (int m = 0; m < 8; ++m) {
      int d = m * 16 + l15;
#pragma unroll
      for (int gg = 0; gg < 2; ++gg) {
        int sl = (gg * 2 + (quad >> 1)) ^ (d & 3) ^ ((d >> 2) & 3);
        u16x4 va = *(const u16x4*)&Vt[d * 32 + sl * 8 + (quad & 1) * 4];
#pragma unroll
        for (int qt = 0; qt < 2; ++qt) oacc[qt][m] = mfma16k16(va, pb[gg][qt], oacc[qt][m]);
      }
    }
  }

#pragma unroll
  for (int qt = 0; qt < 2; ++qt) {
    int qrow0 = m0 + wid * 32 + qt * 16;  // wave-uniform
    if (qrow0 < HWc) {
      size_t sb = ((size_t)si * NT + g * 25 + (qrow0 >> 6)) * 64 + (qrow0 & 63);
      if (lane < 16 && qrow0 + lane < HWc) Lp[sb + lane] = lacc[qt][0];
      if (qrow0 + l15 < HWc) {
#pragma unroll
        for (int m = 0; m < 8; ++m)
          *(f32x4*)&Oacc[(sb + l15) * 128 + m * 16 + quad * 4] = oacc[qt][m];
      }
    }
  }
}

// ---------------- normalize: O = bf16(sum_seg Oacc / sum_seg Lp) ----------------
__global__ __launch_bounds__(256) void attn_norm(const float* __restrict__ Oacc,
                                                 const float* __restrict__ Lp,
                                                 const int* __restrict__ sel,
                                                 u16* __restrict__ O) {
  const int HWc = 1560, DIMc = 1536, NT = 600;
  int tile = blockIdx.x;  // 600
  int g = tile / 25, mt = tile % 25;
  int h = g >> 1, t = g & 1;
  int m0 = mt * 64;
  int tid = threadIdx.x;
  const int nch0 = (sel[1] >= 0) ? 98 : 49;
  const int nch1 = (sel[3] >= 0) ? 98 : 49;
  const int ns0 = 6 * nch0 / (nch0 + nch1);
  const int nseg = (t == 0) ? ns0 : 6 - ns0;
#pragma unroll
  for (int e = 0; e < 8; ++e) {
    int idx = e * 256 + tid;   // 0..2047 f32x4 slots (64 q x 32)
    int qloc = idx >> 5;
    int d4 = (idx & 31) * 4;
    int q = m0 + qloc;
    if (q < HWc) {
      f32x4 a = {0.f, 0.f, 0.f, 0.f};
      float l = 0.f;
      for (int s = 0; s < nseg; ++s) {
        const size_t sbase = ((size_t)s * NT + tile) * 64 + qloc;
        f32x4 v = *(const f32x4*)&Oacc[sbase * 128 + d4];
#pragma unroll
        for (int r = 0; r < 4; ++r) a[r] += v[r];
        l += Lp[sbase];
      }
      float linv = 1.f / l;
      u16x4 o;
#pragma unroll
      for (int r = 0; r < 4; ++r) o[r] = f2bf(a[r] * linv);
      *(u16x4*)(O + (size_t)(t * HWc + q) * DIMc + h * 128 + d4) = o;
    }
  }
}

extern "C" void kernel_launch(void* const* d_in, const int* in_sizes, int n_in,
                              void* d_out, int out_size, void* d_ws, size_t ws_size,
                              hipStream_t stream) {
  const float* hs  = (const float*)d_in[0];
  const float* his = (const float*)d_in[1];
  const float* fc  = (const float*)d_in[2];
  const float* fs  = (const float*)d_in[3];
  const float* fch = (const float*)d_in[4];
  const float* fsh = (const float*)d_in[5];
  const int*   sel = (const int*)d_in[6];
  const float* Wq  = (const float*)d_in[7];
  const float* bq  = (const float*)d_in[8];
  const float* Wk  = (const float*)d_in[9];
  const float* bk  = (const float*)d_in[10];
  const float* Wv  = (const float*)d_in[11];
  const float* bv  = (const float*)d_in[12];
  const float* Wo  = (const float*)d_in[13];
  const float* bo  = (const float*)d_in[14];
  const float* gq  = (const float*)d_in[15];
  const float* gk  = (const float*)d_in[16];

  const int QT = 3120, KT = 12480, DIMc = 1536;
  u16* p = (u16*)d_ws;
  u16* qb  = p; p += (size_t)QT * DIMc;
  u16* kb2 = p; p += (size_t)KT * DIMc;
  u16* vt  = p; p += (size_t)DIMc * KT;   // V^T [1536][12480]
  u16* ab  = p; p += (size_t)QT * DIMc;
  u16* wob = p; p += (size_t)DIMc * DIMc;
  u16* scratch = p;
  u16* hsb = scratch;
  u16* hib = hsb + (size_t)QT * DIMc;
  u16* wqb = hib + (size_t)KT * DIMc;
  u16* wkb = wqb + (size_t)DIMc * DIMc;   // wkb and wvb adjacent -> stacked [3072][1536]
  u16* wvb = wkb + (size_t)DIMc * DIMc;
  float* oaccb = (float*)scratch;                      // f32 [4][600][64][128]
  float* lpb   = oaccb + (size_t)4 * 600 * 64 * 128;   // f32 [4][600][64]

  cvt_all<<<dim3(32616), 256, 0, stream>>>(hs, his, Wq, Wk, Wv, Wo,
                                           hsb, hib, wqb, wkb, wvb, wob, sel);

  gemm_qkv<<<dim3(2656), 256, 0, stream>>>(hsb, hib, wqb, wkb, bq, bk, bv,
                                           qb, kb2, vt, sel, KT);

  const float qscale = (float)(0.08838834764831845 * 1.4426950408889634);
  norm_rope_all<<<dim3(QT + KT), 192, 0, stream>>>(qb, kb2, gq, gk, fc, fs, fch, fsh,
                                                   qscale, sel);

  // attn14 clobbers hsb/hib/wq/wk/wv (all dead by now); wob stays live for the final gemm.
  attn14<<<dim3(936), 256, 0, stream>>>(qb, kb2, vt, sel, oaccb, lpb);
  attn_norm<<<dim3(600), 256, 0, stream>>>(oaccb, lpb, sel, ab);

  gemm_v2<1, 12><<<dim3(300), 256, 0, stream>>>(ab, wob, bo, d_out, QT);
}